// Round 21
// baseline (382.657 us; speedup 1.0000x reference)
//
#include <hip/hip_runtime.h>
#include <math.h>

typedef unsigned short ushort_t;
typedef __attribute__((ext_vector_type(8))) short short8;
typedef __attribute__((ext_vector_type(4))) float f32x4;

#define MFMA16(a, b, c) __builtin_amdgcn_mfma_f32_16x16x32_bf16((a), (b), (c), 0, 0, 0)

static __device__ __forceinline__ float fast_exp2(float x) {
#if __has_builtin(__builtin_amdgcn_exp2f)
  return __builtin_amdgcn_exp2f(x);
#else
  return exp2f(x);
#endif
}

static __device__ __forceinline__ ushort_t f2bf(float f) {
  unsigned int u = __float_as_uint(f);
  u = u + 0x7FFFu + ((u >> 16) & 1u);  // RTNE
  return (ushort_t)(u >> 16);
}
static __device__ __forceinline__ ushort_t f2bf_trunc(float f) {
  return (ushort_t)(__float_as_uint(f) >> 16);  // truncate: 1 op, fine for P in [0,1]
}
static __device__ __forceinline__ float bf2f(ushort_t s) {
  return __uint_as_float(((unsigned int)s) << 16);
}

// async global->LDS, 16B per lane. l_uniform: wave-uniform LDS base (lane*16 implicit).
static __device__ __forceinline__ void stage16(const ushort_t* g_perlane, char* l_uniform, int lane) {
#if __has_builtin(__builtin_amdgcn_global_load_lds)
  __builtin_amdgcn_global_load_lds((const __attribute__((address_space(1))) void*)g_perlane,
                                   (__attribute__((address_space(3))) void*)l_uniform, 16, 0, 0);
#else
  *(uint4*)(l_uniform + lane * 16) = *(const uint4*)g_perlane;
#endif
}

// ---------------- RMSNorm fp32 in -> bf16 out ----------------
__global__ __launch_bounds__(256) void rmsnorm_k(const float* __restrict__ x,
                                                 const float* __restrict__ g,
                                                 ushort_t* __restrict__ o) {
  const int r = blockIdx.x, t = threadIdx.x;
  const float4 xv = ((const float4*)(x + (size_t)r * 1024))[t];
  float ss = xv.x * xv.x + xv.y * xv.y + xv.z * xv.z + xv.w * xv.w;
#pragma unroll
  for (int m = 32; m >= 1; m >>= 1) ss += __shfl_xor(ss, m);
  __shared__ float wp[4];
  if ((t & 63) == 0) wp[t >> 6] = ss;
  __syncthreads();
  const float inv = rsqrtf((wp[0] + wp[1] + wp[2] + wp[3]) * (1.f / 1024.f) + 1e-5f);
  const float4 gv = ((const float4*)g)[t];
  ushort4 ov = {f2bf(xv.x * inv * gv.x), f2bf(xv.y * inv * gv.y),
                f2bf(xv.z * inv * gv.z), f2bf(xv.w * inv * gv.w)};
  *(ushort4*)(o + (size_t)r * 1024 + t * 4) = ov;
}

// ---------------- transpose + cast: fp32 [R][C] -> bf16 rows of out ----------------
// mode 0: out row = col.  mode 1/2: interleaved W1/W3 fragment rows.
__global__ __launch_bounds__(256) void transpose_cast_k(const float* __restrict__ in,
                                                        ushort_t* __restrict__ out,
                                                        int R, int C, int mode) {
  __shared__ ushort_t Ts[64][72];
  const int t = threadIdx.x;
  const int c0 = blockIdx.x * 64, r0 = blockIdx.y * 64;
  const int lr = t >> 4, lc = (t & 15) * 4;
#pragma unroll
  for (int i = 0; i < 4; ++i) {
    const float4 v = *(const float4*)&in[(size_t)(r0 + lr + i * 16) * C + c0 + lc];
    Ts[lr + i * 16][lc + 0] = f2bf(v.x);
    Ts[lr + i * 16][lc + 1] = f2bf(v.y);
    Ts[lr + i * 16][lc + 2] = f2bf(v.z);
    Ts[lr + i * 16][lc + 3] = f2bf(v.w);
  }
  __syncthreads();
  const int rr = (t & 15) * 4;
#pragma unroll
  for (int i = 0; i < 4; ++i) {
    const int cc = (t >> 4) + i * 16;
    const int cg = c0 + cc;
    int orow;
    if (mode == 0)
      orow = cg;
    else
      orow = ((cg >> 7) << 8) + (((cg >> 4) & 7) << 5) + (cg & 15) + (mode == 2 ? 16 : 0);
    ushort4 o = {Ts[rr + 0][cc], Ts[rr + 1][cc], Ts[rr + 2][cc], Ts[rr + 3][cc]};
    *(ushort4*)&out[(size_t)orow * R + r0 + rr] = o;
  }
}

// ---------------- 4x fused 1024x1024 transpose+cast (Wq,Wk,Wv,Wo in one launch) ----------------
__global__ __launch_bounds__(256) void transpose4_k(const float* __restrict__ s0,
                                                    const float* __restrict__ s1,
                                                    const float* __restrict__ s2,
                                                    const float* __restrict__ s3,
                                                    ushort_t* __restrict__ d0,
                                                    ushort_t* __restrict__ d1,
                                                    ushort_t* __restrict__ d2,
                                                    ushort_t* __restrict__ d3) {
  const int z = blockIdx.z;
  const float* in = (z == 0) ? s0 : (z == 1) ? s1 : (z == 2) ? s2 : s3;
  ushort_t* out = (z == 0) ? d0 : (z == 1) ? d1 : (z == 2) ? d2 : d3;
  __shared__ ushort_t Ts[64][72];
  const int t = threadIdx.x;
  const int c0 = blockIdx.x * 64, r0 = blockIdx.y * 64;
  const int lr = t >> 4, lc = (t & 15) * 4;
#pragma unroll
  for (int i = 0; i < 4; ++i) {
    const float4 v = *(const float4*)&in[(size_t)(r0 + lr + i * 16) * 1024 + c0 + lc];
    Ts[lr + i * 16][lc + 0] = f2bf(v.x);
    Ts[lr + i * 16][lc + 1] = f2bf(v.y);
    Ts[lr + i * 16][lc + 2] = f2bf(v.z);
    Ts[lr + i * 16][lc + 3] = f2bf(v.w);
  }
  __syncthreads();
  const int rr = (t & 15) * 4;
#pragma unroll
  for (int i = 0; i < 4; ++i) {
    const int cc = (t >> 4) + i * 16;
    ushort4 o = {Ts[rr + 0][cc], Ts[rr + 1][cc], Ts[rr + 2][cc], Ts[rr + 3][cc]};
    *(ushort4*)&out[(size_t)(c0 + cc) * 1024 + r0 + rr] = o;
  }
}

// ---------------- RoPE in-place on bf16, ld=3072; Q and K in ONE launch ----------------
__global__ __launch_bounds__(256) void rope_k(ushort_t* __restrict__ qkv) {
  const int HALF = 4096 * 128;
  int idx = blockIdx.x * 256 + threadIdx.x;
  const int isK = idx >= HALF;
  idx &= HALF - 1;
  const float scale = isK ? 1.0f : 0.18033688011112042f;  // 0.125 * log2(e)
  const int row = idx >> 7, rem = idx & 127;
  const int head = rem >> 3, gq = rem & 7;
  const int i0 = gq * 4;
  const int s = row & 2047;
  ushort_t* p = qkv + (size_t)row * 3072 + isK * 1024 + head * 64 + i0 * 2;
  uint4 v = *(uint4*)p;
  ushort_t* e = (ushort_t*)&v;
#pragma unroll
  for (int k = 0; k < 4; ++k) {
    const float ang = (float)s * expf(-(float)(i0 + k) * 0.28782313662425572f);  // ln(1e4)/32
    float sn, cs;
    sincosf(ang, &sn, &cs);
    const float x1 = bf2f(e[2 * k]), x2 = bf2f(e[2 * k + 1]);
    e[2 * k] = f2bf((x1 * cs - x2 * sn) * scale);
    e[2 * k + 1] = f2bf((x2 * cs + x1 * sn) * scale);
  }
  *(uint4*)p = v;
}

// ---------------- 256x256-tile MFMA GEMM: BK=32, 4-slot ring, PHASE-SPLIT schedule ----------------
template <int FUSED>
__global__ __launch_bounds__(512, 2) void gemm256_k(const ushort_t* __restrict__ A,
                                                    const ushort_t* __restrict__ Bt,
                                                    ushort_t* __restrict__ C,
                                                    int N, int K) {
  __shared__ uint4 smem[131072 / 16];  // A: 4 x 16KB @0 ; B: 4 x 16KB @65536
  char* sm = (char*)smem;
  const int flat = blockIdx.y * gridDim.x + blockIdx.x;
  const int total = gridDim.x * gridDim.y;
  const int swz = (flat & 7) * (total >> 3) + (flat >> 3);
  const int bx = swz % gridDim.x, by = swz / gridDim.x;
  const int t = threadIdx.x, lane = t & 63, w = t >> 6;
  const int g = lane >> 4, li = lane & 15;
  const int wr = w >> 2, wc = w & 3;
  const int nr0 = bx * 256, m0 = by * 256;
  const int wb4 = (t & 448) << 4;  // wave base * 16
  const int srow = t & 255;
  const int sg0 = t >> 8;  // 0..1
  const size_t rowA = (size_t)(m0 + srow) * K;
  const size_t rowB = (size_t)(nr0 + srow) * K;
  f32x4 acc[8][4] = {};
  const int nkt = K >> 5;  // BK=32

  auto stageA = [&](int kt) {
    char* dA = sm + (kt & 3) * 16384;
    const int k0 = kt << 5;
#pragma unroll
    for (int c = 0; c < 2; ++c)
      stage16(A + rowA + k0 + (c * 2 + sg0) * 8, dA + ((c * 512) << 4) + wb4, lane);
  };
  auto stageB = [&](int kt) {
    char* dB = sm + 65536 + (kt & 3) * 16384;
    const int k0 = kt << 5;
#pragma unroll
    for (int c = 0; c < 2; ++c)
      stage16(Bt + rowB + k0 + (c * 2 + sg0) * 8, dB + ((c * 512) << 4) + wb4, lane);
  };

  stageA(0); stageB(0); stageA(1); stageB(1);       // 8 loads
  asm volatile("s_waitcnt vmcnt(4)" ::: "memory");  // tile0 forced; tile1 in flight
  __builtin_amdgcn_s_barrier();
  for (int kt = 0; kt < nkt; ++kt) {
    const char* sA = sm + (kt & 3) * 16384;
    const char* sB = sm + 65536 + (kt & 3) * 16384;
    const bool pf = (kt + 2 < nkt);
    // ---- phase 0: quadrant mi0-3 ----
    short8 af0[4], bfr[4];
#pragma unroll
    for (int mi = 0; mi < 4; ++mi)
      af0[mi] = *(const short8*)(sA + ((g * 256 + wr * 128 + mi * 16 + li) << 4));
#pragma unroll
    for (int ni = 0; ni < 4; ++ni)
      bfr[ni] = *(const short8*)(sB + ((g * 256 + wc * 64 + ni * 16 + li) << 4));
    if (pf) stageA(kt + 2);
    __builtin_amdgcn_s_barrier();
    __builtin_amdgcn_s_setprio(1);
#pragma unroll
    for (int mi = 0; mi < 4; ++mi)
#pragma unroll
      for (int ni = 0; ni < 4; ++ni) acc[mi][ni] = MFMA16(af0[mi], bfr[ni], acc[mi][ni]);
    __builtin_amdgcn_s_setprio(0);
    __builtin_amdgcn_s_barrier();
    // ---- phase 1: quadrant mi4-7 ----
    short8 af1[4];
#pragma unroll
    for (int mi = 0; mi < 4; ++mi)
      af1[mi] = *(const short8*)(sA + ((g * 256 + wr * 128 + (mi + 4) * 16 + li) << 4));
    if (pf) stageB(kt + 2);
    if (pf)
      asm volatile("s_waitcnt vmcnt(4)" ::: "memory");  // force tile kt+1; kt+2 stays in flight
    else if (kt + 1 < nkt)
      asm volatile("s_waitcnt vmcnt(0)" ::: "memory");  // tail: force last tile
    __builtin_amdgcn_s_barrier();
    __builtin_amdgcn_s_setprio(1);
#pragma unroll
    for (int mi = 0; mi < 4; ++mi)
#pragma unroll
      for (int ni = 0; ni < 4; ++ni) acc[mi + 4][ni] = MFMA16(af1[mi], bfr[ni], acc[mi + 4][ni]);
    __builtin_amdgcn_s_setprio(0);
    __builtin_amdgcn_s_barrier();
  }
  if (FUSED == 0) {
#pragma unroll
    for (int mi = 0; mi < 8; ++mi)
#pragma unroll
      for (int ni = 0; ni < 4; ++ni)
#pragma unroll
        for (int r = 0; r < 4; ++r) {
          const int row = m0 + wr * 128 + mi * 16 + g * 4 + r;
          const int col = nr0 + wc * 64 + ni * 16 + li;
          C[(size_t)row * N + col] = f2bf(acc[mi][ni][r]);
        }
  } else {
#pragma unroll
    for (int mi = 0; mi < 8; ++mi)
#pragma unroll
      for (int p = 0; p < 2; ++p)
#pragma unroll
        for (int r = 0; r < 4; ++r) {
          const float v1 = acc[mi][2 * p][r];
          const float v3 = acc[mi][2 * p + 1][r];
          const float o = v1 / (1.f + __expf(-v1)) * v3;
          const int row = m0 + wr * 128 + mi * 16 + g * 4 + r;
          const int col = bx * 128 + wc * 32 + p * 16 + li;
          C[(size_t)row * N + col] = f2bf(o);
        }
  }
}

// ---------------- 128x128-tile MFMA GEMM, 3-buffer counted-vmcnt pipeline (4 waves) ----------------
template <int MODE>
__global__ __launch_bounds__(256) void gemm_k(const ushort_t* __restrict__ A,
                                              const ushort_t* __restrict__ Bt,
                                              const float* __restrict__ R,
                                              void* __restrict__ C,
                                              int N, int K) {
  __shared__ uint4 smem[49152 / 16];  // 3 x (A 8KB @ buf*8192 | B 8KB @ 24576+buf*8192)
  char* sm = (char*)smem;
  const int flat = blockIdx.y * gridDim.x + blockIdx.x;
  const int total = gridDim.x * gridDim.y;
  const int swz = (flat & 7) * (total >> 3) + (flat >> 3);
  const int bx = swz % gridDim.x, by = swz / gridDim.x;
  const int t = threadIdx.x, lane = t & 63, w = t >> 6;
  const int g = lane >> 4, li = lane & 15;
  const int wr = w >> 1, wc = w & 1;
  const int n0 = bx * 128, m0 = by * 128;
  const int wb = t & 192;
  const int r0s = t & 127, g0s = (t >> 7) << 3;
  const size_t rowA = (size_t)(m0 + r0s) * K;
  const size_t rowB = (size_t)(n0 + r0s) * K;
  f32x4 acc[4][4] = {};
  const int nkt = K >> 5;

  auto stage_all = [&](int buf, int kt) {
    const int k0 = (kt << 5) + g0s;
    char* dA = sm + buf * 8192;
    char* dB = sm + 24576 + buf * 8192;
    stage16(A + rowA + k0, dA + (wb << 4), lane);
    stage16(A + rowA + k0 + 16, dA + ((256 + wb) << 4), lane);
    stage16(Bt + rowB + k0, dB + (wb << 4), lane);
    stage16(Bt + rowB + k0 + 16, dB + ((256 + wb) << 4), lane);
  };

  stage_all(0, 0);
  stage_all(1, 1);
  asm volatile("s_waitcnt vmcnt(4)" ::: "memory");  // buf0 landed; buf1 in flight
  __builtin_amdgcn_s_barrier();
  int b0 = 0;
  for (int kt = 0; kt < nkt; ++kt) {
    int bn = b0 + 2;
    if (bn >= 3) bn -= 3;
    if (kt + 2 < nkt) stage_all(bn, kt + 2);
    const char* smA = sm + b0 * 8192;
    const char* smB = sm + 24576 + b0 * 8192;
    short8 af[4], bfr[4];
#pragma unroll
    for (int mi = 0; mi < 4; ++mi)
      af[mi] = *(const short8*)(smA + ((g * 128 + wr * 64 + mi * 16 + li) << 4));
#pragma unroll
    for (int ni = 0; ni < 4; ++ni)
      bfr[ni] = *(const short8*)(smB + ((g * 128 + wc * 64 + ni * 16 + li) << 4));
    __builtin_amdgcn_s_setprio(1);
#pragma unroll
    for (int mi = 0; mi < 4; ++mi)
#pragma unroll
      for (int ni = 0; ni < 4; ++ni) acc[mi][ni] = MFMA16(af[mi], bfr[ni], acc[mi][ni]);
    __builtin_amdgcn_s_setprio(0);
    if (kt + 2 < nkt) {
      asm volatile("s_waitcnt vmcnt(4) lgkmcnt(0)" ::: "memory");  // kt+1 done, kt+2 in flight
      __builtin_amdgcn_s_barrier();
    } else if (kt + 1 < nkt) {
      asm volatile("s_waitcnt vmcnt(0) lgkmcnt(0)" ::: "memory");
      __builtin_amdgcn_s_barrier();
    }
    ++b0;
    if (b0 == 3) b0 = 0;
  }
#pragma unroll
  for (int mi = 0; mi < 4; ++mi)
#pragma unroll
    for (int ni = 0; ni < 4; ++ni)
#pragma unroll
      for (int r = 0; r < 4; ++r) {
        const int row = m0 + wr * 64 + mi * 16 + g * 4 + r;
        const int col = n0 + wc * 64 + ni * 16 + li;
        const float v = acc[mi][ni][r];
        if (MODE == 1)
          ((float*)C)[(size_t)row * N + col] = v + R[(size_t)row * N + col];
        else
          ((ushort_t*)C)[(size_t)row * N + col] = f2bf(v);
      }
}

// ---------------- 128x128-tile MFMA GEMM, 8 WAVES (512 thr), 3-buffer ring ----------------
// Same tile/traffic as gemm_k; 2x waves per SIMD for latency hiding (Wo, W2 shapes).
// Waves 2x4: each owns 64 rows x 32 cols (acc[4][2]). 2 global_load_lds/tile -> vmcnt(2).
template <int MODE>
__global__ __launch_bounds__(512) void gemm8w_k(const ushort_t* __restrict__ A,
                                                const ushort_t* __restrict__ Bt,
                                                const float* __restrict__ R,
                                                void* __restrict__ C,
                                                int N, int K) {
  __shared__ uint4 smem[49152 / 16];  // 3 x (A 8KB @ buf*8192 | B 8KB @ 24576+buf*8192)
  char* sm = (char*)smem;
  const int flat = blockIdx.y * gridDim.x + blockIdx.x;
  const int total = gridDim.x * gridDim.y;
  const int swz = (flat & 7) * (total >> 3) + (flat >> 3);
  const int bx = swz % gridDim.x, by = swz / gridDim.x;
  const int t = threadIdx.x, lane = t & 63, w = t >> 6;  // w in 0..7
  const int g = lane >> 4, li = lane & 15;
  const int wr = w >> 2, wc = w & 3;  // 2 x 4 waves: 64-row x 32-col each
  const int n0 = bx * 128, m0 = by * 128;
  const int r0s = t & 127, g0s = (t >> 7) << 3;  // slot = t: row t&127, k-octet t>>7 (0..3)
  const size_t rowA = (size_t)(m0 + r0s) * K;
  const size_t rowB = (size_t)(n0 + r0s) * K;
  const int wb4 = (t & 448) << 4;  // wave-uniform LDS base
  f32x4 acc[4][2] = {};
  const int nkt = K >> 5;

  auto stage_all = [&](int buf, int kt) {
    const int k0 = (kt << 5) + g0s;
    stage16(A + rowA + k0, sm + buf * 8192 + wb4, lane);
    stage16(Bt + rowB + k0, sm + 24576 + buf * 8192 + wb4, lane);
  };

  stage_all(0, 0);
  stage_all(1, 1);
  asm volatile("s_waitcnt vmcnt(2)" ::: "memory");  // buf0 landed; buf1 in flight
  __builtin_amdgcn_s_barrier();
  int b0 = 0;
  for (int kt = 0; kt < nkt; ++kt) {
    int bn = b0 + 2;
    if (bn >= 3) bn -= 3;
    if (kt + 2 < nkt) stage_all(bn, kt + 2);
    const char* smA = sm + b0 * 8192;
    const char* smB = sm + 24576 + b0 * 8192;
    short8 af[4], bfr[2];
#pragma unroll
    for (int mi = 0; mi < 4; ++mi)
      af[mi] = *(const short8*)(smA + ((g * 128 + wr * 64 + mi * 16 + li) << 4));
#pragma unroll
    for (int ni = 0; ni < 2; ++ni)
      bfr[ni] = *(const short8*)(smB + ((g * 128 + wc * 32 + ni * 16 + li) << 4));
    __builtin_amdgcn_s_setprio(1);
#pragma unroll
    for (int mi = 0; mi < 4; ++mi)
#pragma unroll
      for (int ni = 0; ni < 2; ++ni) acc[mi][ni] = MFMA16(af[mi], bfr[ni], acc[mi][ni]);
    __builtin_amdgcn_s_setprio(0);
    if (kt + 2 < nkt) {
      asm volatile("s_waitcnt vmcnt(2) lgkmcnt(0)" ::: "memory");  // kt+1 done, kt+2 in flight
      __builtin_amdgcn_s_barrier();
    } else if (kt + 1 < nkt) {
      asm volatile("s_waitcnt vmcnt(0) lgkmcnt(0)" ::: "memory");
      __builtin_amdgcn_s_barrier();
    }
    ++b0;
    if (b0 == 3) b0 = 0;
  }
#pragma unroll
  for (int mi = 0; mi < 4; ++mi)
#pragma unroll
    for (int ni = 0; ni < 2; ++ni)
#pragma unroll
      for (int r = 0; r < 4; ++r) {
        const int row = m0 + wr * 64 + mi * 16 + g * 4 + r;
        const int col = n0 + wc * 32 + ni * 16 + li;
        const float v = acc[mi][ni][r];
        if (MODE == 1)
          ((float*)C)[(size_t)row * N + col] = v + R[(size_t)row * N + col];
        else
          ((ushort_t*)C)[(size_t)row * N + col] = f2bf(v);
      }
}

// ---------------- Swapped-operand MFMA flash attention (causal) — R14-proven ----------------
__global__ __launch_bounds__(256) void attn_k(const ushort_t* __restrict__ qkv,
                                              ushort_t* __restrict__ ctx) {
  __shared__ uint4 smemv[32768 / 16];  // K0|K1 @0,8192 ; V0|V1 @16384,24576
  char* sm = (char*)smemv;
  const int qt = 31 - blockIdx.x;  // longest blocks dispatched first
  const int bh = blockIdx.y;
  const int b = bh >> 4, h = bh & 15;
  const int t = threadIdx.x, lane = t & 63, w = t >> 6;
  const int g = lane >> 4, li = lane & 15;
  const int rowb = b * 2048;
  const size_t qbase = (size_t)rowb * 3072 + h * 64;
  const int q0 = qt * 64;
  const ushort_t* kptr = qkv + qbase + 1024;
  const ushort_t* vptr = qkv + qbase + 2048;

  short8 qa[2];
  {
    const int qrow = q0 + w * 16 + li;
    qa[0] = *(const short8*)(qkv + qbase + (size_t)qrow * 3072 + 8 * g);
    qa[1] = *(const short8*)(qkv + qbase + (size_t)qrow * 3072 + 32 + 8 * g);
  }
  f32x4 acc[4] = {};
  float mr = -INFINITY, lr = 0.f;  // per-lane: q = li
  const int sb = g * 20;           // broadcast source base

  const int vj = t & 63;
  const int vcol2 = 2 * (((vj >> 5) << 5) + (((vj >> 2) & 3) << 3) + (((vj >> 4) & 1) << 2) + (vj & 3));

  uint4 vr0, vr1;  // in-flight V registers (T14)
  auto stageK = [&](int buf, int kt) {
    char* dst = sm + buf * 8192;
    const ushort_t* src = kptr + (size_t)kt * 64 * 3072 + (size_t)(t & 63) * 3072;
    stage16(src + (t >> 6) * 8, dst + ((t & 192) << 4), lane);
    stage16(src + ((t >> 6) + 4) * 8, dst + 4096 + ((t & 192) << 4), lane);
  };
  auto loadV = [&](int kt) {
    const ushort_t* src = vptr + (size_t)(kt * 64 + vj) * 3072 + w * 16;
    vr0 = *(const uint4*)src;
    vr1 = *(const uint4*)(src + 8);
  };
  auto writeV = [&](int buf) {
    char* dst = sm + 16384 + buf * 8192;
    ushort_t tmp[16];
    *(uint4*)tmp = vr0;
    *(uint4*)(tmp + 8) = vr1;
#pragma unroll
    for (int e = 0; e < 16; ++e) {
      const int dh = w * 16 + e;
      *(ushort_t*)(dst + dh * 128 + (vcol2 ^ ((dh & 7) << 4))) = tmp[e];
    }
  };

  stageK(0, 0);
  loadV(0);
  writeV(0);
  __syncthreads();
  int cur = 0;
  for (int kt = 0; kt <= qt; ++kt) {
    if (kt < qt) {  // issue next tile's loads EARLY
      stageK(cur ^ 1, kt + 1);
      loadV(kt + 1);
    }
    const char* Kf = sm + cur * 8192;
    const char* Vt = sm + 16384 + cur * 8192;
    f32x4 s[4];
    __builtin_amdgcn_s_setprio(1);
#pragma unroll
    for (int nt = 0; nt < 4; ++nt) {
      f32x4 z = {0.f, 0.f, 0.f, 0.f};
#pragma unroll
      for (int hh = 0; hh < 2; ++hh) {
        const short8 kf = *(const short8*)(Kf + (((hh * 4 + g) * 64 + nt * 16 + li) << 4));
        z = MFMA16(kf, qa[hh], z);
      }
      s[nt] = z;
    }
    __builtin_amdgcn_s_setprio(0);
    if (kt == qt) {
      const int qq = q0 + w * 16 + li;
#pragma unroll
      for (int nt = 0; nt < 4; ++nt)
#pragma unroll
        for (int r = 0; r < 4; ++r)
          if (kt * 64 + nt * 16 + g * 4 + r > qq) s[nt][r] = -INFINITY;
    }
    float pm = -INFINITY;
#pragma unroll
    for (int nt = 0; nt < 4; ++nt)
#pragma unroll
      for (int r = 0; r < 4; ++r) pm = fmaxf(pm, s[nt][r]);
    pm = fmaxf(pm, __shfl_xor(pm, 16));
    pm = fmaxf(pm, __shfl_xor(pm, 32));
    if (__any(pm > mr + 11.5f)) {
      const float nm = fmaxf(mr, pm);
      const float rs = fast_exp2(mr - nm);
      mr = nm;
      lr *= rs;
#pragma unroll
      for (int r = 0; r < 4; ++r) {
        const float rsb = __shfl(rs, sb + r);
#pragma unroll
        for (int dt = 0; dt < 4; ++dt) acc[dt][r] *= rsb;
      }
    }
    float ps = 0.f;
#pragma unroll
    for (int nt = 0; nt < 4; ++nt)
#pragma unroll
      for (int r = 0; r < 4; ++r) {
        s[nt][r] = fast_exp2(s[nt][r] - mr);
        ps += s[nt][r];
      }
    ps += __shfl_xor(ps, 16);
    ps += __shfl_xor(ps, 32);
    lr += ps;
    if (kt < qt) writeV(cur ^ 1);
    short8 pa[2];
#pragma unroll
    for (int m = 0; m < 2; ++m)
#pragma unroll
      for (int r = 0; r < 4; ++r) {
        pa[m][r] = (short)f2bf_trunc(s[2 * m][r]);
        pa[m][4 + r] = (short)f2bf_trunc(s[2 * m + 1][r]);
      }
    __builtin_amdgcn_s_setprio(1);
#pragma unroll
    for (int dt = 0; dt < 4; ++dt) {
      const int dh = dt * 16 + li;
#pragma unroll
      for (int m = 0; m < 2; ++m) {
        const short8 vb = *(const short8*)(Vt + dh * 128 + ((m * 64 + g * 16) ^ ((dh & 7) << 4)));
        acc[dt] = MFMA16(pa[m], vb, acc[dt]);
      }
    }
    __builtin_amdgcn_s_setprio(0);
    __syncthreads();
    cur ^= 1;
  }
#pragma unroll
  for (int r = 0; r < 4; ++r) {
    const float lrb = __shfl(lr, sb + r);
    const float inv = 1.f / lrb;
    const int row = rowb + q0 + w * 16 + g * 4 + r;
#pragma unroll
    for (int dt = 0; dt < 4; ++dt) {
      const int col = h * 64 + dt * 16 + li;
      ctx[(size_t)row * 1024 + col] = f2bf(acc[dt][r] * inv);
    }
  }
}

extern "C" void kernel_launch(void* const* d_in, const int* in_sizes, int n_in,
                              void* d_out, int out_size, void* d_ws, size_t ws_size,
                              hipStream_t stream) {
  const float* x = (const float*)d_in[0];
  const float* Wq = (const float*)d_in[1];
  const float* Wk = (const float*)d_in[2];
  const float* Wv = (const float*)d_in[3];
  const float* Wo = (const float*)d_in[4];
  const float* g1 = (const float*)d_in[5];
  const float* g2 = (const float*)d_in[6];
  const float* W1 = (const float*)d_in[7];
  const float* W2 = (const float*)d_in[8];
  const float* W3 = (const float*)d_in[9];
  float* out = (float*)d_out;

  char* wsb = (char*)d_ws;
  ushort_t* hb = (ushort_t*)(wsb);                   // 0..8 MiB
  ushort_t* qkv = (ushort_t*)(wsb + (8u << 20));     // 8..32 (dead after attn)
  ushort_t* ctx = (ushort_t*)(wsb + (32u << 20));    // 32..40 (dead after Wo)
  ushort_t* x1b = (ushort_t*)(wsb + (8u << 20));     // 8..40, overlays dead qkv+ctx
  ushort_t* wqkvT = (ushort_t*)(wsb + (72u << 20));  // 72..78
  ushort_t* woT = (ushort_t*)(wsb + (78u << 20));    // 78..80
  ushort_t* w13iT = (ushort_t*)(wsb + (80u << 20));  // 80..96 (interleaved W1|W3 fragments)
  ushort_t* w2T = (ushort_t*)(wsb + (96u << 20));    // 96..104

  // weight transpose+cast to bf16 [N][K]: the four 1024^2 in one launch,
  // W1/W3 interleaved fragments, W2 plain.
  transpose4_k<<<dim3(16, 16, 4), 256, 0, stream>>>(Wq, Wk, Wv, Wo, wqkvT,
                                                    wqkvT + 1024 * 1024,
                                                    wqkvT + 2 * 1024 * 1024, woT);
  transpose_cast_k<<<dim3(64, 16), 256, 0, stream>>>(W1, w13iT, 1024, 4096, 1);
  transpose_cast_k<<<dim3(64, 16), 256, 0, stream>>>(W3, w13iT, 1024, 4096, 2);
  transpose_cast_k<<<dim3(16, 64), 256, 0, stream>>>(W2, w2T, 4096, 1024, 0);

  // 1. h = rmsnorm(x, g1) -> bf16
  rmsnorm_k<<<4096, 256, 0, stream>>>(x, g1, hb);
  // 2. qkv = h @ [Wq|Wk|Wv]   (128^2 tile, 768 blocks = 3/CU)
  gemm_k<0><<<dim3(24, 32), 256, 0, stream>>>(hb, wqkvT, nullptr, qkv, 3072, 1024);
  // 3. RoPE on Q and K in one launch (Q scale = 1/sqrt(dh) * log2(e))
  rope_k<<<4096, 256, 0, stream>>>(qkv);
  // 4. ctx = causal flash attention (R14 structure)
  attn_k<<<dim3(32, 32), 256, 0, stream>>>(qkv, ctx);
  // 5. out1 = x + ctx @ Wo  (fp32)  — 8-wave 128^2 (same traffic, 2x waves/SIMD)
  gemm8w_k<1><<<dim3(8, 32), 512, 0, stream>>>(ctx, woT, x, out, 1024, 1024);
  // 6. h2 = rmsnorm(out1, g2) -> bf16
  rmsnorm_k<<<4096, 256, 0, stream>>>(out, g2, hb);
  // 7. x1 = silu(h2@W1) * (h2@W3)  — fused interleaved GEMM, phase-split ring pipeline
  gemm256_k<1><<<dim3(32, 16), 512, 0, stream>>>(hb, w13iT, x1b, 4096, 1024);
  // 8. out = out1 + x1 @ W2  — 8-wave 128^2 (same traffic, 2x waves/SIMD)
  gemm8w_k<1><<<dim3(8, 32), 512, 0, stream>>>(x1b, w2T, out, out, 1024, 4096);
}

// Round 22
// 372.560 us; speedup vs baseline: 1.0271x; 1.0271x over previous
//
#include <hip/hip_runtime.h>
#include <math.h>

typedef unsigned short ushort_t;
typedef __attribute__((ext_vector_type(8))) short short8;
typedef __attribute__((ext_vector_type(4))) float f32x4;

#define MFMA16(a, b, c) __builtin_amdgcn_mfma_f32_16x16x32_bf16((a), (b), (c), 0, 0, 0)

static __device__ __forceinline__ float fast_exp2(float x) {
#if __has_builtin(__builtin_amdgcn_exp2f)
  return __builtin_amdgcn_exp2f(x);
#else
  return exp2f(x);
#endif
}

static __device__ __forceinline__ ushort_t f2bf(float f) {
  unsigned int u = __float_as_uint(f);
  u = u + 0x7FFFu + ((u >> 16) & 1u);  // RTNE
  return (ushort_t)(u >> 16);
}
static __device__ __forceinline__ ushort_t f2bf_trunc(float f) {
  return (ushort_t)(__float_as_uint(f) >> 16);  // truncate: 1 op, fine for P in [0,1]
}
static __device__ __forceinline__ float bf2f(ushort_t s) {
  return __uint_as_float(((unsigned int)s) << 16);
}

// async global->LDS, 16B per lane. l_uniform: wave-uniform LDS base (lane*16 implicit).
static __device__ __forceinline__ void stage16(const ushort_t* g_perlane, char* l_uniform, int lane) {
#if __has_builtin(__builtin_amdgcn_global_load_lds)
  __builtin_amdgcn_global_load_lds((const __attribute__((address_space(1))) void*)g_perlane,
                                   (__attribute__((address_space(3))) void*)l_uniform, 16, 0, 0);
#else
  *(uint4*)(l_uniform + lane * 16) = *(const uint4*)g_perlane;
#endif
}

// ---------------- RMSNorm fp32 in -> bf16 out ----------------
__global__ __launch_bounds__(256) void rmsnorm_k(const float* __restrict__ x,
                                                 const float* __restrict__ g,
                                                 ushort_t* __restrict__ o) {
  const int r = blockIdx.x, t = threadIdx.x;
  const float4 xv = ((const float4*)(x + (size_t)r * 1024))[t];
  float ss = xv.x * xv.x + xv.y * xv.y + xv.z * xv.z + xv.w * xv.w;
#pragma unroll
  for (int m = 32; m >= 1; m >>= 1) ss += __shfl_xor(ss, m);
  __shared__ float wp[4];
  if ((t & 63) == 0) wp[t >> 6] = ss;
  __syncthreads();
  const float inv = rsqrtf((wp[0] + wp[1] + wp[2] + wp[3]) * (1.f / 1024.f) + 1e-5f);
  const float4 gv = ((const float4*)g)[t];
  ushort4 ov = {f2bf(xv.x * inv * gv.x), f2bf(xv.y * inv * gv.y),
                f2bf(xv.z * inv * gv.z), f2bf(xv.w * inv * gv.w)};
  *(ushort4*)(o + (size_t)r * 1024 + t * 4) = ov;
}

// ---------------- 4x fused 1024x1024 transpose+cast (Wq,Wk,Wv,Wo in one launch) ----------------
__global__ __launch_bounds__(256) void transpose4_k(const float* __restrict__ s0,
                                                    const float* __restrict__ s1,
                                                    const float* __restrict__ s2,
                                                    const float* __restrict__ s3,
                                                    ushort_t* __restrict__ d0,
                                                    ushort_t* __restrict__ d1,
                                                    ushort_t* __restrict__ d2,
                                                    ushort_t* __restrict__ d3) {
  const int z = blockIdx.z;
  const float* in = (z == 0) ? s0 : (z == 1) ? s1 : (z == 2) ? s2 : s3;
  ushort_t* out = (z == 0) ? d0 : (z == 1) ? d1 : (z == 2) ? d2 : d3;
  __shared__ ushort_t Ts[64][72];
  const int t = threadIdx.x;
  const int c0 = blockIdx.x * 64, r0 = blockIdx.y * 64;
  const int lr = t >> 4, lc = (t & 15) * 4;
#pragma unroll
  for (int i = 0; i < 4; ++i) {
    const float4 v = *(const float4*)&in[(size_t)(r0 + lr + i * 16) * 1024 + c0 + lc];
    Ts[lr + i * 16][lc + 0] = f2bf(v.x);
    Ts[lr + i * 16][lc + 1] = f2bf(v.y);
    Ts[lr + i * 16][lc + 2] = f2bf(v.z);
    Ts[lr + i * 16][lc + 3] = f2bf(v.w);
  }
  __syncthreads();
  const int rr = (t & 15) * 4;
#pragma unroll
  for (int i = 0; i < 4; ++i) {
    const int cc = (t >> 4) + i * 16;
    ushort4 o = {Ts[rr + 0][cc], Ts[rr + 1][cc], Ts[rr + 2][cc], Ts[rr + 3][cc]};
    *(ushort4*)&out[(size_t)(c0 + cc) * 1024 + r0 + rr] = o;
  }
}

// ---------------- 3x fused FFN-weight transpose+cast (W1,W3,W2 in one launch) ----------------
// z=0: W1 (1024x4096) -> w13iT interleaved mode1.  z=1: W3 -> w13iT mode2.
// z=2: W2 (4096x1024) -> w2T plain; its (16,64) grid is remapped from the (64,16) launch.
__global__ __launch_bounds__(256) void transpose3_k(const float* __restrict__ s0,
                                                    const float* __restrict__ s1,
                                                    const float* __restrict__ s2,
                                                    ushort_t* __restrict__ d01,
                                                    ushort_t* __restrict__ d2) {
  const int z = blockIdx.z;
  const float* in;
  ushort_t* out;
  int R, C, mode, c0, r0;
  if (z == 2) {
    in = s2; out = d2; R = 4096; C = 1024; mode = 0;
    const int flat = blockIdx.y * 64 + blockIdx.x;  // 0..1023
    c0 = (flat & 15) * 64;
    r0 = (flat >> 4) * 64;
  } else {
    in = (z == 0) ? s0 : s1; out = d01; R = 1024; C = 4096; mode = (z == 0) ? 1 : 2;
    c0 = blockIdx.x * 64;
    r0 = blockIdx.y * 64;
  }
  __shared__ ushort_t Ts[64][72];
  const int t = threadIdx.x;
  const int lr = t >> 4, lc = (t & 15) * 4;
#pragma unroll
  for (int i = 0; i < 4; ++i) {
    const float4 v = *(const float4*)&in[(size_t)(r0 + lr + i * 16) * C + c0 + lc];
    Ts[lr + i * 16][lc + 0] = f2bf(v.x);
    Ts[lr + i * 16][lc + 1] = f2bf(v.y);
    Ts[lr + i * 16][lc + 2] = f2bf(v.z);
    Ts[lr + i * 16][lc + 3] = f2bf(v.w);
  }
  __syncthreads();
  const int rr = (t & 15) * 4;
#pragma unroll
  for (int i = 0; i < 4; ++i) {
    const int cc = (t >> 4) + i * 16;
    const int cg = c0 + cc;
    int orow;
    if (mode == 0)
      orow = cg;
    else
      orow = ((cg >> 7) << 8) + (((cg >> 4) & 7) << 5) + (cg & 15) + (mode == 2 ? 16 : 0);
    ushort4 o = {Ts[rr + 0][cc], Ts[rr + 1][cc], Ts[rr + 2][cc], Ts[rr + 3][cc]};
    *(ushort4*)&out[(size_t)orow * R + r0 + rr] = o;
  }
}

// ---------------- RoPE in-place on bf16, ld=3072; Q and K in ONE launch ----------------
__global__ __launch_bounds__(256) void rope_k(ushort_t* __restrict__ qkv) {
  const int HALF = 4096 * 128;
  int idx = blockIdx.x * 256 + threadIdx.x;
  const int isK = idx >= HALF;
  idx &= HALF - 1;
  const float scale = isK ? 1.0f : 0.18033688011112042f;  // 0.125 * log2(e)
  const int row = idx >> 7, rem = idx & 127;
  const int head = rem >> 3, gq = rem & 7;
  const int i0 = gq * 4;
  const int s = row & 2047;
  ushort_t* p = qkv + (size_t)row * 3072 + isK * 1024 + head * 64 + i0 * 2;
  uint4 v = *(uint4*)p;
  ushort_t* e = (ushort_t*)&v;
#pragma unroll
  for (int k = 0; k < 4; ++k) {
    const float ang = (float)s * expf(-(float)(i0 + k) * 0.28782313662425572f);  // ln(1e4)/32
    float sn, cs;
    sincosf(ang, &sn, &cs);
    const float x1 = bf2f(e[2 * k]), x2 = bf2f(e[2 * k + 1]);
    e[2 * k] = f2bf((x1 * cs - x2 * sn) * scale);
    e[2 * k + 1] = f2bf((x2 * cs + x1 * sn) * scale);
  }
  *(uint4*)p = v;
}

// ---------------- 256x256-tile MFMA GEMM: BK=32, 4-slot ring, PHASE-SPLIT schedule ----------------
template <int FUSED>
__global__ __launch_bounds__(512, 2) void gemm256_k(const ushort_t* __restrict__ A,
                                                    const ushort_t* __restrict__ Bt,
                                                    ushort_t* __restrict__ C,
                                                    int N, int K) {
  __shared__ uint4 smem[131072 / 16];  // A: 4 x 16KB @0 ; B: 4 x 16KB @65536
  char* sm = (char*)smem;
  const int flat = blockIdx.y * gridDim.x + blockIdx.x;
  const int total = gridDim.x * gridDim.y;
  const int swz = (flat & 7) * (total >> 3) + (flat >> 3);
  const int bx = swz % gridDim.x, by = swz / gridDim.x;
  const int t = threadIdx.x, lane = t & 63, w = t >> 6;
  const int g = lane >> 4, li = lane & 15;
  const int wr = w >> 2, wc = w & 3;
  const int nr0 = bx * 256, m0 = by * 256;
  const int wb4 = (t & 448) << 4;  // wave base * 16
  const int srow = t & 255;
  const int sg0 = t >> 8;  // 0..1
  const size_t rowA = (size_t)(m0 + srow) * K;
  const size_t rowB = (size_t)(nr0 + srow) * K;
  f32x4 acc[8][4] = {};
  const int nkt = K >> 5;  // BK=32

  auto stageA = [&](int kt) {
    char* dA = sm + (kt & 3) * 16384;
    const int k0 = kt << 5;
#pragma unroll
    for (int c = 0; c < 2; ++c)
      stage16(A + rowA + k0 + (c * 2 + sg0) * 8, dA + ((c * 512) << 4) + wb4, lane);
  };
  auto stageB = [&](int kt) {
    char* dB = sm + 65536 + (kt & 3) * 16384;
    const int k0 = kt << 5;
#pragma unroll
    for (int c = 0; c < 2; ++c)
      stage16(Bt + rowB + k0 + (c * 2 + sg0) * 8, dB + ((c * 512) << 4) + wb4, lane);
  };

  stageA(0); stageB(0); stageA(1); stageB(1);       // 8 loads
  asm volatile("s_waitcnt vmcnt(4)" ::: "memory");  // tile0 forced; tile1 in flight
  __builtin_amdgcn_s_barrier();
  for (int kt = 0; kt < nkt; ++kt) {
    const char* sA = sm + (kt & 3) * 16384;
    const char* sB = sm + 65536 + (kt & 3) * 16384;
    const bool pf = (kt + 2 < nkt);
    // ---- phase 0: quadrant mi0-3 ----
    short8 af0[4], bfr[4];
#pragma unroll
    for (int mi = 0; mi < 4; ++mi)
      af0[mi] = *(const short8*)(sA + ((g * 256 + wr * 128 + mi * 16 + li) << 4));
#pragma unroll
    for (int ni = 0; ni < 4; ++ni)
      bfr[ni] = *(const short8*)(sB + ((g * 256 + wc * 64 + ni * 16 + li) << 4));
    if (pf) stageA(kt + 2);
    __builtin_amdgcn_s_barrier();
    __builtin_amdgcn_s_setprio(1);
#pragma unroll
    for (int mi = 0; mi < 4; ++mi)
#pragma unroll
      for (int ni = 0; ni < 4; ++ni) acc[mi][ni] = MFMA16(af0[mi], bfr[ni], acc[mi][ni]);
    __builtin_amdgcn_s_setprio(0);
    __builtin_amdgcn_s_barrier();
    // ---- phase 1: quadrant mi4-7 ----
    short8 af1[4];
#pragma unroll
    for (int mi = 0; mi < 4; ++mi)
      af1[mi] = *(const short8*)(sA + ((g * 256 + wr * 128 + (mi + 4) * 16 + li) << 4));
    if (pf) stageB(kt + 2);
    if (pf)
      asm volatile("s_waitcnt vmcnt(4)" ::: "memory");  // force tile kt+1; kt+2 stays in flight
    else if (kt + 1 < nkt)
      asm volatile("s_waitcnt vmcnt(0)" ::: "memory");  // tail: force last tile
    __builtin_amdgcn_s_barrier();
    __builtin_amdgcn_s_setprio(1);
#pragma unroll
    for (int mi = 0; mi < 4; ++mi)
#pragma unroll
      for (int ni = 0; ni < 4; ++ni) acc[mi + 4][ni] = MFMA16(af1[mi], bfr[ni], acc[mi + 4][ni]);
    __builtin_amdgcn_s_setprio(0);
    __builtin_amdgcn_s_barrier();
  }
  if (FUSED == 0) {
#pragma unroll
    for (int mi = 0; mi < 8; ++mi)
#pragma unroll
      for (int ni = 0; ni < 4; ++ni)
#pragma unroll
        for (int r = 0; r < 4; ++r) {
          const int row = m0 + wr * 128 + mi * 16 + g * 4 + r;
          const int col = nr0 + wc * 64 + ni * 16 + li;
          C[(size_t)row * N + col] = f2bf(acc[mi][ni][r]);
        }
  } else {
#pragma unroll
    for (int mi = 0; mi < 8; ++mi)
#pragma unroll
      for (int p = 0; p < 2; ++p)
#pragma unroll
        for (int r = 0; r < 4; ++r) {
          const float v1 = acc[mi][2 * p][r];
          const float v3 = acc[mi][2 * p + 1][r];
          const float o = v1 / (1.f + __expf(-v1)) * v3;
          const int row = m0 + wr * 128 + mi * 16 + g * 4 + r;
          const int col = bx * 128 + wc * 32 + p * 16 + li;
          C[(size_t)row * N + col] = f2bf(o);
        }
  }
}

// ---------------- 128x128-tile MFMA GEMM, 3-buffer counted-vmcnt pipeline ----------------
template <int MODE>
__global__ __launch_bounds__(256) void gemm_k(const ushort_t* __restrict__ A,
                                              const ushort_t* __restrict__ Bt,
                                              const float* __restrict__ R,
                                              void* __restrict__ C,
                                              int N, int K) {
  __shared__ uint4 smem[49152 / 16];  // 3 x (A 8KB @ buf*8192 | B 8KB @ 24576+buf*8192)
  char* sm = (char*)smem;
  const int flat = blockIdx.y * gridDim.x + blockIdx.x;
  const int total = gridDim.x * gridDim.y;
  const int swz = (flat & 7) * (total >> 3) + (flat >> 3);
  const int bx = swz % gridDim.x, by = swz / gridDim.x;
  const int t = threadIdx.x, lane = t & 63, w = t >> 6;
  const int g = lane >> 4, li = lane & 15;
  const int wr = w >> 1, wc = w & 1;
  const int n0 = bx * 128, m0 = by * 128;
  const int wb = t & 192;
  const int r0s = t & 127, g0s = (t >> 7) << 3;
  const size_t rowA = (size_t)(m0 + r0s) * K;
  const size_t rowB = (size_t)(n0 + r0s) * K;
  f32x4 acc[4][4] = {};
  const int nkt = K >> 5;

  auto stage_all = [&](int buf, int kt) {
    const int k0 = (kt << 5) + g0s;
    char* dA = sm + buf * 8192;
    char* dB = sm + 24576 + buf * 8192;
    stage16(A + rowA + k0, dA + (wb << 4), lane);
    stage16(A + rowA + k0 + 16, dA + ((256 + wb) << 4), lane);
    stage16(Bt + rowB + k0, dB + (wb << 4), lane);
    stage16(Bt + rowB + k0 + 16, dB + ((256 + wb) << 4), lane);
  };

  stage_all(0, 0);
  stage_all(1, 1);
  asm volatile("s_waitcnt vmcnt(4)" ::: "memory");  // buf0 landed; buf1 in flight
  __builtin_amdgcn_s_barrier();
  int b0 = 0;
  for (int kt = 0; kt < nkt; ++kt) {
    int bn = b0 + 2;
    if (bn >= 3) bn -= 3;
    if (kt + 2 < nkt) stage_all(bn, kt + 2);
    const char* smA = sm + b0 * 8192;
    const char* smB = sm + 24576 + b0 * 8192;
    short8 af[4], bfr[4];
#pragma unroll
    for (int mi = 0; mi < 4; ++mi)
      af[mi] = *(const short8*)(smA + ((g * 128 + wr * 64 + mi * 16 + li) << 4));
#pragma unroll
    for (int ni = 0; ni < 4; ++ni)
      bfr[ni] = *(const short8*)(smB + ((g * 128 + wc * 64 + ni * 16 + li) << 4));
    __builtin_amdgcn_s_setprio(1);
#pragma unroll
    for (int mi = 0; mi < 4; ++mi)
#pragma unroll
      for (int ni = 0; ni < 4; ++ni) acc[mi][ni] = MFMA16(af[mi], bfr[ni], acc[mi][ni]);
    __builtin_amdgcn_s_setprio(0);
    if (kt + 2 < nkt) {
      asm volatile("s_waitcnt vmcnt(4) lgkmcnt(0)" ::: "memory");  // kt+1 done, kt+2 in flight
      __builtin_amdgcn_s_barrier();
    } else if (kt + 1 < nkt) {
      asm volatile("s_waitcnt vmcnt(0) lgkmcnt(0)" ::: "memory");
      __builtin_amdgcn_s_barrier();
    }
    ++b0;
    if (b0 == 3) b0 = 0;
  }
#pragma unroll
  for (int mi = 0; mi < 4; ++mi)
#pragma unroll
    for (int ni = 0; ni < 4; ++ni)
#pragma unroll
      for (int r = 0; r < 4; ++r) {
        const int row = m0 + wr * 64 + mi * 16 + g * 4 + r;
        const int col = n0 + wc * 64 + ni * 16 + li;
        const float v = acc[mi][ni][r];
        if (MODE == 1)
          ((float*)C)[(size_t)row * N + col] = v + R[(size_t)row * N + col];
        else
          ((ushort_t*)C)[(size_t)row * N + col] = f2bf(v);
      }
}

// ---------------- Swapped-operand MFMA flash attention (causal) — R14-proven ----------------
__global__ __launch_bounds__(256) void attn_k(const ushort_t* __restrict__ qkv,
                                              ushort_t* __restrict__ ctx) {
  __shared__ uint4 smemv[32768 / 16];  // K0|K1 @0,8192 ; V0|V1 @16384,24576
  char* sm = (char*)smemv;
  const int qt = 31 - blockIdx.x;  // longest blocks dispatched first
  const int bh = blockIdx.y;
  const int b = bh >> 4, h = bh & 15;
  const int t = threadIdx.x, lane = t & 63, w = t >> 6;
  const int g = lane >> 4, li = lane & 15;
  const int rowb = b * 2048;
  const size_t qbase = (size_t)rowb * 3072 + h * 64;
  const int q0 = qt * 64;
  const ushort_t* kptr = qkv + qbase + 1024;
  const ushort_t* vptr = qkv + qbase + 2048;

  short8 qa[2];
  {
    const int qrow = q0 + w * 16 + li;
    qa[0] = *(const short8*)(qkv + qbase + (size_t)qrow * 3072 + 8 * g);
    qa[1] = *(const short8*)(qkv + qbase + (size_t)qrow * 3072 + 32 + 8 * g);
  }
  f32x4 acc[4] = {};
  float mr = -INFINITY, lr = 0.f;  // per-lane: q = li
  const int sb = g * 20;           // broadcast source base

  const int vj = t & 63;
  const int vcol2 = 2 * (((vj >> 5) << 5) + (((vj >> 2) & 3) << 3) + (((vj >> 4) & 1) << 2) + (vj & 3));

  uint4 vr0, vr1;  // in-flight V registers (T14)
  auto stageK = [&](int buf, int kt) {
    char* dst = sm + buf * 8192;
    const ushort_t* src = kptr + (size_t)kt * 64 * 3072 + (size_t)(t & 63) * 3072;
    stage16(src + (t >> 6) * 8, dst + ((t & 192) << 4), lane);
    stage16(src + ((t >> 6) + 4) * 8, dst + 4096 + ((t & 192) << 4), lane);
  };
  auto loadV = [&](int kt) {
    const ushort_t* src = vptr + (size_t)(kt * 64 + vj) * 3072 + w * 16;
    vr0 = *(const uint4*)src;
    vr1 = *(const uint4*)(src + 8);
  };
  auto writeV = [&](int buf) {
    char* dst = sm + 16384 + buf * 8192;
    ushort_t tmp[16];
    *(uint4*)tmp = vr0;
    *(uint4*)(tmp + 8) = vr1;
#pragma unroll
    for (int e = 0; e < 16; ++e) {
      const int dh = w * 16 + e;
      *(ushort_t*)(dst + dh * 128 + (vcol2 ^ ((dh & 7) << 4))) = tmp[e];
    }
  };

  stageK(0, 0);
  loadV(0);
  writeV(0);
  __syncthreads();
  int cur = 0;
  for (int kt = 0; kt <= qt; ++kt) {
    if (kt < qt) {  // issue next tile's loads EARLY
      stageK(cur ^ 1, kt + 1);
      loadV(kt + 1);
    }
    const char* Kf = sm + cur * 8192;
    const char* Vt = sm + 16384 + cur * 8192;
    f32x4 s[4];
    __builtin_amdgcn_s_setprio(1);
#pragma unroll
    for (int nt = 0; nt < 4; ++nt) {
      f32x4 z = {0.f, 0.f, 0.f, 0.f};
#pragma unroll
      for (int hh = 0; hh < 2; ++hh) {
        const short8 kf = *(const short8*)(Kf + (((hh * 4 + g) * 64 + nt * 16 + li) << 4));
        z = MFMA16(kf, qa[hh], z);
      }
      s[nt] = z;
    }
    __builtin_amdgcn_s_setprio(0);
    if (kt == qt) {
      const int qq = q0 + w * 16 + li;
#pragma unroll
      for (int nt = 0; nt < 4; ++nt)
#pragma unroll
        for (int r = 0; r < 4; ++r)
          if (kt * 64 + nt * 16 + g * 4 + r > qq) s[nt][r] = -INFINITY;
    }
    float pm = -INFINITY;
#pragma unroll
    for (int nt = 0; nt < 4; ++nt)
#pragma unroll
      for (int r = 0; r < 4; ++r) pm = fmaxf(pm, s[nt][r]);
    pm = fmaxf(pm, __shfl_xor(pm, 16));
    pm = fmaxf(pm, __shfl_xor(pm, 32));
    if (__any(pm > mr + 11.5f)) {
      const float nm = fmaxf(mr, pm);
      const float rs = fast_exp2(mr - nm);
      mr = nm;
      lr *= rs;
#pragma unroll
      for (int r = 0; r < 4; ++r) {
        const float rsb = __shfl(rs, sb + r);
#pragma unroll
        for (int dt = 0; dt < 4; ++dt) acc[dt][r] *= rsb;
      }
    }
    float ps = 0.f;
#pragma unroll
    for (int nt = 0; nt < 4; ++nt)
#pragma unroll
      for (int r = 0; r < 4; ++r) {
        s[nt][r] = fast_exp2(s[nt][r] - mr);
        ps += s[nt][r];
      }
    ps += __shfl_xor(ps, 16);
    ps += __shfl_xor(ps, 32);
    lr += ps;
    if (kt < qt) writeV(cur ^ 1);
    short8 pa[2];
#pragma unroll
    for (int m = 0; m < 2; ++m)
#pragma unroll
      for (int r = 0; r < 4; ++r) {
        pa[m][r] = (short)f2bf_trunc(s[2 * m][r]);
        pa[m][4 + r] = (short)f2bf_trunc(s[2 * m + 1][r]);
      }
    __builtin_amdgcn_s_setprio(1);
#pragma unroll
    for (int dt = 0; dt < 4; ++dt) {
      const int dh = dt * 16 + li;
#pragma unroll
      for (int m = 0; m < 2; ++m) {
        const short8 vb = *(const short8*)(Vt + dh * 128 + ((m * 64 + g * 16) ^ ((dh & 7) << 4)));
        acc[dt] = MFMA16(pa[m], vb, acc[dt]);
      }
    }
    __builtin_amdgcn_s_setprio(0);
    __syncthreads();
    cur ^= 1;
  }
#pragma unroll
  for (int r = 0; r < 4; ++r) {
    const float lrb = __shfl(lr, sb + r);
    const float inv = 1.f / lrb;
    const int row = rowb + q0 + w * 16 + g * 4 + r;
#pragma unroll
    for (int dt = 0; dt < 4; ++dt) {
      const int col = h * 64 + dt * 16 + li;
      ctx[(size_t)row * 1024 + col] = f2bf(acc[dt][r] * inv);
    }
  }
}

extern "C" void kernel_launch(void* const* d_in, const int* in_sizes, int n_in,
                              void* d_out, int out_size, void* d_ws, size_t ws_size,
                              hipStream_t stream) {
  const float* x = (const float*)d_in[0];
  const float* Wq = (const float*)d_in[1];
  const float* Wk = (const float*)d_in[2];
  const float* Wv = (const float*)d_in[3];
  const float* Wo = (const float*)d_in[4];
  const float* g1 = (const float*)d_in[5];
  const float* g2 = (const float*)d_in[6];
  const float* W1 = (const float*)d_in[7];
  const float* W2 = (const float*)d_in[8];
  const float* W3 = (const float*)d_in[9];
  float* out = (float*)d_out;

  char* wsb = (char*)d_ws;
  ushort_t* hb = (ushort_t*)(wsb);                   // 0..8 MiB
  ushort_t* qkv = (ushort_t*)(wsb + (8u << 20));     // 8..32 (dead after attn)
  ushort_t* ctx = (ushort_t*)(wsb + (32u << 20));    // 32..40 (dead after Wo)
  ushort_t* x1b = (ushort_t*)(wsb + (8u << 20));     // 8..40, overlays dead qkv+ctx
  ushort_t* wqkvT = (ushort_t*)(wsb + (72u << 20));  // 72..78
  ushort_t* woT = (ushort_t*)(wsb + (78u << 20));    // 78..80
  ushort_t* w13iT = (ushort_t*)(wsb + (80u << 20));  // 80..96 (interleaved W1|W3 fragments)
  ushort_t* w2T = (ushort_t*)(wsb + (96u << 20));    // 96..104

  // weight transpose+cast to bf16 [N][K]: four 1024^2 in one launch; W1/W3/W2 in one launch.
  transpose4_k<<<dim3(16, 16, 4), 256, 0, stream>>>(Wq, Wk, Wv, Wo, wqkvT,
                                                    wqkvT + 1024 * 1024,
                                                    wqkvT + 2 * 1024 * 1024, woT);
  transpose3_k<<<dim3(64, 16, 3), 256, 0, stream>>>(W1, W3, W2, w13iT, w2T);

  // 1. h = rmsnorm(x, g1) -> bf16
  rmsnorm_k<<<4096, 256, 0, stream>>>(x, g1, hb);
  // 2. qkv = h @ [Wq|Wk|Wv]   (128^2 tile, 768 blocks = 3/CU)
  gemm_k<0><<<dim3(24, 32), 256, 0, stream>>>(hb, wqkvT, nullptr, qkv, 3072, 1024);
  // 3. RoPE on Q and K in one launch (Q scale = 1/sqrt(dh) * log2(e))
  rope_k<<<4096, 256, 0, stream>>>(qkv);
  // 4. ctx = causal flash attention (R14 structure)
  attn_k<<<dim3(32, 32), 256, 0, stream>>>(qkv, ctx);
  // 5. out1 = x + ctx @ Wo  (fp32)
  gemm_k<1><<<dim3(8, 32), 256, 0, stream>>>(ctx, woT, x, out, 1024, 1024);
  // 6. h2 = rmsnorm(out1, g2) -> bf16
  rmsnorm_k<<<4096, 256, 0, stream>>>(out, g2, hb);
  // 7. x1 = silu(h2@W1) * (h2@W3)  — fused interleaved GEMM, phase-split ring pipeline
  gemm256_k<1><<<dim3(32, 16), 512, 0, stream>>>(hb, w13iT, x1b, 4096, 1024);
  // 8. out = out1 + x1 @ W2  (proven 128^2 3-buffer pipeline)
  gemm_k<1><<<dim3(8, 32), 256, 0, stream>>>(x1b, w2T, out, out, 1024, 4096);
}

// Round 23
// 339.740 us; speedup vs baseline: 1.1263x; 1.0966x over previous
//
#include <hip/hip_runtime.h>
#include <math.h>

typedef unsigned short ushort_t;
typedef __attribute__((ext_vector_type(8))) short short8;
typedef __attribute__((ext_vector_type(4))) float f32x4;

#define MFMA16(a, b, c) __builtin_amdgcn_mfma_f32_16x16x32_bf16((a), (b), (c), 0, 0, 0)

static __device__ __forceinline__ float fast_exp2(float x) {
#if __has_builtin(__builtin_amdgcn_exp2f)
  return __builtin_amdgcn_exp2f(x);
#else
  return exp2f(x);
#endif
}

static __device__ __forceinline__ ushort_t f2bf(float f) {
  unsigned int u = __float_as_uint(f);
  u = u + 0x7FFFu + ((u >> 16) & 1u);  // RTNE
  return (ushort_t)(u >> 16);
}
static __device__ __forceinline__ ushort_t f2bf_trunc(float f) {
  return (ushort_t)(__float_as_uint(f) >> 16);  // truncate: 1 op, fine for P in [0,1]
}
static __device__ __forceinline__ float bf2f(ushort_t s) {
  return __uint_as_float(((unsigned int)s) << 16);
}

// async global->LDS, 16B per lane. l_uniform: wave-uniform LDS base (lane*16 implicit).
static __device__ __forceinline__ void stage16(const ushort_t* g_perlane, char* l_uniform, int lane) {
#if __has_builtin(__builtin_amdgcn_global_load_lds)
  __builtin_amdgcn_global_load_lds((const __attribute__((address_space(1))) void*)g_perlane,
                                   (__attribute__((address_space(3))) void*)l_uniform, 16, 0, 0);
#else
  *(uint4*)(l_uniform + lane * 16) = *(const uint4*)g_perlane;
#endif
}

// ---------------- RMSNorm fp32 in -> bf16 out ----------------
__global__ __launch_bounds__(256) void rmsnorm_k(const float* __restrict__ x,
                                                 const float* __restrict__ g,
                                                 ushort_t* __restrict__ o) {
  const int r = blockIdx.x, t = threadIdx.x;
  const float4 xv = ((const float4*)(x + (size_t)r * 1024))[t];
  float ss = xv.x * xv.x + xv.y * xv.y + xv.z * xv.z + xv.w * xv.w;
#pragma unroll
  for (int m = 32; m >= 1; m >>= 1) ss += __shfl_xor(ss, m);
  __shared__ float wp[4];
  if ((t & 63) == 0) wp[t >> 6] = ss;
  __syncthreads();
  const float inv = rsqrtf((wp[0] + wp[1] + wp[2] + wp[3]) * (1.f / 1024.f) + 1e-5f);
  const float4 gv = ((const float4*)g)[t];
  ushort4 ov = {f2bf(xv.x * inv * gv.x), f2bf(xv.y * inv * gv.y),
                f2bf(xv.z * inv * gv.z), f2bf(xv.w * inv * gv.w)};
  *(ushort4*)(o + (size_t)r * 1024 + t * 4) = ov;
}

// ---------------- 4x fused 1024x1024 transpose+cast (Wq,Wk,Wv,Wo in one launch) ----------------
__global__ __launch_bounds__(256) void transpose4_k(const float* __restrict__ s0,
                                                    const float* __restrict__ s1,
                                                    const float* __restrict__ s2,
                                                    const float* __restrict__ s3,
                                                    ushort_t* __restrict__ d0,
                                                    ushort_t* __restrict__ d1,
                                                    ushort_t* __restrict__ d2,
                                                    ushort_t* __restrict__ d3) {
  const int z = blockIdx.z;
  const float* in = (z == 0) ? s0 : (z == 1) ? s1 : (z == 2) ? s2 : s3;
  ushort_t* out = (z == 0) ? d0 : (z == 1) ? d1 : (z == 2) ? d2 : d3;
  __shared__ ushort_t Ts[64][72];
  const int t = threadIdx.x;
  const int c0 = blockIdx.x * 64, r0 = blockIdx.y * 64;
  const int lr = t >> 4, lc = (t & 15) * 4;
#pragma unroll
  for (int i = 0; i < 4; ++i) {
    const float4 v = *(const float4*)&in[(size_t)(r0 + lr + i * 16) * 1024 + c0 + lc];
    Ts[lr + i * 16][lc + 0] = f2bf(v.x);
    Ts[lr + i * 16][lc + 1] = f2bf(v.y);
    Ts[lr + i * 16][lc + 2] = f2bf(v.z);
    Ts[lr + i * 16][lc + 3] = f2bf(v.w);
  }
  __syncthreads();
  const int rr = (t & 15) * 4;
#pragma unroll
  for (int i = 0; i < 4; ++i) {
    const int cc = (t >> 4) + i * 16;
    ushort4 o = {Ts[rr + 0][cc], Ts[rr + 1][cc], Ts[rr + 2][cc], Ts[rr + 3][cc]};
    *(ushort4*)&out[(size_t)(c0 + cc) * 1024 + r0 + rr] = o;
  }
}

// ---------------- 3x fused FFN-weight transpose+cast (W1,W3,W2 in one launch) ----------------
__global__ __launch_bounds__(256) void transpose3_k(const float* __restrict__ s0,
                                                    const float* __restrict__ s1,
                                                    const float* __restrict__ s2,
                                                    ushort_t* __restrict__ d01,
                                                    ushort_t* __restrict__ d2) {
  const int z = blockIdx.z;
  const float* in;
  ushort_t* out;
  int R, C, mode, c0, r0;
  if (z == 2) {
    in = s2; out = d2; R = 4096; C = 1024; mode = 0;
    const int flat = blockIdx.y * 64 + blockIdx.x;  // 0..1023
    c0 = (flat & 15) * 64;
    r0 = (flat >> 4) * 64;
  } else {
    in = (z == 0) ? s0 : s1; out = d01; R = 1024; C = 4096; mode = (z == 0) ? 1 : 2;
    c0 = blockIdx.x * 64;
    r0 = blockIdx.y * 64;
  }
  __shared__ ushort_t Ts[64][72];
  const int t = threadIdx.x;
  const int lr = t >> 4, lc = (t & 15) * 4;
#pragma unroll
  for (int i = 0; i < 4; ++i) {
    const float4 v = *(const float4*)&in[(size_t)(r0 + lr + i * 16) * C + c0 + lc];
    Ts[lr + i * 16][lc + 0] = f2bf(v.x);
    Ts[lr + i * 16][lc + 1] = f2bf(v.y);
    Ts[lr + i * 16][lc + 2] = f2bf(v.z);
    Ts[lr + i * 16][lc + 3] = f2bf(v.w);
  }
  __syncthreads();
  const int rr = (t & 15) * 4;
#pragma unroll
  for (int i = 0; i < 4; ++i) {
    const int cc = (t >> 4) + i * 16;
    const int cg = c0 + cc;
    int orow;
    if (mode == 0)
      orow = cg;
    else
      orow = ((cg >> 7) << 8) + (((cg >> 4) & 7) << 5) + (cg & 15) + (mode == 2 ? 16 : 0);
    ushort4 o = {Ts[rr + 0][cc], Ts[rr + 1][cc], Ts[rr + 2][cc], Ts[rr + 3][cc]};
    *(ushort4*)&out[(size_t)orow * R + r0 + rr] = o;
  }
}

// ---------------- RoPE in-place on bf16, ld=3072; Q and K in ONE launch ----------------
__global__ __launch_bounds__(256) void rope_k(ushort_t* __restrict__ qkv) {
  const int HALF = 4096 * 128;
  int idx = blockIdx.x * 256 + threadIdx.x;
  const int isK = idx >= HALF;
  idx &= HALF - 1;
  const float scale = isK ? 1.0f : 0.18033688011112042f;  // 0.125 * log2(e)
  const int row = idx >> 7, rem = idx & 127;
  const int head = rem >> 3, gq = rem & 7;
  const int i0 = gq * 4;
  const int s = row & 2047;
  ushort_t* p = qkv + (size_t)row * 3072 + isK * 1024 + head * 64 + i0 * 2;
  uint4 v = *(uint4*)p;
  ushort_t* e = (ushort_t*)&v;
#pragma unroll
  for (int k = 0; k < 4; ++k) {
    const float ang = (float)s * expf(-(float)(i0 + k) * 0.28782313662425572f);  // ln(1e4)/32
    float sn, cs;
    sincosf(ang, &sn, &cs);
    const float x1 = bf2f(e[2 * k]), x2 = bf2f(e[2 * k + 1]);
    e[2 * k] = f2bf((x1 * cs - x2 * sn) * scale);
    e[2 * k + 1] = f2bf((x2 * cs + x1 * sn) * scale);
  }
  *(uint4*)p = v;
}

// ---------------- 256x256-tile MFMA GEMM: BK=32, 4-slot ring, PHASE-SPLIT schedule ----------------
template <int FUSED>
__global__ __launch_bounds__(512, 2) void gemm256_k(const ushort_t* __restrict__ A,
                                                    const ushort_t* __restrict__ Bt,
                                                    ushort_t* __restrict__ C,
                                                    int N, int K) {
  __shared__ uint4 smem[131072 / 16];  // A: 4 x 16KB @0 ; B: 4 x 16KB @65536
  char* sm = (char*)smem;
  const int flat = blockIdx.y * gridDim.x + blockIdx.x;
  const int total = gridDim.x * gridDim.y;
  const int swz = (flat & 7) * (total >> 3) + (flat >> 3);
  const int bx = swz % gridDim.x, by = swz / gridDim.x;
  const int t = threadIdx.x, lane = t & 63, w = t >> 6;
  const int g = lane >> 4, li = lane & 15;
  const int wr = w >> 2, wc = w & 3;
  const int nr0 = bx * 256, m0 = by * 256;
  const int wb4 = (t & 448) << 4;  // wave base * 16
  const int srow = t & 255;
  const int sg0 = t >> 8;  // 0..1
  const size_t rowA = (size_t)(m0 + srow) * K;
  const size_t rowB = (size_t)(nr0 + srow) * K;
  f32x4 acc[8][4] = {};
  const int nkt = K >> 5;  // BK=32

  auto stageA = [&](int kt) {
    char* dA = sm + (kt & 3) * 16384;
    const int k0 = kt << 5;
#pragma unroll
    for (int c = 0; c < 2; ++c)
      stage16(A + rowA + k0 + (c * 2 + sg0) * 8, dA + ((c * 512) << 4) + wb4, lane);
  };
  auto stageB = [&](int kt) {
    char* dB = sm + 65536 + (kt & 3) * 16384;
    const int k0 = kt << 5;
#pragma unroll
    for (int c = 0; c < 2; ++c)
      stage16(Bt + rowB + k0 + (c * 2 + sg0) * 8, dB + ((c * 512) << 4) + wb4, lane);
  };

  stageA(0); stageB(0); stageA(1); stageB(1);       // 8 loads
  asm volatile("s_waitcnt vmcnt(4)" ::: "memory");  // tile0 forced; tile1 in flight
  __builtin_amdgcn_s_barrier();
  for (int kt = 0; kt < nkt; ++kt) {
    const char* sA = sm + (kt & 3) * 16384;
    const char* sB = sm + 65536 + (kt & 3) * 16384;
    const bool pf = (kt + 2 < nkt);
    // ---- phase 0: quadrant mi0-3 ----
    short8 af0[4], bfr[4];
#pragma unroll
    for (int mi = 0; mi < 4; ++mi)
      af0[mi] = *(const short8*)(sA + ((g * 256 + wr * 128 + mi * 16 + li) << 4));
#pragma unroll
    for (int ni = 0; ni < 4; ++ni)
      bfr[ni] = *(const short8*)(sB + ((g * 256 + wc * 64 + ni * 16 + li) << 4));
    if (pf) stageA(kt + 2);
    __builtin_amdgcn_s_barrier();
    __builtin_amdgcn_s_setprio(1);
#pragma unroll
    for (int mi = 0; mi < 4; ++mi)
#pragma unroll
      for (int ni = 0; ni < 4; ++ni) acc[mi][ni] = MFMA16(af0[mi], bfr[ni], acc[mi][ni]);
    __builtin_amdgcn_s_setprio(0);
    __builtin_amdgcn_s_barrier();
    // ---- phase 1: quadrant mi4-7 ----
    short8 af1[4];
#pragma unroll
    for (int mi = 0; mi < 4; ++mi)
      af1[mi] = *(const short8*)(sA + ((g * 256 + wr * 128 + (mi + 4) * 16 + li) << 4));
    if (pf) stageB(kt + 2);
    if (pf)
      asm volatile("s_waitcnt vmcnt(4)" ::: "memory");  // force tile kt+1; kt+2 stays in flight
    else if (kt + 1 < nkt)
      asm volatile("s_waitcnt vmcnt(0)" ::: "memory");  // tail: force last tile
    __builtin_amdgcn_s_barrier();
    __builtin_amdgcn_s_setprio(1);
#pragma unroll
    for (int mi = 0; mi < 4; ++mi)
#pragma unroll
      for (int ni = 0; ni < 4; ++ni) acc[mi + 4][ni] = MFMA16(af1[mi], bfr[ni], acc[mi + 4][ni]);
    __builtin_amdgcn_s_setprio(0);
    __builtin_amdgcn_s_barrier();
  }
  if (FUSED == 0) {
#pragma unroll
    for (int mi = 0; mi < 8; ++mi)
#pragma unroll
      for (int ni = 0; ni < 4; ++ni)
#pragma unroll
        for (int r = 0; r < 4; ++r) {
          const int row = m0 + wr * 128 + mi * 16 + g * 4 + r;
          const int col = nr0 + wc * 64 + ni * 16 + li;
          C[(size_t)row * N + col] = f2bf(acc[mi][ni][r]);
        }
  } else {
#pragma unroll
    for (int mi = 0; mi < 8; ++mi)
#pragma unroll
      for (int p = 0; p < 2; ++p)
#pragma unroll
        for (int r = 0; r < 4; ++r) {
          const float v1 = acc[mi][2 * p][r];
          const float v3 = acc[mi][2 * p + 1][r];
          const float o = v1 / (1.f + __expf(-v1)) * v3;
          const int row = m0 + wr * 128 + mi * 16 + g * 4 + r;
          const int col = bx * 128 + wc * 32 + p * 16 + li;
          C[(size_t)row * N + col] = f2bf(o);
        }
  }
}

// ---------------- 128x128-tile MFMA GEMM, 3-buffer counted-vmcnt pipeline ----------------
template <int MODE>
__global__ __launch_bounds__(256) void gemm_k(const ushort_t* __restrict__ A,
                                              const ushort_t* __restrict__ Bt,
                                              const float* __restrict__ R,
                                              void* __restrict__ C,
                                              int N, int K) {
  __shared__ uint4 smem[49152 / 16];  // 3 x (A 8KB @ buf*8192 | B 8KB @ 24576+buf*8192)
  char* sm = (char*)smem;
  const int flat = blockIdx.y * gridDim.x + blockIdx.x;
  const int total = gridDim.x * gridDim.y;
  const int swz = (flat & 7) * (total >> 3) + (flat >> 3);
  const int bx = swz % gridDim.x, by = swz / gridDim.x;
  const int t = threadIdx.x, lane = t & 63, w = t >> 6;
  const int g = lane >> 4, li = lane & 15;
  const int wr = w >> 1, wc = w & 1;
  const int n0 = bx * 128, m0 = by * 128;
  const int wb = t & 192;
  const int r0s = t & 127, g0s = (t >> 7) << 3;
  const size_t rowA = (size_t)(m0 + r0s) * K;
  const size_t rowB = (size_t)(n0 + r0s) * K;
  f32x4 acc[4][4] = {};
  const int nkt = K >> 5;

  auto stage_all = [&](int buf, int kt) {
    const int k0 = (kt << 5) + g0s;
    char* dA = sm + buf * 8192;
    char* dB = sm + 24576 + buf * 8192;
    stage16(A + rowA + k0, dA + (wb << 4), lane);
    stage16(A + rowA + k0 + 16, dA + ((256 + wb) << 4), lane);
    stage16(Bt + rowB + k0, dB + (wb << 4), lane);
    stage16(Bt + rowB + k0 + 16, dB + ((256 + wb) << 4), lane);
  };

  stage_all(0, 0);
  stage_all(1, 1);
  asm volatile("s_waitcnt vmcnt(4)" ::: "memory");  // buf0 landed; buf1 in flight
  __builtin_amdgcn_s_barrier();
  int b0 = 0;
  for (int kt = 0; kt < nkt; ++kt) {
    int bn = b0 + 2;
    if (bn >= 3) bn -= 3;
    if (kt + 2 < nkt) stage_all(bn, kt + 2);
    const char* smA = sm + b0 * 8192;
    const char* smB = sm + 24576 + b0 * 8192;
    short8 af[4], bfr[4];
#pragma unroll
    for (int mi = 0; mi < 4; ++mi)
      af[mi] = *(const short8*)(smA + ((g * 128 + wr * 64 + mi * 16 + li) << 4));
#pragma unroll
    for (int ni = 0; ni < 4; ++ni)
      bfr[ni] = *(const short8*)(smB + ((g * 128 + wc * 64 + ni * 16 + li) << 4));
    __builtin_amdgcn_s_setprio(1);
#pragma unroll
    for (int mi = 0; mi < 4; ++mi)
#pragma unroll
      for (int ni = 0; ni < 4; ++ni) acc[mi][ni] = MFMA16(af[mi], bfr[ni], acc[mi][ni]);
    __builtin_amdgcn_s_setprio(0);
    if (kt + 2 < nkt) {
      asm volatile("s_waitcnt vmcnt(4) lgkmcnt(0)" ::: "memory");  // kt+1 done, kt+2 in flight
      __builtin_amdgcn_s_barrier();
    } else if (kt + 1 < nkt) {
      asm volatile("s_waitcnt vmcnt(0) lgkmcnt(0)" ::: "memory");
      __builtin_amdgcn_s_barrier();
    }
    ++b0;
    if (b0 == 3) b0 = 0;
  }
#pragma unroll
  for (int mi = 0; mi < 4; ++mi)
#pragma unroll
    for (int ni = 0; ni < 4; ++ni)
#pragma unroll
      for (int r = 0; r < 4; ++r) {
        const int row = m0 + wr * 64 + mi * 16 + g * 4 + r;
        const int col = n0 + wc * 64 + ni * 16 + li;
        const float v = acc[mi][ni][r];
        if (MODE == 1)
          ((float*)C)[(size_t)row * N + col] = v + R[(size_t)row * N + col];
        else
          ((ushort_t*)C)[(size_t)row * N + col] = f2bf(v);
      }
}

// ---------------- Swapped-operand MFMA flash attention (causal), WORK-BALANCED PAIRS ----------
// grid (16, 32): block bx processes q-tiles {31-bx, bx} -> every block exactly 33 K-tiles.
// 512 equal blocks = 2/CU, 8 waves/CU CONSTANT (no triangular tail). Body = R14-proven.
__global__ __launch_bounds__(256) void attn_k(const ushort_t* __restrict__ qkv,
                                              ushort_t* __restrict__ ctx) {
  __shared__ uint4 smemv[32768 / 16];  // K0|K1 @0,8192 ; V0|V1 @16384,24576
  char* sm = (char*)smemv;
  const int bh = blockIdx.y;
  const int b = bh >> 4, h = bh & 15;
  const int t = threadIdx.x, lane = t & 63, w = t >> 6;
  const int g = lane >> 4, li = lane & 15;
  const int rowb = b * 2048;
  const size_t qbase = (size_t)rowb * 3072 + h * 64;
  const ushort_t* kptr = qkv + qbase + 1024;
  const ushort_t* vptr = qkv + qbase + 2048;
  const int sb = g * 20;  // broadcast source base: lane sb+r has li == g*4+r

  const int vj = t & 63;
  const int vcol2 = 2 * (((vj >> 5) << 5) + (((vj >> 2) & 3) << 3) + (((vj >> 4) & 1) << 2) + (vj & 3));

  uint4 vr0, vr1;  // in-flight V registers (T14)
  auto stageK = [&](int buf, int kt) {
    char* dst = sm + buf * 8192;
    const ushort_t* src = kptr + (size_t)kt * 64 * 3072 + (size_t)(t & 63) * 3072;
    stage16(src + (t >> 6) * 8, dst + ((t & 192) << 4), lane);
    stage16(src + ((t >> 6) + 4) * 8, dst + 4096 + ((t & 192) << 4), lane);
  };
  auto loadV = [&](int kt) {
    const ushort_t* src = vptr + (size_t)(kt * 64 + vj) * 3072 + w * 16;
    vr0 = *(const uint4*)src;
    vr1 = *(const uint4*)(src + 8);
  };
  auto writeV = [&](int buf) {
    char* dst = sm + 16384 + buf * 8192;
    ushort_t tmp[16];
    *(uint4*)tmp = vr0;
    *(uint4*)(tmp + 8) = vr1;
#pragma unroll
    for (int e = 0; e < 16; ++e) {
      const int dh = w * 16 + e;
      *(ushort_t*)(dst + dh * 128 + (vcol2 ^ ((dh & 7) << 4))) = tmp[e];
    }
  };

  for (int hv = 0; hv < 2; ++hv) {
    const int qt = (hv == 0) ? (31 - (int)blockIdx.x) : (int)blockIdx.x;  // long half first
    const int q0 = qt * 64;

    short8 qa[2];
    {
      const int qrow = q0 + w * 16 + li;
      qa[0] = *(const short8*)(qkv + qbase + (size_t)qrow * 3072 + 8 * g);
      qa[1] = *(const short8*)(qkv + qbase + (size_t)qrow * 3072 + 32 + 8 * g);
    }
    f32x4 acc[4] = {};
    float mr = -INFINITY, lr = 0.f;  // per-lane: q = li

    stageK(0, 0);
    loadV(0);
    writeV(0);
    __syncthreads();
    int cur = 0;
    for (int kt = 0; kt <= qt; ++kt) {
      if (kt < qt) {  // issue next tile's loads EARLY
        stageK(cur ^ 1, kt + 1);
        loadV(kt + 1);
      }
      const char* Kf = sm + cur * 8192;
      const char* Vt = sm + 16384 + cur * 8192;
      f32x4 s[4];
      __builtin_amdgcn_s_setprio(1);
#pragma unroll
      for (int nt = 0; nt < 4; ++nt) {
        f32x4 z = {0.f, 0.f, 0.f, 0.f};
#pragma unroll
        for (int hh = 0; hh < 2; ++hh) {
          const short8 kf = *(const short8*)(Kf + (((hh * 4 + g) * 64 + nt * 16 + li) << 4));
          z = MFMA16(kf, qa[hh], z);
        }
        s[nt] = z;
      }
      __builtin_amdgcn_s_setprio(0);
      if (kt == qt) {  // causal mask on diagonal tile
        const int qq = q0 + w * 16 + li;
#pragma unroll
        for (int nt = 0; nt < 4; ++nt)
#pragma unroll
          for (int r = 0; r < 4; ++r)
            if (kt * 64 + nt * 16 + g * 4 + r > qq) s[nt][r] = -INFINITY;
      }
      float pm = -INFINITY;
#pragma unroll
      for (int nt = 0; nt < 4; ++nt)
#pragma unroll
        for (int r = 0; r < 4; ++r) pm = fmaxf(pm, s[nt][r]);
      pm = fmaxf(pm, __shfl_xor(pm, 16));
      pm = fmaxf(pm, __shfl_xor(pm, 32));
      if (__any(pm > mr + 11.5f)) {
        const float nm = fmaxf(mr, pm);
        const float rs = fast_exp2(mr - nm);
        mr = nm;
        lr *= rs;
#pragma unroll
        for (int r = 0; r < 4; ++r) {
          const float rsb = __shfl(rs, sb + r);
#pragma unroll
          for (int dt = 0; dt < 4; ++dt) acc[dt][r] *= rsb;
        }
      }
      float ps = 0.f;
#pragma unroll
      for (int nt = 0; nt < 4; ++nt)
#pragma unroll
        for (int r = 0; r < 4; ++r) {
          s[nt][r] = fast_exp2(s[nt][r] - mr);
          ps += s[nt][r];
        }
      ps += __shfl_xor(ps, 16);
      ps += __shfl_xor(ps, 32);
      lr += ps;
      if (kt < qt) writeV(cur ^ 1);
      short8 pa[2];
#pragma unroll
      for (int m = 0; m < 2; ++m)
#pragma unroll
        for (int r = 0; r < 4; ++r) {
          pa[m][r] = (short)f2bf_trunc(s[2 * m][r]);
          pa[m][4 + r] = (short)f2bf_trunc(s[2 * m + 1][r]);
        }
      __builtin_amdgcn_s_setprio(1);
#pragma unroll
      for (int dt = 0; dt < 4; ++dt) {
        const int dh = dt * 16 + li;
#pragma unroll
        for (int m = 0; m < 2; ++m) {
          const short8 vb = *(const short8*)(Vt + dh * 128 + ((m * 64 + g * 16) ^ ((dh & 7) << 4)));
          acc[dt] = MFMA16(pa[m], vb, acc[dt]);
        }
      }
      __builtin_amdgcn_s_setprio(0);
      __syncthreads();
      cur ^= 1;
    }
#pragma unroll
    for (int r = 0; r < 4; ++r) {
      const float lrb = __shfl(lr, sb + r);
      const float inv = 1.f / lrb;
      const int row = rowb + q0 + w * 16 + g * 4 + r;
#pragma unroll
      for (int dt = 0; dt < 4; ++dt) {
        const int col = h * 64 + dt * 16 + li;
        ctx[(size_t)row * 1024 + col] = f2bf(acc[dt][r] * inv);
      }
    }
  }
}

extern "C" void kernel_launch(void* const* d_in, const int* in_sizes, int n_in,
                              void* d_out, int out_size, void* d_ws, size_t ws_size,
                              hipStream_t stream) {
  const float* x = (const float*)d_in[0];
  const float* Wq = (const float*)d_in[1];
  const float* Wk = (const float*)d_in[2];
  const float* Wv = (const float*)d_in[3];
  const float* Wo = (const float*)d_in[4];
  const float* g1 = (const float*)d_in[5];
  const float* g2 = (const float*)d_in[6];
  const float* W1 = (const float*)d_in[7];
  const float* W2 = (const float*)d_in[8];
  const float* W3 = (const float*)d_in[9];
  float* out = (float*)d_out;

  char* wsb = (char*)d_ws;
  ushort_t* hb = (ushort_t*)(wsb);                   // 0..8 MiB
  ushort_t* qkv = (ushort_t*)(wsb + (8u << 20));     // 8..32 (dead after attn)
  ushort_t* ctx = (ushort_t*)(wsb + (32u << 20));    // 32..40 (dead after Wo)
  ushort_t* x1b = (ushort_t*)(wsb + (8u << 20));     // 8..40, overlays dead qkv+ctx
  ushort_t* wqkvT = (ushort_t*)(wsb + (72u << 20));  // 72..78
  ushort_t* woT = (ushort_t*)(wsb + (78u << 20));    // 78..80
  ushort_t* w13iT = (ushort_t*)(wsb + (80u << 20));  // 80..96 (interleaved W1|W3 fragments)
  ushort_t* w2T = (ushort_t*)(wsb + (96u << 20));    // 96..104

  // weight transpose+cast to bf16 [N][K]: four 1024^2 in one launch; W1/W3/W2 in one launch.
  transpose4_k<<<dim3(16, 16, 4), 256, 0, stream>>>(Wq, Wk, Wv, Wo, wqkvT,
                                                    wqkvT + 1024 * 1024,
                                                    wqkvT + 2 * 1024 * 1024, woT);
  transpose3_k<<<dim3(64, 16, 3), 256, 0, stream>>>(W1, W3, W2, w13iT, w2T);

  // 1. h = rmsnorm(x, g1) -> bf16
  rmsnorm_k<<<4096, 256, 0, stream>>>(x, g1, hb);
  // 2. qkv = h @ [Wq|Wk|Wv]   (128^2 tile, 768 blocks = 3/CU)
  gemm_k<0><<<dim3(24, 32), 256, 0, stream>>>(hb, wqkvT, nullptr, qkv, 3072, 1024);
  // 3. RoPE on Q and K in one launch (Q scale = 1/sqrt(dh) * log2(e))
  rope_k<<<4096, 256, 0, stream>>>(qkv);
  // 4. ctx = causal flash attention (work-balanced q-tile pairs: 512 equal blocks)
  attn_k<<<dim3(16, 32), 256, 0, stream>>>(qkv, ctx);
  // 5. out1 = x + ctx @ Wo  (fp32)
  gemm_k<1><<<dim3(8, 32), 256, 0, stream>>>(ctx, woT, x, out, 1024, 1024);
  // 6. h2 = rmsnorm(out1, g2) -> bf16
  rmsnorm_k<<<4096, 256, 0, stream>>>(out, g2, hb);
  // 7. x1 = silu(h2@W1) * (h2@W3)  — fused interleaved GEMM, phase-split ring pipeline
  gemm256_k<1><<<dim3(32, 16), 512, 0, stream>>>(hb, w13iT, x1b, 4096, 1024);
  // 8. out = out1 + x1 @ W2  (proven 128^2 3-buffer pipeline)
  gemm_k<1><<<dim3(8, 32), 256, 0, stream>>>(x1b, w2T, out, out, 1024, 4096);
}

// Round 24
// 337.260 us; speedup vs baseline: 1.1346x; 1.0074x over previous
//
#include <hip/hip_runtime.h>
#include <math.h>

typedef unsigned short ushort_t;
typedef __attribute__((ext_vector_type(8))) short short8;
typedef __attribute__((ext_vector_type(4))) float f32x4;

#define MFMA16(a, b, c) __builtin_amdgcn_mfma_f32_16x16x32_bf16((a), (b), (c), 0, 0, 0)

static __device__ __forceinline__ float fast_exp2(float x) {
#if __has_builtin(__builtin_amdgcn_exp2f)
  return __builtin_amdgcn_exp2f(x);
#else
  return exp2f(x);
#endif
}

static __device__ __forceinline__ ushort_t f2bf(float f) {
  unsigned int u = __float_as_uint(f);
  u = u + 0x7FFFu + ((u >> 16) & 1u);  // RTNE
  return (ushort_t)(u >> 16);
}
static __device__ __forceinline__ ushort_t f2bf_trunc(float f) {
  return (ushort_t)(__float_as_uint(f) >> 16);  // truncate: 1 op, fine for P in [0,1]
}
static __device__ __forceinline__ float bf2f(ushort_t s) {
  return __uint_as_float(((unsigned int)s) << 16);
}

// async global->LDS, 16B per lane. l_uniform: wave-uniform LDS base (lane*16 implicit).
static __device__ __forceinline__ void stage16(const ushort_t* g_perlane, char* l_uniform, int lane) {
#if __has_builtin(__builtin_amdgcn_global_load_lds)
  __builtin_amdgcn_global_load_lds((const __attribute__((address_space(1))) void*)g_perlane,
                                   (__attribute__((address_space(3))) void*)l_uniform, 16, 0, 0);
#else
  *(uint4*)(l_uniform + lane * 16) = *(const uint4*)g_perlane;
#endif
}

// ---------------- RMSNorm fp32 in -> bf16 out ----------------
__global__ __launch_bounds__(256) void rmsnorm_k(const float* __restrict__ x,
                                                 const float* __restrict__ g,
                                                 ushort_t* __restrict__ o) {
  const int r = blockIdx.x, t = threadIdx.x;
  const float4 xv = ((const float4*)(x + (size_t)r * 1024))[t];
  float ss = xv.x * xv.x + xv.y * xv.y + xv.z * xv.z + xv.w * xv.w;
#pragma unroll
  for (int m = 32; m >= 1; m >>= 1) ss += __shfl_xor(ss, m);
  __shared__ float wp[4];
  if ((t & 63) == 0) wp[t >> 6] = ss;
  __syncthreads();
  const float inv = rsqrtf((wp[0] + wp[1] + wp[2] + wp[3]) * (1.f / 1024.f) + 1e-5f);
  const float4 gv = ((const float4*)g)[t];
  ushort4 ov = {f2bf(xv.x * inv * gv.x), f2bf(xv.y * inv * gv.y),
                f2bf(xv.z * inv * gv.z), f2bf(xv.w * inv * gv.w)};
  *(ushort4*)(o + (size_t)r * 1024 + t * 4) = ov;
}

// ---------------- 4x fused 1024x1024 transpose+cast (Wq,Wk,Wv,Wo in one launch) ----------------
__global__ __launch_bounds__(256) void transpose4_k(const float* __restrict__ s0,
                                                    const float* __restrict__ s1,
                                                    const float* __restrict__ s2,
                                                    const float* __restrict__ s3,
                                                    ushort_t* __restrict__ d0,
                                                    ushort_t* __restrict__ d1,
                                                    ushort_t* __restrict__ d2,
                                                    ushort_t* __restrict__ d3) {
  const int z = blockIdx.z;
  const float* in = (z == 0) ? s0 : (z == 1) ? s1 : (z == 2) ? s2 : s3;
  ushort_t* out = (z == 0) ? d0 : (z == 1) ? d1 : (z == 2) ? d2 : d3;
  __shared__ ushort_t Ts[64][72];
  const int t = threadIdx.x;
  const int c0 = blockIdx.x * 64, r0 = blockIdx.y * 64;
  const int lr = t >> 4, lc = (t & 15) * 4;
#pragma unroll
  for (int i = 0; i < 4; ++i) {
    const float4 v = *(const float4*)&in[(size_t)(r0 + lr + i * 16) * 1024 + c0 + lc];
    Ts[lr + i * 16][lc + 0] = f2bf(v.x);
    Ts[lr + i * 16][lc + 1] = f2bf(v.y);
    Ts[lr + i * 16][lc + 2] = f2bf(v.z);
    Ts[lr + i * 16][lc + 3] = f2bf(v.w);
  }
  __syncthreads();
  const int rr = (t & 15) * 4;
#pragma unroll
  for (int i = 0; i < 4; ++i) {
    const int cc = (t >> 4) + i * 16;
    ushort4 o = {Ts[rr + 0][cc], Ts[rr + 1][cc], Ts[rr + 2][cc], Ts[rr + 3][cc]};
    *(ushort4*)&out[(size_t)(c0 + cc) * 1024 + r0 + rr] = o;
  }
}

// ---------------- 3x fused FFN-weight transpose+cast (W1,W3,W2 in one launch) ----------------
__global__ __launch_bounds__(256) void transpose3_k(const float* __restrict__ s0,
                                                    const float* __restrict__ s1,
                                                    const float* __restrict__ s2,
                                                    ushort_t* __restrict__ d01,
                                                    ushort_t* __restrict__ d2) {
  const int z = blockIdx.z;
  const float* in;
  ushort_t* out;
  int R, C, mode, c0, r0;
  if (z == 2) {
    in = s2; out = d2; R = 4096; C = 1024; mode = 0;
    const int flat = blockIdx.y * 64 + blockIdx.x;  // 0..1023
    c0 = (flat & 15) * 64;
    r0 = (flat >> 4) * 64;
  } else {
    in = (z == 0) ? s0 : s1; out = d01; R = 1024; C = 4096; mode = (z == 0) ? 1 : 2;
    c0 = blockIdx.x * 64;
    r0 = blockIdx.y * 64;
  }
  __shared__ ushort_t Ts[64][72];
  const int t = threadIdx.x;
  const int lr = t >> 4, lc = (t & 15) * 4;
#pragma unroll
  for (int i = 0; i < 4; ++i) {
    const float4 v = *(const float4*)&in[(size_t)(r0 + lr + i * 16) * C + c0 + lc];
    Ts[lr + i * 16][lc + 0] = f2bf(v.x);
    Ts[lr + i * 16][lc + 1] = f2bf(v.y);
    Ts[lr + i * 16][lc + 2] = f2bf(v.z);
    Ts[lr + i * 16][lc + 3] = f2bf(v.w);
  }
  __syncthreads();
  const int rr = (t & 15) * 4;
#pragma unroll
  for (int i = 0; i < 4; ++i) {
    const int cc = (t >> 4) + i * 16;
    const int cg = c0 + cc;
    int orow;
    if (mode == 0)
      orow = cg;
    else
      orow = ((cg >> 7) << 8) + (((cg >> 4) & 7) << 5) + (cg & 15) + (mode == 2 ? 16 : 0);
    ushort4 o = {Ts[rr + 0][cc], Ts[rr + 1][cc], Ts[rr + 2][cc], Ts[rr + 3][cc]};
    *(ushort4*)&out[(size_t)orow * R + r0 + rr] = o;
  }
}

// ---------------- RoPE in-place on bf16, ld=3072; Q and K in ONE launch ----------------
__global__ __launch_bounds__(256) void rope_k(ushort_t* __restrict__ qkv) {
  const int HALF = 4096 * 128;
  int idx = blockIdx.x * 256 + threadIdx.x;
  const int isK = idx >= HALF;
  idx &= HALF - 1;
  const float scale = isK ? 1.0f : 0.18033688011112042f;  // 0.125 * log2(e)
  const int row = idx >> 7, rem = idx & 127;
  const int head = rem >> 3, gq = rem & 7;
  const int i0 = gq * 4;
  const int s = row & 2047;
  ushort_t* p = qkv + (size_t)row * 3072 + isK * 1024 + head * 64 + i0 * 2;
  uint4 v = *(uint4*)p;
  ushort_t* e = (ushort_t*)&v;
#pragma unroll
  for (int k = 0; k < 4; ++k) {
    const float ang = (float)s * expf(-(float)(i0 + k) * 0.28782313662425572f);  // ln(1e4)/32
    float sn, cs;
    sincosf(ang, &sn, &cs);
    const float x1 = bf2f(e[2 * k]), x2 = bf2f(e[2 * k + 1]);
    e[2 * k] = f2bf((x1 * cs - x2 * sn) * scale);
    e[2 * k + 1] = f2bf((x2 * cs + x1 * sn) * scale);
  }
  *(uint4*)p = v;
}

// ---------------- 256x256-tile MFMA GEMM: BK=32, 4-slot ring, PHASE-SPLIT schedule ----------------
// 2D XCD supertiling (grid fixed at 32x16): XCD = flat&7 owns an 8bx x 8by region
// -> per-XCD B working set 4 MB (fits L2) instead of 16 MB.
template <int FUSED>
__global__ __launch_bounds__(512, 2) void gemm256_k(const ushort_t* __restrict__ A,
                                                    const ushort_t* __restrict__ Bt,
                                                    ushort_t* __restrict__ C,
                                                    int N, int K) {
  __shared__ uint4 smem[131072 / 16];  // A: 4 x 16KB @0 ; B: 4 x 16KB @65536
  char* sm = (char*)smem;
  const int flat = blockIdx.y * gridDim.x + blockIdx.x;
  const int xcd = flat & 7;
  const int idx = flat >> 3;  // 0..63
  const int bx = (xcd & 3) * 8 + (idx & 7);
  const int by = (xcd >> 2) * 8 + (idx >> 3);
  const int t = threadIdx.x, lane = t & 63, w = t >> 6;
  const int g = lane >> 4, li = lane & 15;
  const int wr = w >> 2, wc = w & 3;
  const int nr0 = bx * 256, m0 = by * 256;
  const int wb4 = (t & 448) << 4;  // wave base * 16
  const int srow = t & 255;
  const int sg0 = t >> 8;  // 0..1
  const size_t rowA = (size_t)(m0 + srow) * K;
  const size_t rowB = (size_t)(nr0 + srow) * K;
  f32x4 acc[8][4] = {};
  const int nkt = K >> 5;  // BK=32

  auto stageA = [&](int kt) {
    char* dA = sm + (kt & 3) * 16384;
    const int k0 = kt << 5;
#pragma unroll
    for (int c = 0; c < 2; ++c)
      stage16(A + rowA + k0 + (c * 2 + sg0) * 8, dA + ((c * 512) << 4) + wb4, lane);
  };
  auto stageB = [&](int kt) {
    char* dB = sm + 65536 + (kt & 3) * 16384;
    const int k0 = kt << 5;
#pragma unroll
    for (int c = 0; c < 2; ++c)
      stage16(Bt + rowB + k0 + (c * 2 + sg0) * 8, dB + ((c * 512) << 4) + wb4, lane);
  };

  stageA(0); stageB(0); stageA(1); stageB(1);       // 8 loads
  asm volatile("s_waitcnt vmcnt(4)" ::: "memory");  // tile0 forced; tile1 in flight
  __builtin_amdgcn_s_barrier();
  for (int kt = 0; kt < nkt; ++kt) {
    const char* sA = sm + (kt & 3) * 16384;
    const char* sB = sm + 65536 + (kt & 3) * 16384;
    const bool pf = (kt + 2 < nkt);
    // ---- phase 0: quadrant mi0-3 ----
    short8 af0[4], bfr[4];
#pragma unroll
    for (int mi = 0; mi < 4; ++mi)
      af0[mi] = *(const short8*)(sA + ((g * 256 + wr * 128 + mi * 16 + li) << 4));
#pragma unroll
    for (int ni = 0; ni < 4; ++ni)
      bfr[ni] = *(const short8*)(sB + ((g * 256 + wc * 64 + ni * 16 + li) << 4));
    if (pf) stageA(kt + 2);
    __builtin_amdgcn_s_barrier();
    __builtin_amdgcn_s_setprio(1);
#pragma unroll
    for (int mi = 0; mi < 4; ++mi)
#pragma unroll
      for (int ni = 0; ni < 4; ++ni) acc[mi][ni] = MFMA16(af0[mi], bfr[ni], acc[mi][ni]);
    __builtin_amdgcn_s_setprio(0);
    __builtin_amdgcn_s_barrier();
    // ---- phase 1: quadrant mi4-7 ----
    short8 af1[4];
#pragma unroll
    for (int mi = 0; mi < 4; ++mi)
      af1[mi] = *(const short8*)(sA + ((g * 256 + wr * 128 + (mi + 4) * 16 + li) << 4));
    if (pf) stageB(kt + 2);
    if (pf)
      asm volatile("s_waitcnt vmcnt(4)" ::: "memory");  // force tile kt+1; kt+2 stays in flight
    else if (kt + 1 < nkt)
      asm volatile("s_waitcnt vmcnt(0)" ::: "memory");  // tail: force last tile
    __builtin_amdgcn_s_barrier();
    __builtin_amdgcn_s_setprio(1);
#pragma unroll
    for (int mi = 0; mi < 4; ++mi)
#pragma unroll
      for (int ni = 0; ni < 4; ++ni) acc[mi + 4][ni] = MFMA16(af1[mi], bfr[ni], acc[mi + 4][ni]);
    __builtin_amdgcn_s_setprio(0);
    __builtin_amdgcn_s_barrier();
  }
  if (FUSED == 0) {
#pragma unroll
    for (int mi = 0; mi < 8; ++mi)
#pragma unroll
      for (int ni = 0; ni < 4; ++ni)
#pragma unroll
        for (int r = 0; r < 4; ++r) {
          const int row = m0 + wr * 128 + mi * 16 + g * 4 + r;
          const int col = nr0 + wc * 64 + ni * 16 + li;
          C[(size_t)row * N + col] = f2bf(acc[mi][ni][r]);
        }
  } else {
#pragma unroll
    for (int mi = 0; mi < 8; ++mi)
#pragma unroll
      for (int p = 0; p < 2; ++p)
#pragma unroll
        for (int r = 0; r < 4; ++r) {
          const float v1 = acc[mi][2 * p][r];
          const float v3 = acc[mi][2 * p + 1][r];
          const float o = v1 / (1.f + __expf(-v1)) * v3;
          const int row = m0 + wr * 128 + mi * 16 + g * 4 + r;
          const int col = bx * 128 + wc * 32 + p * 16 + li;
          C[(size_t)row * N + col] = f2bf(o);
        }
  }
}

// ---------------- 128x128-tile MFMA GEMM, 3-buffer counted-vmcnt pipeline ----------------
template <int MODE>
__global__ __launch_bounds__(256) void gemm_k(const ushort_t* __restrict__ A,
                                              const ushort_t* __restrict__ Bt,
                                              const float* __restrict__ R,
                                              void* __restrict__ C,
                                              int N, int K) {
  __shared__ uint4 smem[49152 / 16];  // 3 x (A 8KB @ buf*8192 | B 8KB @ 24576+buf*8192)
  char* sm = (char*)smem;
  const int flat = blockIdx.y * gridDim.x + blockIdx.x;
  const int total = gridDim.x * gridDim.y;
  const int swz = (flat & 7) * (total >> 3) + (flat >> 3);
  const int bx = swz % gridDim.x, by = swz / gridDim.x;
  const int t = threadIdx.x, lane = t & 63, w = t >> 6;
  const int g = lane >> 4, li = lane & 15;
  const int wr = w >> 1, wc = w & 1;
  const int n0 = bx * 128, m0 = by * 128;
  const int wb = t & 192;
  const int r0s = t & 127, g0s = (t >> 7) << 3;
  const size_t rowA = (size_t)(m0 + r0s) * K;
  const size_t rowB = (size_t)(n0 + r0s) * K;
  f32x4 acc[4][4] = {};
  const int nkt = K >> 5;

  auto stage_all = [&](int buf, int kt) {
    const int k0 = (kt << 5) + g0s;
    char* dA = sm + buf * 8192;
    char* dB = sm + 24576 + buf * 8192;
    stage16(A + rowA + k0, dA + (wb << 4), lane);
    stage16(A + rowA + k0 + 16, dA + ((256 + wb) << 4), lane);
    stage16(Bt + rowB + k0, dB + (wb << 4), lane);
    stage16(Bt + rowB + k0 + 16, dB + ((256 + wb) << 4), lane);
  };

  stage_all(0, 0);
  stage_all(1, 1);
  asm volatile("s_waitcnt vmcnt(4)" ::: "memory");  // buf0 landed; buf1 in flight
  __builtin_amdgcn_s_barrier();
  int b0 = 0;
  for (int kt = 0; kt < nkt; ++kt) {
    int bn = b0 + 2;
    if (bn >= 3) bn -= 3;
    if (kt + 2 < nkt) stage_all(bn, kt + 2);
    const char* smA = sm + b0 * 8192;
    const char* smB = sm + 24576 + b0 * 8192;
    short8 af[4], bfr[4];
#pragma unroll
    for (int mi = 0; mi < 4; ++mi)
      af[mi] = *(const short8*)(smA + ((g * 128 + wr * 64 + mi * 16 + li) << 4));
#pragma unroll
    for (int ni = 0; ni < 4; ++ni)
      bfr[ni] = *(const short8*)(smB + ((g * 128 + wc * 64 + ni * 16 + li) << 4));
    __builtin_amdgcn_s_setprio(1);
#pragma unroll
    for (int mi = 0; mi < 4; ++mi)
#pragma unroll
      for (int ni = 0; ni < 4; ++ni) acc[mi][ni] = MFMA16(af[mi], bfr[ni], acc[mi][ni]);
    __builtin_amdgcn_s_setprio(0);
    if (kt + 2 < nkt) {
      asm volatile("s_waitcnt vmcnt(4) lgkmcnt(0)" ::: "memory");  // kt+1 done, kt+2 in flight
      __builtin_amdgcn_s_barrier();
    } else if (kt + 1 < nkt) {
      asm volatile("s_waitcnt vmcnt(0) lgkmcnt(0)" ::: "memory");
      __builtin_amdgcn_s_barrier();
    }
    ++b0;
    if (b0 == 3) b0 = 0;
  }
#pragma unroll
  for (int mi = 0; mi < 4; ++mi)
#pragma unroll
    for (int ni = 0; ni < 4; ++ni)
#pragma unroll
      for (int r = 0; r < 4; ++r) {
        const int row = m0 + wr * 64 + mi * 16 + g * 4 + r;
        const int col = n0 + wc * 64 + ni * 16 + li;
        const float v = acc[mi][ni][r];
        if (MODE == 1)
          ((float*)C)[(size_t)row * N + col] = v + R[(size_t)row * N + col];
        else
          ((ushort_t*)C)[(size_t)row * N + col] = f2bf(v);
      }
}

// ---------------- Swapped-operand MFMA flash attention (causal), WORK-BALANCED PAIRS ----------
// grid (16, 32): block bx processes q-tiles {31-bx, bx} -> every block exactly 33 K-tiles.
__global__ __launch_bounds__(256) void attn_k(const ushort_t* __restrict__ qkv,
                                              ushort_t* __restrict__ ctx) {
  __shared__ uint4 smemv[32768 / 16];  // K0|K1 @0,8192 ; V0|V1 @16384,24576
  char* sm = (char*)smemv;
  const int bh = blockIdx.y;
  const int b = bh >> 4, h = bh & 15;
  const int t = threadIdx.x, lane = t & 63, w = t >> 6;
  const int g = lane >> 4, li = lane & 15;
  const int rowb = b * 2048;
  const size_t qbase = (size_t)rowb * 3072 + h * 64;
  const ushort_t* kptr = qkv + qbase + 1024;
  const ushort_t* vptr = qkv + qbase + 2048;
  const int sb = g * 20;  // broadcast source base: lane sb+r has li == g*4+r

  const int vj = t & 63;
  const int vcol2 = 2 * (((vj >> 5) << 5) + (((vj >> 2) & 3) << 3) + (((vj >> 4) & 1) << 2) + (vj & 3));

  uint4 vr0, vr1;  // in-flight V registers (T14)
  auto stageK = [&](int buf, int kt) {
    char* dst = sm + buf * 8192;
    const ushort_t* src = kptr + (size_t)kt * 64 * 3072 + (size_t)(t & 63) * 3072;
    stage16(src + (t >> 6) * 8, dst + ((t & 192) << 4), lane);
    stage16(src + ((t >> 6) + 4) * 8, dst + 4096 + ((t & 192) << 4), lane);
  };
  auto loadV = [&](int kt) {
    const ushort_t* src = vptr + (size_t)(kt * 64 + vj) * 3072 + w * 16;
    vr0 = *(const uint4*)src;
    vr1 = *(const uint4*)(src + 8);
  };
  auto writeV = [&](int buf) {
    char* dst = sm + 16384 + buf * 8192;
    ushort_t tmp[16];
    *(uint4*)tmp = vr0;
    *(uint4*)(tmp + 8) = vr1;
#pragma unroll
    for (int e = 0; e < 16; ++e) {
      const int dh = w * 16 + e;
      *(ushort_t*)(dst + dh * 128 + (vcol2 ^ ((dh & 7) << 4))) = tmp[e];
    }
  };

  for (int hv = 0; hv < 2; ++hv) {
    const int qt = (hv == 0) ? (31 - (int)blockIdx.x) : (int)blockIdx.x;  // long half first
    const int q0 = qt * 64;

    short8 qa[2];
    {
      const int qrow = q0 + w * 16 + li;
      qa[0] = *(const short8*)(qkv + qbase + (size_t)qrow * 3072 + 8 * g);
      qa[1] = *(const short8*)(qkv + qbase + (size_t)qrow * 3072 + 32 + 8 * g);
    }
    f32x4 acc[4] = {};
    float mr = -INFINITY, lr = 0.f;  // per-lane: q = li

    stageK(0, 0);
    loadV(0);
    writeV(0);
    __syncthreads();
    int cur = 0;
    for (int kt = 0; kt <= qt; ++kt) {
      if (kt < qt) {  // issue next tile's loads EARLY
        stageK(cur ^ 1, kt + 1);
        loadV(kt + 1);
      }
      const char* Kf = sm + cur * 8192;
      const char* Vt = sm + 16384 + cur * 8192;
      f32x4 s[4];
      __builtin_amdgcn_s_setprio(1);
#pragma unroll
      for (int nt = 0; nt < 4; ++nt) {
        f32x4 z = {0.f, 0.f, 0.f, 0.f};
#pragma unroll
        for (int hh = 0; hh < 2; ++hh) {
          const short8 kf = *(const short8*)(Kf + (((hh * 4 + g) * 64 + nt * 16 + li) << 4));
          z = MFMA16(kf, qa[hh], z);
        }
        s[nt] = z;
      }
      __builtin_amdgcn_s_setprio(0);
      if (kt == qt) {  // causal mask on diagonal tile
        const int qq = q0 + w * 16 + li;
#pragma unroll
        for (int nt = 0; nt < 4; ++nt)
#pragma unroll
          for (int r = 0; r < 4; ++r)
            if (kt * 64 + nt * 16 + g * 4 + r > qq) s[nt][r] = -INFINITY;
      }
      float pm = -INFINITY;
#pragma unroll
      for (int nt = 0; nt < 4; ++nt)
#pragma unroll
        for (int r = 0; r < 4; ++r) pm = fmaxf(pm, s[nt][r]);
      pm = fmaxf(pm, __shfl_xor(pm, 16));
      pm = fmaxf(pm, __shfl_xor(pm, 32));
      if (__any(pm > mr + 11.5f)) {
        const float nm = fmaxf(mr, pm);
        const float rs = fast_exp2(mr - nm);
        mr = nm;
        lr *= rs;
#pragma unroll
        for (int r = 0; r < 4; ++r) {
          const float rsb = __shfl(rs, sb + r);
#pragma unroll
          for (int dt = 0; dt < 4; ++dt) acc[dt][r] *= rsb;
        }
      }
      float ps = 0.f;
#pragma unroll
      for (int nt = 0; nt < 4; ++nt)
#pragma unroll
        for (int r = 0; r < 4; ++r) {
          s[nt][r] = fast_exp2(s[nt][r] - mr);
          ps += s[nt][r];
        }
      ps += __shfl_xor(ps, 16);
      ps += __shfl_xor(ps, 32);
      lr += ps;
      if (kt < qt) writeV(cur ^ 1);
      short8 pa[2];
#pragma unroll
      for (int m = 0; m < 2; ++m)
#pragma unroll
        for (int r = 0; r < 4; ++r) {
          pa[m][r] = (short)f2bf_trunc(s[2 * m][r]);
          pa[m][4 + r] = (short)f2bf_trunc(s[2 * m + 1][r]);
        }
      __builtin_amdgcn_s_setprio(1);
#pragma unroll
      for (int dt = 0; dt < 4; ++dt) {
        const int dh = dt * 16 + li;
#pragma unroll
        for (int m = 0; m < 2; ++m) {
          const short8 vb = *(const short8*)(Vt + dh * 128 + ((m * 64 + g * 16) ^ ((dh & 7) << 4)));
          acc[dt] = MFMA16(pa[m], vb, acc[dt]);
        }
      }
      __builtin_amdgcn_s_setprio(0);
      __syncthreads();
      cur ^= 1;
    }
#pragma unroll
    for (int r = 0; r < 4; ++r) {
      const float lrb = __shfl(lr, sb + r);
      const float inv = 1.f / lrb;
      const int row = rowb + q0 + w * 16 + g * 4 + r;
#pragma unroll
      for (int dt = 0; dt < 4; ++dt) {
        const int col = h * 64 + dt * 16 + li;
        ctx[(size_t)row * 1024 + col] = f2bf(acc[dt][r] * inv);
      }
    }
  }
}

extern "C" void kernel_launch(void* const* d_in, const int* in_sizes, int n_in,
                              void* d_out, int out_size, void* d_ws, size_t ws_size,
                              hipStream_t stream) {
  const float* x = (const float*)d_in[0];
  const float* Wq = (const float*)d_in[1];
  const float* Wk = (const float*)d_in[2];
  const float* Wv = (const float*)d_in[3];
  const float* Wo = (const float*)d_in[4];
  const float* g1 = (const float*)d_in[5];
  const float* g2 = (const float*)d_in[6];
  const float* W1 = (const float*)d_in[7];
  const float* W2 = (const float*)d_in[8];
  const float* W3 = (const float*)d_in[9];
  float* out = (float*)d_out;

  char* wsb = (char*)d_ws;
  ushort_t* hb = (ushort_t*)(wsb);                   // 0..8 MiB
  ushort_t* qkv = (ushort_t*)(wsb + (8u << 20));     // 8..32 (dead after attn)
  ushort_t* ctx = (ushort_t*)(wsb + (32u << 20));    // 32..40 (dead after Wo)
  ushort_t* x1b = (ushort_t*)(wsb + (8u << 20));     // 8..40, overlays dead qkv+ctx
  ushort_t* wqkvT = (ushort_t*)(wsb + (72u << 20));  // 72..78
  ushort_t* woT = (ushort_t*)(wsb + (78u << 20));    // 78..80
  ushort_t* w13iT = (ushort_t*)(wsb + (80u << 20));  // 80..96 (interleaved W1|W3 fragments)
  ushort_t* w2T = (ushort_t*)(wsb + (96u << 20));    // 96..104

  // weight transpose+cast to bf16 [N][K]: four 1024^2 in one launch; W1/W3/W2 in one launch.
  transpose4_k<<<dim3(16, 16, 4), 256, 0, stream>>>(Wq, Wk, Wv, Wo, wqkvT,
                                                    wqkvT + 1024 * 1024,
                                                    wqkvT + 2 * 1024 * 1024, woT);
  transpose3_k<<<dim3(64, 16, 3), 256, 0, stream>>>(W1, W3, W2, w13iT, w2T);

  // 1. h = rmsnorm(x, g1) -> bf16
  rmsnorm_k<<<4096, 256, 0, stream>>>(x, g1, hb);
  // 2. qkv = h @ [Wq|Wk|Wv]   (128^2 tile, 768 blocks = 3/CU)
  gemm_k<0><<<dim3(24, 32), 256, 0, stream>>>(hb, wqkvT, nullptr, qkv, 3072, 1024);
  // 3. RoPE on Q and K in one launch (Q scale = 1/sqrt(dh) * log2(e))
  rope_k<<<4096, 256, 0, stream>>>(qkv);
  // 4. ctx = causal flash attention (work-balanced q-tile pairs: 512 equal blocks)
  attn_k<<<dim3(16, 32), 256, 0, stream>>>(qkv, ctx);
  // 5. out1 = x + ctx @ Wo  (fp32)
  gemm_k<1><<<dim3(8, 32), 256, 0, stream>>>(ctx, woT, x, out, 1024, 1024);
  // 6. h2 = rmsnorm(out1, g2) -> bf16
  rmsnorm_k<<<4096, 256, 0, stream>>>(out, g2, hb);
  // 7. x1 = silu(h2@W1) * (h2@W3)  — 2D-XCD-supertiled fused interleaved GEMM
  gemm256_k<1><<<dim3(32, 16), 512, 0, stream>>>(hb, w13iT, x1b, 4096, 1024);
  // 8. out = out1 + x1 @ W2  (proven 128^2 3-buffer pipeline)
  gemm_k<1><<<dim3(8, 32), 256, 0, stream>>>(x1b, w2T, out, out, 1024, 4096);
}

// Round 25
// 330.201 us; speedup vs baseline: 1.1589x; 1.0214x over previous
//
#include <hip/hip_runtime.h>
#include <math.h>

typedef unsigned short ushort_t;
typedef __attribute__((ext_vector_type(8))) short short8;
typedef __attribute__((ext_vector_type(4))) float f32x4;

#define MFMA16(a, b, c) __builtin_amdgcn_mfma_f32_16x16x32_bf16((a), (b), (c), 0, 0, 0)

static __device__ __forceinline__ float fast_exp2(float x) {
#if __has_builtin(__builtin_amdgcn_exp2f)
  return __builtin_amdgcn_exp2f(x);
#else
  return exp2f(x);
#endif
}

static __device__ __forceinline__ ushort_t f2bf(float f) {
  unsigned int u = __float_as_uint(f);
  u = u + 0x7FFFu + ((u >> 16) & 1u);  // RTNE
  return (ushort_t)(u >> 16);
}
static __device__ __forceinline__ ushort_t f2bf_trunc(float f) {
  return (ushort_t)(__float_as_uint(f) >> 16);  // truncate: 1 op, fine for P in [0,1]
}
static __device__ __forceinline__ float bf2f(ushort_t s) {
  return __uint_as_float(((unsigned int)s) << 16);
}

// async global->LDS, 16B per lane. l_uniform: wave-uniform LDS base (lane*16 implicit).
static __device__ __forceinline__ void stage16(const ushort_t* g_perlane, char* l_uniform, int lane) {
#if __has_builtin(__builtin_amdgcn_global_load_lds)
  __builtin_amdgcn_global_load_lds((const __attribute__((address_space(1))) void*)g_perlane,
                                   (__attribute__((address_space(3))) void*)l_uniform, 16, 0, 0);
#else
  *(uint4*)(l_uniform + lane * 16) = *(const uint4*)g_perlane;
#endif
}

// ---------------- RMSNorm fp32 in -> bf16 out ----------------
__global__ __launch_bounds__(256) void rmsnorm_k(const float* __restrict__ x,
                                                 const float* __restrict__ g,
                                                 ushort_t* __restrict__ o) {
  const int r = blockIdx.x, t = threadIdx.x;
  const float4 xv = ((const float4*)(x + (size_t)r * 1024))[t];
  float ss = xv.x * xv.x + xv.y * xv.y + xv.z * xv.z + xv.w * xv.w;
#pragma unroll
  for (int m = 32; m >= 1; m >>= 1) ss += __shfl_xor(ss, m);
  __shared__ float wp[4];
  if ((t & 63) == 0) wp[t >> 6] = ss;
  __syncthreads();
  const float inv = rsqrtf((wp[0] + wp[1] + wp[2] + wp[3]) * (1.f / 1024.f) + 1e-5f);
  const float4 gv = ((const float4*)g)[t];
  ushort4 ov = {f2bf(xv.x * inv * gv.x), f2bf(xv.y * inv * gv.y),
                f2bf(xv.z * inv * gv.z), f2bf(xv.w * inv * gv.w)};
  *(ushort4*)(o + (size_t)r * 1024 + t * 4) = ov;
}

// ---------------- 4x fused 1024x1024 transpose+cast (Wq,Wk,Wv,Wo in one launch) ----------------
__global__ __launch_bounds__(256) void transpose4_k(const float* __restrict__ s0,
                                                    const float* __restrict__ s1,
                                                    const float* __restrict__ s2,
                                                    const float* __restrict__ s3,
                                                    ushort_t* __restrict__ d0,
                                                    ushort_t* __restrict__ d1,
                                                    ushort_t* __restrict__ d2,
                                                    ushort_t* __restrict__ d3) {
  const int z = blockIdx.z;
  const float* in = (z == 0) ? s0 : (z == 1) ? s1 : (z == 2) ? s2 : s3;
  ushort_t* out = (z == 0) ? d0 : (z == 1) ? d1 : (z == 2) ? d2 : d3;
  __shared__ ushort_t Ts[64][72];
  const int t = threadIdx.x;
  const int c0 = blockIdx.x * 64, r0 = blockIdx.y * 64;
  const int lr = t >> 4, lc = (t & 15) * 4;
#pragma unroll
  for (int i = 0; i < 4; ++i) {
    const float4 v = *(const float4*)&in[(size_t)(r0 + lr + i * 16) * 1024 + c0 + lc];
    Ts[lr + i * 16][lc + 0] = f2bf(v.x);
    Ts[lr + i * 16][lc + 1] = f2bf(v.y);
    Ts[lr + i * 16][lc + 2] = f2bf(v.z);
    Ts[lr + i * 16][lc + 3] = f2bf(v.w);
  }
  __syncthreads();
  const int rr = (t & 15) * 4;
#pragma unroll
  for (int i = 0; i < 4; ++i) {
    const int cc = (t >> 4) + i * 16;
    ushort4 o = {Ts[rr + 0][cc], Ts[rr + 1][cc], Ts[rr + 2][cc], Ts[rr + 3][cc]};
    *(ushort4*)&out[(size_t)(c0 + cc) * 1024 + r0 + rr] = o;
  }
}

// ---------------- 3x fused FFN-weight transpose+cast (W1,W3,W2 in one launch) ----------------
__global__ __launch_bounds__(256) void transpose3_k(const float* __restrict__ s0,
                                                    const float* __restrict__ s1,
                                                    const float* __restrict__ s2,
                                                    ushort_t* __restrict__ d01,
                                                    ushort_t* __restrict__ d2) {
  const int z = blockIdx.z;
  const float* in;
  ushort_t* out;
  int R, C, mode, c0, r0;
  if (z == 2) {
    in = s2; out = d2; R = 4096; C = 1024; mode = 0;
    const int flat = blockIdx.y * 64 + blockIdx.x;  // 0..1023
    c0 = (flat & 15) * 64;
    r0 = (flat >> 4) * 64;
  } else {
    in = (z == 0) ? s0 : s1; out = d01; R = 1024; C = 4096; mode = (z == 0) ? 1 : 2;
    c0 = blockIdx.x * 64;
    r0 = blockIdx.y * 64;
  }
  __shared__ ushort_t Ts[64][72];
  const int t = threadIdx.x;
  const int lr = t >> 4, lc = (t & 15) * 4;
#pragma unroll
  for (int i = 0; i < 4; ++i) {
    const float4 v = *(const float4*)&in[(size_t)(r0 + lr + i * 16) * C + c0 + lc];
    Ts[lr + i * 16][lc + 0] = f2bf(v.x);
    Ts[lr + i * 16][lc + 1] = f2bf(v.y);
    Ts[lr + i * 16][lc + 2] = f2bf(v.z);
    Ts[lr + i * 16][lc + 3] = f2bf(v.w);
  }
  __syncthreads();
  const int rr = (t & 15) * 4;
#pragma unroll
  for (int i = 0; i < 4; ++i) {
    const int cc = (t >> 4) + i * 16;
    const int cg = c0 + cc;
    int orow;
    if (mode == 0)
      orow = cg;
    else
      orow = ((cg >> 7) << 8) + (((cg >> 4) & 7) << 5) + (cg & 15) + (mode == 2 ? 16 : 0);
    ushort4 o = {Ts[rr + 0][cc], Ts[rr + 1][cc], Ts[rr + 2][cc], Ts[rr + 3][cc]};
    *(ushort4*)&out[(size_t)orow * R + r0 + rr] = o;
  }
}

// ---------------- 256x256-tile MFMA GEMM: BK=32, 4-slot ring, PHASE-SPLIT schedule ----------------
// 2D XCD supertiling (grid fixed at 32x16): XCD = flat&7 owns an 8bx x 8by region.
template <int FUSED>
__global__ __launch_bounds__(512, 2) void gemm256_k(const ushort_t* __restrict__ A,
                                                    const ushort_t* __restrict__ Bt,
                                                    ushort_t* __restrict__ C,
                                                    int N, int K) {
  __shared__ uint4 smem[131072 / 16];  // A: 4 x 16KB @0 ; B: 4 x 16KB @65536
  char* sm = (char*)smem;
  const int flat = blockIdx.y * gridDim.x + blockIdx.x;
  const int xcd = flat & 7;
  const int idx = flat >> 3;  // 0..63
  const int bx = (xcd & 3) * 8 + (idx & 7);
  const int by = (xcd >> 2) * 8 + (idx >> 3);
  const int t = threadIdx.x, lane = t & 63, w = t >> 6;
  const int g = lane >> 4, li = lane & 15;
  const int wr = w >> 2, wc = w & 3;
  const int nr0 = bx * 256, m0 = by * 256;
  const int wb4 = (t & 448) << 4;  // wave base * 16
  const int srow = t & 255;
  const int sg0 = t >> 8;  // 0..1
  const size_t rowA = (size_t)(m0 + srow) * K;
  const size_t rowB = (size_t)(nr0 + srow) * K;
  f32x4 acc[8][4] = {};
  const int nkt = K >> 5;  // BK=32

  auto stageA = [&](int kt) {
    char* dA = sm + (kt & 3) * 16384;
    const int k0 = kt << 5;
#pragma unroll
    for (int c = 0; c < 2; ++c)
      stage16(A + rowA + k0 + (c * 2 + sg0) * 8, dA + ((c * 512) << 4) + wb4, lane);
  };
  auto stageB = [&](int kt) {
    char* dB = sm + 65536 + (kt & 3) * 16384;
    const int k0 = kt << 5;
#pragma unroll
    for (int c = 0; c < 2; ++c)
      stage16(Bt + rowB + k0 + (c * 2 + sg0) * 8, dB + ((c * 512) << 4) + wb4, lane);
  };

  stageA(0); stageB(0); stageA(1); stageB(1);       // 8 loads
  asm volatile("s_waitcnt vmcnt(4)" ::: "memory");  // tile0 forced; tile1 in flight
  __builtin_amdgcn_s_barrier();
  for (int kt = 0; kt < nkt; ++kt) {
    const char* sA = sm + (kt & 3) * 16384;
    const char* sB = sm + 65536 + (kt & 3) * 16384;
    const bool pf = (kt + 2 < nkt);
    // ---- phase 0: quadrant mi0-3 ----
    short8 af0[4], bfr[4];
#pragma unroll
    for (int mi = 0; mi < 4; ++mi)
      af0[mi] = *(const short8*)(sA + ((g * 256 + wr * 128 + mi * 16 + li) << 4));
#pragma unroll
    for (int ni = 0; ni < 4; ++ni)
      bfr[ni] = *(const short8*)(sB + ((g * 256 + wc * 64 + ni * 16 + li) << 4));
    if (pf) stageA(kt + 2);
    __builtin_amdgcn_s_barrier();
    __builtin_amdgcn_s_setprio(1);
#pragma unroll
    for (int mi = 0; mi < 4; ++mi)
#pragma unroll
      for (int ni = 0; ni < 4; ++ni) acc[mi][ni] = MFMA16(af0[mi], bfr[ni], acc[mi][ni]);
    __builtin_amdgcn_s_setprio(0);
    __builtin_amdgcn_s_barrier();
    // ---- phase 1: quadrant mi4-7 ----
    short8 af1[4];
#pragma unroll
    for (int mi = 0; mi < 4; ++mi)
      af1[mi] = *(const short8*)(sA + ((g * 256 + wr * 128 + (mi + 4) * 16 + li) << 4));
    if (pf) stageB(kt + 2);
    if (pf)
      asm volatile("s_waitcnt vmcnt(4)" ::: "memory");  // force tile kt+1; kt+2 stays in flight
    else if (kt + 1 < nkt)
      asm volatile("s_waitcnt vmcnt(0)" ::: "memory");  // tail: force last tile
    __builtin_amdgcn_s_barrier();
    __builtin_amdgcn_s_setprio(1);
#pragma unroll
    for (int mi = 0; mi < 4; ++mi)
#pragma unroll
      for (int ni = 0; ni < 4; ++ni) acc[mi + 4][ni] = MFMA16(af1[mi], bfr[ni], acc[mi + 4][ni]);
    __builtin_amdgcn_s_setprio(0);
    __builtin_amdgcn_s_barrier();
  }
  if (FUSED == 0) {
#pragma unroll
    for (int mi = 0; mi < 8; ++mi)
#pragma unroll
      for (int ni = 0; ni < 4; ++ni)
#pragma unroll
        for (int r = 0; r < 4; ++r) {
          const int row = m0 + wr * 128 + mi * 16 + g * 4 + r;
          const int col = nr0 + wc * 64 + ni * 16 + li;
          C[(size_t)row * N + col] = f2bf(acc[mi][ni][r]);
        }
  } else {
#pragma unroll
    for (int mi = 0; mi < 8; ++mi)
#pragma unroll
      for (int p = 0; p < 2; ++p)
#pragma unroll
        for (int r = 0; r < 4; ++r) {
          const float v1 = acc[mi][2 * p][r];
          const float v3 = acc[mi][2 * p + 1][r];
          const float o = v1 / (1.f + __expf(-v1)) * v3;
          const int row = m0 + wr * 128 + mi * 16 + g * 4 + r;
          const int col = bx * 128 + wc * 32 + p * 16 + li;
          C[(size_t)row * N + col] = f2bf(o);
        }
  }
}

// ---------------- 128x128-tile MFMA GEMM, 3-buffer counted-vmcnt pipeline ----------------
// MODE 0: C=bf16(A@B). MODE 1: C=fp32(A@B + R). MODE 2: C=bf16 with fused RoPE (QKV, N=3072).
// QKV2D=1: 2D XCD supertile for grid (24,32): XCD owns 12bx x 8by region.
template <int MODE, int QKV2D>
__global__ __launch_bounds__(256) void gemm_k(const ushort_t* __restrict__ A,
                                              const ushort_t* __restrict__ Bt,
                                              const float* __restrict__ R,
                                              void* __restrict__ C,
                                              int N, int K) {
  __shared__ uint4 smem[49152 / 16];  // 3 x (A 8KB @ buf*8192 | B 8KB @ 24576+buf*8192)
  char* sm = (char*)smem;
  const int flat = blockIdx.y * gridDim.x + blockIdx.x;
  int bx, by;
  if (QKV2D) {  // grid (24,32): region 12x8 per XCD -> A 2MB + B 3MB working set
    const int xcd = flat & 7;
    const int idx = flat >> 3;  // 0..95
    bx = (xcd & 1) * 12 + idx % 12;
    by = (xcd >> 1) * 8 + idx / 12;
  } else {
    const int total = gridDim.x * gridDim.y;
    const int swz = (flat & 7) * (total >> 3) + (flat >> 3);
    bx = swz % gridDim.x;
    by = swz / gridDim.x;
  }
  const int t = threadIdx.x, lane = t & 63, w = t >> 6;
  const int g = lane >> 4, li = lane & 15;
  const int wr = w >> 1, wc = w & 1;
  const int n0 = bx * 128, m0 = by * 128;
  const int wb = t & 192;
  const int r0s = t & 127, g0s = (t >> 7) << 3;
  const size_t rowA = (size_t)(m0 + r0s) * K;
  const size_t rowB = (size_t)(n0 + r0s) * K;
  f32x4 acc[4][4] = {};
  const int nkt = K >> 5;

  auto stage_all = [&](int buf, int kt) {
    const int k0 = (kt << 5) + g0s;
    char* dA = sm + buf * 8192;
    char* dB = sm + 24576 + buf * 8192;
    stage16(A + rowA + k0, dA + (wb << 4), lane);
    stage16(A + rowA + k0 + 16, dA + ((256 + wb) << 4), lane);
    stage16(Bt + rowB + k0, dB + (wb << 4), lane);
    stage16(Bt + rowB + k0 + 16, dB + ((256 + wb) << 4), lane);
  };

  stage_all(0, 0);
  stage_all(1, 1);
  asm volatile("s_waitcnt vmcnt(4)" ::: "memory");  // buf0 landed; buf1 in flight
  __builtin_amdgcn_s_barrier();
  int b0 = 0;
  for (int kt = 0; kt < nkt; ++kt) {
    int bn = b0 + 2;
    if (bn >= 3) bn -= 3;
    if (kt + 2 < nkt) stage_all(bn, kt + 2);
    const char* smA = sm + b0 * 8192;
    const char* smB = sm + 24576 + b0 * 8192;
    short8 af[4], bfr[4];
#pragma unroll
    for (int mi = 0; mi < 4; ++mi)
      af[mi] = *(const short8*)(smA + ((g * 128 + wr * 64 + mi * 16 + li) << 4));
#pragma unroll
    for (int ni = 0; ni < 4; ++ni)
      bfr[ni] = *(const short8*)(smB + ((g * 128 + wc * 64 + ni * 16 + li) << 4));
    __builtin_amdgcn_s_setprio(1);
#pragma unroll
    for (int mi = 0; mi < 4; ++mi)
#pragma unroll
      for (int ni = 0; ni < 4; ++ni) acc[mi][ni] = MFMA16(af[mi], bfr[ni], acc[mi][ni]);
    __builtin_amdgcn_s_setprio(0);
    if (kt + 2 < nkt) {
      asm volatile("s_waitcnt vmcnt(4) lgkmcnt(0)" ::: "memory");  // kt+1 done, kt+2 in flight
      __builtin_amdgcn_s_barrier();
    } else if (kt + 1 < nkt) {
      asm volatile("s_waitcnt vmcnt(0) lgkmcnt(0)" ::: "memory");
      __builtin_amdgcn_s_barrier();
    }
    ++b0;
    if (b0 == 3) b0 = 0;
  }
#pragma unroll
  for (int mi = 0; mi < 4; ++mi)
#pragma unroll
    for (int ni = 0; ni < 4; ++ni)
#pragma unroll
      for (int r = 0; r < 4; ++r) {
        const int row = m0 + wr * 64 + mi * 16 + g * 4 + r;
        const int col = n0 + wc * 64 + ni * 16 + li;
        const float v = acc[mi][ni][r];
        if (MODE == 1) {
          ((float*)C)[(size_t)row * N + col] = v + R[(size_t)row * N + col];
        } else if (MODE == 2) {
          // fused RoPE: sect 0 = Q (scale folded), 1 = K, 2 = V (no rotation).
          // sect is uniform across the 16-lane group; pair (even,odd col) = lanes (li, li^1).
          const int sect = col >> 10;
          float ov = v;
          const float p = __shfl_xor(v, 1);  // partner value (uniform control flow)
          if (sect < 2) {
            const float fi = (float)((col & 63) >> 1);
            const float fs = (float)(row & 2047);
            const float ang = fs * __expf(-fi * 0.28782313662425572f);  // ln(1e4)/32
            float sn, cs;
            __sincosf(ang, &sn, &cs);
            const float scale = (sect == 0) ? 0.18033688011112042f : 1.0f;  // 0.125*log2e
            ov = ((li & 1) == 0) ? (v * cs - p * sn) * scale : (v * cs + p * sn) * scale;
          }
          ((ushort_t*)C)[(size_t)row * N + col] = f2bf(ov);
        } else {
          ((ushort_t*)C)[(size_t)row * N + col] = f2bf(v);
        }
      }
}

// ---------------- Swapped-operand MFMA flash attention (causal), WORK-BALANCED PAIRS ----------
// grid (16, 32): block bx processes q-tiles {31-bx, bx} -> every block exactly 33 K-tiles.
__global__ __launch_bounds__(256) void attn_k(const ushort_t* __restrict__ qkv,
                                              ushort_t* __restrict__ ctx) {
  __shared__ uint4 smemv[32768 / 16];  // K0|K1 @0,8192 ; V0|V1 @16384,24576
  char* sm = (char*)smemv;
  const int bh = blockIdx.y;
  const int b = bh >> 4, h = bh & 15;
  const int t = threadIdx.x, lane = t & 63, w = t >> 6;
  const int g = lane >> 4, li = lane & 15;
  const int rowb = b * 2048;
  const size_t qbase = (size_t)rowb * 3072 + h * 64;
  const ushort_t* kptr = qkv + qbase + 1024;
  const ushort_t* vptr = qkv + qbase + 2048;
  const int sb = g * 20;  // broadcast source base: lane sb+r has li == g*4+r

  const int vj = t & 63;
  const int vcol2 = 2 * (((vj >> 5) << 5) + (((vj >> 2) & 3) << 3) + (((vj >> 4) & 1) << 2) + (vj & 3));

  uint4 vr0, vr1;  // in-flight V registers (T14)
  auto stageK = [&](int buf, int kt) {
    char* dst = sm + buf * 8192;
    const ushort_t* src = kptr + (size_t)kt * 64 * 3072 + (size_t)(t & 63) * 3072;
    stage16(src + (t >> 6) * 8, dst + ((t & 192) << 4), lane);
    stage16(src + ((t >> 6) + 4) * 8, dst + 4096 + ((t & 192) << 4), lane);
  };
  auto loadV = [&](int kt) {
    const ushort_t* src = vptr + (size_t)(kt * 64 + vj) * 3072 + w * 16;
    vr0 = *(const uint4*)src;
    vr1 = *(const uint4*)(src + 8);
  };
  auto writeV = [&](int buf) {
    char* dst = sm + 16384 + buf * 8192;
    ushort_t tmp[16];
    *(uint4*)tmp = vr0;
    *(uint4*)(tmp + 8) = vr1;
#pragma unroll
    for (int e = 0; e < 16; ++e) {
      const int dh = w * 16 + e;
      *(ushort_t*)(dst + dh * 128 + (vcol2 ^ ((dh & 7) << 4))) = tmp[e];
    }
  };

  for (int hv = 0; hv < 2; ++hv) {
    const int qt = (hv == 0) ? (31 - (int)blockIdx.x) : (int)blockIdx.x;  // long half first
    const int q0 = qt * 64;

    short8 qa[2];
    {
      const int qrow = q0 + w * 16 + li;
      qa[0] = *(const short8*)(qkv + qbase + (size_t)qrow * 3072 + 8 * g);
      qa[1] = *(const short8*)(qkv + qbase + (size_t)qrow * 3072 + 32 + 8 * g);
    }
    f32x4 acc[4] = {};
    float mr = -INFINITY, lr = 0.f;  // per-lane: q = li

    stageK(0, 0);
    loadV(0);
    writeV(0);
    __syncthreads();
    int cur = 0;
    for (int kt = 0; kt <= qt; ++kt) {
      if (kt < qt) {  // issue next tile's loads EARLY
        stageK(cur ^ 1, kt + 1);
        loadV(kt + 1);
      }
      const char* Kf = sm + cur * 8192;
      const char* Vt = sm + 16384 + cur * 8192;
      f32x4 s[4];
      __builtin_amdgcn_s_setprio(1);
#pragma unroll
      for (int nt = 0; nt < 4; ++nt) {
        f32x4 z = {0.f, 0.f, 0.f, 0.f};
#pragma unroll
        for (int hh = 0; hh < 2; ++hh) {
          const short8 kf = *(const short8*)(Kf + (((hh * 4 + g) * 64 + nt * 16 + li) << 4));
          z = MFMA16(kf, qa[hh], z);
        }
        s[nt] = z;
      }
      __builtin_amdgcn_s_setprio(0);
      if (kt == qt) {  // causal mask on diagonal tile
        const int qq = q0 + w * 16 + li;
#pragma unroll
        for (int nt = 0; nt < 4; ++nt)
#pragma unroll
          for (int r = 0; r < 4; ++r)
            if (kt * 64 + nt * 16 + g * 4 + r > qq) s[nt][r] = -INFINITY;
      }
      float pm = -INFINITY;
#pragma unroll
      for (int nt = 0; nt < 4; ++nt)
#pragma unroll
        for (int r = 0; r < 4; ++r) pm = fmaxf(pm, s[nt][r]);
      pm = fmaxf(pm, __shfl_xor(pm, 16));
      pm = fmaxf(pm, __shfl_xor(pm, 32));
      if (__any(pm > mr + 11.5f)) {
        const float nm = fmaxf(mr, pm);
        const float rs = fast_exp2(mr - nm);
        mr = nm;
        lr *= rs;
#pragma unroll
        for (int r = 0; r < 4; ++r) {
          const float rsb = __shfl(rs, sb + r);
#pragma unroll
          for (int dt = 0; dt < 4; ++dt) acc[dt][r] *= rsb;
        }
      }
      float ps = 0.f;
#pragma unroll
      for (int nt = 0; nt < 4; ++nt)
#pragma unroll
        for (int r = 0; r < 4; ++r) {
          s[nt][r] = fast_exp2(s[nt][r] - mr);
          ps += s[nt][r];
        }
      ps += __shfl_xor(ps, 16);
      ps += __shfl_xor(ps, 32);
      lr += ps;
      if (kt < qt) writeV(cur ^ 1);
      short8 pa[2];
#pragma unroll
      for (int m = 0; m < 2; ++m)
#pragma unroll
        for (int r = 0; r < 4; ++r) {
          pa[m][r] = (short)f2bf_trunc(s[2 * m][r]);
          pa[m][4 + r] = (short)f2bf_trunc(s[2 * m + 1][r]);
        }
      __builtin_amdgcn_s_setprio(1);
#pragma unroll
      for (int dt = 0; dt < 4; ++dt) {
        const int dh = dt * 16 + li;
#pragma unroll
        for (int m = 0; m < 2; ++m) {
          const short8 vb = *(const short8*)(Vt + dh * 128 + ((m * 64 + g * 16) ^ ((dh & 7) << 4)));
          acc[dt] = MFMA16(pa[m], vb, acc[dt]);
        }
      }
      __builtin_amdgcn_s_setprio(0);
      __syncthreads();
      cur ^= 1;
    }
#pragma unroll
    for (int r = 0; r < 4; ++r) {
      const float lrb = __shfl(lr, sb + r);
      const float inv = 1.f / lrb;
      const int row = rowb + q0 + w * 16 + g * 4 + r;
#pragma unroll
      for (int dt = 0; dt < 4; ++dt) {
        const int col = h * 64 + dt * 16 + li;
        ctx[(size_t)row * 1024 + col] = f2bf(acc[dt][r] * inv);
      }
    }
  }
}

extern "C" void kernel_launch(void* const* d_in, const int* in_sizes, int n_in,
                              void* d_out, int out_size, void* d_ws, size_t ws_size,
                              hipStream_t stream) {
  const float* x = (const float*)d_in[0];
  const float* Wq = (const float*)d_in[1];
  const float* Wk = (const float*)d_in[2];
  const float* Wv = (const float*)d_in[3];
  const float* Wo = (const float*)d_in[4];
  const float* g1 = (const float*)d_in[5];
  const float* g2 = (const float*)d_in[6];
  const float* W1 = (const float*)d_in[7];
  const float* W2 = (const float*)d_in[8];
  const float* W3 = (const float*)d_in[9];
  float* out = (float*)d_out;

  char* wsb = (char*)d_ws;
  ushort_t* hb = (ushort_t*)(wsb);                   // 0..8 MiB
  ushort_t* qkv = (ushort_t*)(wsb + (8u << 20));     // 8..32 (dead after attn)
  ushort_t* ctx = (ushort_t*)(wsb + (32u << 20));    // 32..40 (dead after Wo)
  ushort_t* x1b = (ushort_t*)(wsb + (8u << 20));     // 8..40, overlays dead qkv+ctx
  ushort_t* wqkvT = (ushort_t*)(wsb + (72u << 20));  // 72..78
  ushort_t* woT = (ushort_t*)(wsb + (78u << 20));    // 78..80
  ushort_t* w13iT = (ushort_t*)(wsb + (80u << 20));  // 80..96 (interleaved W1|W3 fragments)
  ushort_t* w2T = (ushort_t*)(wsb + (96u << 20));    // 96..104

  // weight transpose+cast to bf16 [N][K]: four 1024^2 in one launch; W1/W3/W2 in one launch.
  transpose4_k<<<dim3(16, 16, 4), 256, 0, stream>>>(Wq, Wk, Wv, Wo, wqkvT,
                                                    wqkvT + 1024 * 1024,
                                                    wqkvT + 2 * 1024 * 1024, woT);
  transpose3_k<<<dim3(64, 16, 3), 256, 0, stream>>>(W1, W3, W2, w13iT, w2T);

  // 1. h = rmsnorm(x, g1) -> bf16
  rmsnorm_k<<<4096, 256, 0, stream>>>(x, g1, hb);
  // 2+3. qkv = h @ [Wq|Wk|Wv] with FUSED RoPE epilogue (2D XCD supertile, 12x8 regions)
  gemm_k<2, 1><<<dim3(24, 32), 256, 0, stream>>>(hb, wqkvT, nullptr, qkv, 3072, 1024);
  // 4. ctx = causal flash attention (work-balanced q-tile pairs: 512 equal blocks)
  attn_k<<<dim3(16, 32), 256, 0, stream>>>(qkv, ctx);
  // 5. out1 = x + ctx @ Wo  (fp32)
  gemm_k<1, 0><<<dim3(8, 32), 256, 0, stream>>>(ctx, woT, x, out, 1024, 1024);
  // 6. h2 = rmsnorm(out1, g2) -> bf16
  rmsnorm_k<<<4096, 256, 0, stream>>>(out, g2, hb);
  // 7. x1 = silu(h2@W1) * (h2@W3)  — 2D-XCD-supertiled fused interleaved GEMM
  gemm256_k<1><<<dim3(32, 16), 512, 0, stream>>>(hb, w13iT, x1b, 4096, 1024);
  // 8. out = out1 + x1 @ W2  (proven 128^2 3-buffer pipeline)
  gemm_k<1, 0><<<dim3(8, 32), 256, 0, stream>>>(x1b, w2T, out, out, 1024, 4096);
}

// Round 26
// 328.832 us; speedup vs baseline: 1.1637x; 1.0042x over previous
//
#include <hip/hip_runtime.h>
#include <math.h>

typedef unsigned short ushort_t;
typedef __attribute__((ext_vector_type(8))) short short8;
typedef __attribute__((ext_vector_type(4))) float f32x4;

#define MFMA16(a, b, c) __builtin_amdgcn_mfma_f32_16x16x32_bf16((a), (b), (c), 0, 0, 0)

static __device__ __forceinline__ float fast_exp2(float x) {
#if __has_builtin(__builtin_amdgcn_exp2f)
  return __builtin_amdgcn_exp2f(x);
#else
  return exp2f(x);
#endif
}

static __device__ __forceinline__ ushort_t f2bf(float f) {
  unsigned int u = __float_as_uint(f);
  u = u + 0x7FFFu + ((u >> 16) & 1u);  // RTNE
  return (ushort_t)(u >> 16);
}
static __device__ __forceinline__ ushort_t f2bf_trunc(float f) {
  return (ushort_t)(__float_as_uint(f) >> 16);  // truncate: 1 op, fine for P in [0,1]
}
static __device__ __forceinline__ float bf2f(ushort_t s) {
  return __uint_as_float(((unsigned int)s) << 16);
}

// async global->LDS, 16B per lane. l_uniform: wave-uniform LDS base (lane*16 implicit).
static __device__ __forceinline__ void stage16(const ushort_t* g_perlane, char* l_uniform, int lane) {
#if __has_builtin(__builtin_amdgcn_global_load_lds)
  __builtin_amdgcn_global_load_lds((const __attribute__((address_space(1))) void*)g_perlane,
                                   (__attribute__((address_space(3))) void*)l_uniform, 16, 0, 0);
#else
  *(uint4*)(l_uniform + lane * 16) = *(const uint4*)g_perlane;
#endif
}

// ---------------- RMSNorm fp32 in -> bf16 out ----------------
__global__ __launch_bounds__(256) void rmsnorm_k(const float* __restrict__ x,
                                                 const float* __restrict__ g,
                                                 ushort_t* __restrict__ o) {
  const int r = blockIdx.x, t = threadIdx.x;
  const float4 xv = ((const float4*)(x + (size_t)r * 1024))[t];
  float ss = xv.x * xv.x + xv.y * xv.y + xv.z * xv.z + xv.w * xv.w;
#pragma unroll
  for (int m = 32; m >= 1; m >>= 1) ss += __shfl_xor(ss, m);
  __shared__ float wp[4];
  if ((t & 63) == 0) wp[t >> 6] = ss;
  __syncthreads();
  const float inv = rsqrtf((wp[0] + wp[1] + wp[2] + wp[3]) * (1.f / 1024.f) + 1e-5f);
  const float4 gv = ((const float4*)g)[t];
  ushort4 ov = {f2bf(xv.x * inv * gv.x), f2bf(xv.y * inv * gv.y),
                f2bf(xv.z * inv * gv.z), f2bf(xv.w * inv * gv.w)};
  *(ushort4*)(o + (size_t)r * 1024 + t * 4) = ov;
}

// ---------------- 4x fused 1024x1024 transpose+cast (Wq,Wk,Wv,Wo in one launch) ----------------
__global__ __launch_bounds__(256) void transpose4_k(const float* __restrict__ s0,
                                                    const float* __restrict__ s1,
                                                    const float* __restrict__ s2,
                                                    const float* __restrict__ s3,
                                                    ushort_t* __restrict__ d0,
                                                    ushort_t* __restrict__ d1,
                                                    ushort_t* __restrict__ d2,
                                                    ushort_t* __restrict__ d3) {
  const int z = blockIdx.z;
  const float* in = (z == 0) ? s0 : (z == 1) ? s1 : (z == 2) ? s2 : s3;
  ushort_t* out = (z == 0) ? d0 : (z == 1) ? d1 : (z == 2) ? d2 : d3;
  __shared__ ushort_t Ts[64][72];
  const int t = threadIdx.x;
  const int c0 = blockIdx.x * 64, r0 = blockIdx.y * 64;
  const int lr = t >> 4, lc = (t & 15) * 4;
#pragma unroll
  for (int i = 0; i < 4; ++i) {
    const float4 v = *(const float4*)&in[(size_t)(r0 + lr + i * 16) * 1024 + c0 + lc];
    Ts[lr + i * 16][lc + 0] = f2bf(v.x);
    Ts[lr + i * 16][lc + 1] = f2bf(v.y);
    Ts[lr + i * 16][lc + 2] = f2bf(v.z);
    Ts[lr + i * 16][lc + 3] = f2bf(v.w);
  }
  __syncthreads();
  const int rr = (t & 15) * 4;
#pragma unroll
  for (int i = 0; i < 4; ++i) {
    const int cc = (t >> 4) + i * 16;
    ushort4 o = {Ts[rr + 0][cc], Ts[rr + 1][cc], Ts[rr + 2][cc], Ts[rr + 3][cc]};
    *(ushort4*)&out[(size_t)(c0 + cc) * 1024 + r0 + rr] = o;
  }
}

// ---------------- 3x fused FFN-weight transpose+cast (W1,W3,W2 in one launch) ----------------
__global__ __launch_bounds__(256) void transpose3_k(const float* __restrict__ s0,
                                                    const float* __restrict__ s1,
                                                    const float* __restrict__ s2,
                                                    ushort_t* __restrict__ d01,
                                                    ushort_t* __restrict__ d2) {
  const int z = blockIdx.z;
  const float* in;
  ushort_t* out;
  int R, C, mode, c0, r0;
  if (z == 2) {
    in = s2; out = d2; R = 4096; C = 1024; mode = 0;
    const int flat = blockIdx.y * 64 + blockIdx.x;  // 0..1023
    c0 = (flat & 15) * 64;
    r0 = (flat >> 4) * 64;
  } else {
    in = (z == 0) ? s0 : s1; out = d01; R = 1024; C = 4096; mode = (z == 0) ? 1 : 2;
    c0 = blockIdx.x * 64;
    r0 = blockIdx.y * 64;
  }
  __shared__ ushort_t Ts[64][72];
  const int t = threadIdx.x;
  const int lr = t >> 4, lc = (t & 15) * 4;
#pragma unroll
  for (int i = 0; i < 4; ++i) {
    const float4 v = *(const float4*)&in[(size_t)(r0 + lr + i * 16) * C + c0 + lc];
    Ts[lr + i * 16][lc + 0] = f2bf(v.x);
    Ts[lr + i * 16][lc + 1] = f2bf(v.y);
    Ts[lr + i * 16][lc + 2] = f2bf(v.z);
    Ts[lr + i * 16][lc + 3] = f2bf(v.w);
  }
  __syncthreads();
  const int rr = (t & 15) * 4;
#pragma unroll
  for (int i = 0; i < 4; ++i) {
    const int cc = (t >> 4) + i * 16;
    const int cg = c0 + cc;
    int orow;
    if (mode == 0)
      orow = cg;
    else
      orow = ((cg >> 7) << 8) + (((cg >> 4) & 7) << 5) + (cg & 15) + (mode == 2 ? 16 : 0);
    ushort4 o = {Ts[rr + 0][cc], Ts[rr + 1][cc], Ts[rr + 2][cc], Ts[rr + 3][cc]};
    *(ushort4*)&out[(size_t)orow * R + r0 + rr] = o;
  }
}

// ---------------- 256x256-tile MFMA GEMM: BK=32, 4-slot ring, PHASE-SPLIT schedule ----------------
// 2D XCD supertiling (grid fixed at 32x16): XCD = flat&7 owns an 8bx x 8by region.
template <int FUSED>
__global__ __launch_bounds__(512, 2) void gemm256_k(const ushort_t* __restrict__ A,
                                                    const ushort_t* __restrict__ Bt,
                                                    ushort_t* __restrict__ C,
                                                    int N, int K) {
  __shared__ uint4 smem[131072 / 16];  // A: 4 x 16KB @0 ; B: 4 x 16KB @65536
  char* sm = (char*)smem;
  const int flat = blockIdx.y * gridDim.x + blockIdx.x;
  const int xcd = flat & 7;
  const int idx = flat >> 3;  // 0..63
  const int bx = (xcd & 3) * 8 + (idx & 7);
  const int by = (xcd >> 2) * 8 + (idx >> 3);
  const int t = threadIdx.x, lane = t & 63, w = t >> 6;
  const int g = lane >> 4, li = lane & 15;
  const int wr = w >> 2, wc = w & 3;
  const int nr0 = bx * 256, m0 = by * 256;
  const int wb4 = (t & 448) << 4;  // wave base * 16
  const int srow = t & 255;
  const int sg0 = t >> 8;  // 0..1
  const size_t rowA = (size_t)(m0 + srow) * K;
  const size_t rowB = (size_t)(nr0 + srow) * K;
  f32x4 acc[8][4] = {};
  const int nkt = K >> 5;  // BK=32

  auto stageA = [&](int kt) {
    char* dA = sm + (kt & 3) * 16384;
    const int k0 = kt << 5;
#pragma unroll
    for (int c = 0; c < 2; ++c)
      stage16(A + rowA + k0 + (c * 2 + sg0) * 8, dA + ((c * 512) << 4) + wb4, lane);
  };
  auto stageB = [&](int kt) {
    char* dB = sm + 65536 + (kt & 3) * 16384;
    const int k0 = kt << 5;
#pragma unroll
    for (int c = 0; c < 2; ++c)
      stage16(Bt + rowB + k0 + (c * 2 + sg0) * 8, dB + ((c * 512) << 4) + wb4, lane);
  };

  stageA(0); stageB(0); stageA(1); stageB(1);       // 8 loads
  asm volatile("s_waitcnt vmcnt(4)" ::: "memory");  // tile0 forced; tile1 in flight
  __builtin_amdgcn_s_barrier();
  for (int kt = 0; kt < nkt; ++kt) {
    const char* sA = sm + (kt & 3) * 16384;
    const char* sB = sm + 65536 + (kt & 3) * 16384;
    const bool pf = (kt + 2 < nkt);
    // ---- phase 0: quadrant mi0-3 ----
    short8 af0[4], bfr[4];
#pragma unroll
    for (int mi = 0; mi < 4; ++mi)
      af0[mi] = *(const short8*)(sA + ((g * 256 + wr * 128 + mi * 16 + li) << 4));
#pragma unroll
    for (int ni = 0; ni < 4; ++ni)
      bfr[ni] = *(const short8*)(sB + ((g * 256 + wc * 64 + ni * 16 + li) << 4));
    if (pf) stageA(kt + 2);
    __builtin_amdgcn_s_barrier();
    __builtin_amdgcn_s_setprio(1);
#pragma unroll
    for (int mi = 0; mi < 4; ++mi)
#pragma unroll
      for (int ni = 0; ni < 4; ++ni) acc[mi][ni] = MFMA16(af0[mi], bfr[ni], acc[mi][ni]);
    __builtin_amdgcn_s_setprio(0);
    __builtin_amdgcn_s_barrier();
    // ---- phase 1: quadrant mi4-7 ----
    short8 af1[4];
#pragma unroll
    for (int mi = 0; mi < 4; ++mi)
      af1[mi] = *(const short8*)(sA + ((g * 256 + wr * 128 + (mi + 4) * 16 + li) << 4));
    if (pf) stageB(kt + 2);
    if (pf)
      asm volatile("s_waitcnt vmcnt(4)" ::: "memory");  // force tile kt+1; kt+2 stays in flight
    else if (kt + 1 < nkt)
      asm volatile("s_waitcnt vmcnt(0)" ::: "memory");  // tail: force last tile
    __builtin_amdgcn_s_barrier();
    __builtin_amdgcn_s_setprio(1);
#pragma unroll
    for (int mi = 0; mi < 4; ++mi)
#pragma unroll
      for (int ni = 0; ni < 4; ++ni) acc[mi + 4][ni] = MFMA16(af1[mi], bfr[ni], acc[mi + 4][ni]);
    __builtin_amdgcn_s_setprio(0);
    __builtin_amdgcn_s_barrier();
  }
  if (FUSED == 0) {
#pragma unroll
    for (int mi = 0; mi < 8; ++mi)
#pragma unroll
      for (int ni = 0; ni < 4; ++ni)
#pragma unroll
        for (int r = 0; r < 4; ++r) {
          const int row = m0 + wr * 128 + mi * 16 + g * 4 + r;
          const int col = nr0 + wc * 64 + ni * 16 + li;
          C[(size_t)row * N + col] = f2bf(acc[mi][ni][r]);
        }
  } else {
#pragma unroll
    for (int mi = 0; mi < 8; ++mi)
#pragma unroll
      for (int p = 0; p < 2; ++p)
#pragma unroll
        for (int r = 0; r < 4; ++r) {
          const float v1 = acc[mi][2 * p][r];
          const float v3 = acc[mi][2 * p + 1][r];
          const float o = v1 / (1.f + __expf(-v1)) * v3;
          const int row = m0 + wr * 128 + mi * 16 + g * 4 + r;
          const int col = bx * 128 + wc * 32 + p * 16 + li;
          C[(size_t)row * N + col] = f2bf(o);
        }
  }
}

// ---------------- 128x128-tile MFMA GEMM, 3-buffer counted-vmcnt pipeline ----------------
// MODE 0: C=bf16(A@B). MODE 1: C=fp32(A@B + R). MODE 2: C=bf16 with fused RoPE (QKV, N=3072).
// QKV2D=1: 2D XCD supertile for grid (24,32). PSPLIT=1: two-phase barrier schedule
// (reads+A-stage | 8 MFMA || reads+B-stage+vmcnt | 8 MFMA) for wave role diversity.
template <int MODE, int QKV2D, int PSPLIT>
__global__ __launch_bounds__(256) void gemm_k(const ushort_t* __restrict__ A,
                                              const ushort_t* __restrict__ Bt,
                                              const float* __restrict__ R,
                                              void* __restrict__ C,
                                              int N, int K) {
  __shared__ uint4 smem[49152 / 16];  // 3 x (A 8KB @ buf*8192 | B 8KB @ 24576+buf*8192)
  char* sm = (char*)smem;
  const int flat = blockIdx.y * gridDim.x + blockIdx.x;
  int bx, by;
  if (QKV2D) {  // grid (24,32): region 12x8 per XCD -> A 2MB + B 3MB working set
    const int xcd = flat & 7;
    const int idx = flat >> 3;  // 0..95
    bx = (xcd & 1) * 12 + idx % 12;
    by = (xcd >> 1) * 8 + idx / 12;
  } else {
    const int total = gridDim.x * gridDim.y;
    const int swz = (flat & 7) * (total >> 3) + (flat >> 3);
    bx = swz % gridDim.x;
    by = swz / gridDim.x;
  }
  const int t = threadIdx.x, lane = t & 63, w = t >> 6;
  const int g = lane >> 4, li = lane & 15;
  const int wr = w >> 1, wc = w & 1;
  const int n0 = bx * 128, m0 = by * 128;
  const int wb = t & 192;
  const int r0s = t & 127, g0s = (t >> 7) << 3;
  const size_t rowA = (size_t)(m0 + r0s) * K;
  const size_t rowB = (size_t)(n0 + r0s) * K;
  f32x4 acc[4][4] = {};
  const int nkt = K >> 5;

  auto stageAh = [&](int buf, int kt) {
    const int k0 = (kt << 5) + g0s;
    char* dA = sm + buf * 8192;
    stage16(A + rowA + k0, dA + (wb << 4), lane);
    stage16(A + rowA + k0 + 16, dA + ((256 + wb) << 4), lane);
  };
  auto stageBh = [&](int buf, int kt) {
    const int k0 = (kt << 5) + g0s;
    char* dB = sm + 24576 + buf * 8192;
    stage16(Bt + rowB + k0, dB + (wb << 4), lane);
    stage16(Bt + rowB + k0 + 16, dB + ((256 + wb) << 4), lane);
  };

  stageAh(0, 0); stageBh(0, 0);
  stageAh(1, 1); stageBh(1, 1);
  asm volatile("s_waitcnt vmcnt(4)" ::: "memory");  // buf0 landed; buf1 in flight
  __builtin_amdgcn_s_barrier();
  int b0 = 0;
  for (int kt = 0; kt < nkt; ++kt) {
    int bn = b0 + 2;
    if (bn >= 3) bn -= 3;
    const bool pf = (kt + 2 < nkt);
    const char* smA = sm + b0 * 8192;
    const char* smB = sm + 24576 + b0 * 8192;
    if (PSPLIT) {
      // ---- phase 0: rows mi0-1 ----
      short8 af0[2], bfr[4];
#pragma unroll
      for (int mi = 0; mi < 2; ++mi)
        af0[mi] = *(const short8*)(smA + ((g * 128 + wr * 64 + mi * 16 + li) << 4));
#pragma unroll
      for (int ni = 0; ni < 4; ++ni)
        bfr[ni] = *(const short8*)(smB + ((g * 128 + wc * 64 + ni * 16 + li) << 4));
      if (pf) stageAh(bn, kt + 2);
      __builtin_amdgcn_s_barrier();
      __builtin_amdgcn_s_setprio(1);
#pragma unroll
      for (int mi = 0; mi < 2; ++mi)
#pragma unroll
        for (int ni = 0; ni < 4; ++ni) acc[mi][ni] = MFMA16(af0[mi], bfr[ni], acc[mi][ni]);
      __builtin_amdgcn_s_setprio(0);
      __builtin_amdgcn_s_barrier();
      // ---- phase 1: rows mi2-3 ----
      short8 af1[2];
#pragma unroll
      for (int mi = 0; mi < 2; ++mi)
        af1[mi] = *(const short8*)(smA + ((g * 128 + wr * 64 + (mi + 2) * 16 + li) << 4));
      if (pf) stageBh(bn, kt + 2);
      if (pf)
        asm volatile("s_waitcnt vmcnt(4) lgkmcnt(0)" ::: "memory");  // kt+1 done; kt+2 in flight
      else if (kt + 1 < nkt)
        asm volatile("s_waitcnt vmcnt(0) lgkmcnt(0)" ::: "memory");
      __builtin_amdgcn_s_barrier();
      __builtin_amdgcn_s_setprio(1);
#pragma unroll
      for (int mi = 0; mi < 2; ++mi)
#pragma unroll
        for (int ni = 0; ni < 4; ++ni) acc[mi + 2][ni] = MFMA16(af1[mi], bfr[ni], acc[mi + 2][ni]);
      __builtin_amdgcn_s_setprio(0);
      __builtin_amdgcn_s_barrier();
    } else {
      if (pf) { stageAh(bn, kt + 2); stageBh(bn, kt + 2); }
      short8 af[4], bfr[4];
#pragma unroll
      for (int mi = 0; mi < 4; ++mi)
        af[mi] = *(const short8*)(smA + ((g * 128 + wr * 64 + mi * 16 + li) << 4));
#pragma unroll
      for (int ni = 0; ni < 4; ++ni)
        bfr[ni] = *(const short8*)(smB + ((g * 128 + wc * 64 + ni * 16 + li) << 4));
      __builtin_amdgcn_s_setprio(1);
#pragma unroll
      for (int mi = 0; mi < 4; ++mi)
#pragma unroll
        for (int ni = 0; ni < 4; ++ni) acc[mi][ni] = MFMA16(af[mi], bfr[ni], acc[mi][ni]);
      __builtin_amdgcn_s_setprio(0);
      if (pf) {
        asm volatile("s_waitcnt vmcnt(4) lgkmcnt(0)" ::: "memory");  // kt+1 done, kt+2 in flight
        __builtin_amdgcn_s_barrier();
      } else if (kt + 1 < nkt) {
        asm volatile("s_waitcnt vmcnt(0) lgkmcnt(0)" ::: "memory");
        __builtin_amdgcn_s_barrier();
      }
    }
    ++b0;
    if (b0 == 3) b0 = 0;
  }
#pragma unroll
  for (int mi = 0; mi < 4; ++mi)
#pragma unroll
    for (int ni = 0; ni < 4; ++ni)
#pragma unroll
      for (int r = 0; r < 4; ++r) {
        const int row = m0 + wr * 64 + mi * 16 + g * 4 + r;
        const int col = n0 + wc * 64 + ni * 16 + li;
        const float v = acc[mi][ni][r];
        if (MODE == 1) {
          ((float*)C)[(size_t)row * N + col] = v + R[(size_t)row * N + col];
        } else if (MODE == 2) {
          // fused RoPE: sect 0 = Q (scale folded), 1 = K, 2 = V (no rotation).
          const int sect = col >> 10;
          float ov = v;
          const float p = __shfl_xor(v, 1);  // partner value (uniform control flow)
          if (sect < 2) {
            const float fi = (float)((col & 63) >> 1);
            const float fs = (float)(row & 2047);
            const float ang = fs * __expf(-fi * 0.28782313662425572f);  // ln(1e4)/32
            float sn, cs;
            __sincosf(ang, &sn, &cs);
            const float scale = (sect == 0) ? 0.18033688011112042f : 1.0f;  // 0.125*log2e
            ov = ((li & 1) == 0) ? (v * cs - p * sn) * scale : (v * cs + p * sn) * scale;
          }
          ((ushort_t*)C)[(size_t)row * N + col] = f2bf(ov);
        } else {
          ((ushort_t*)C)[(size_t)row * N + col] = f2bf(v);
        }
      }
}

// ---------------- Swapped-operand MFMA flash attention (causal), WORK-BALANCED PAIRS ----------
// grid (16, 32): block bx processes q-tiles {31-bx, bx} -> every block exactly 33 K-tiles.
__global__ __launch_bounds__(256) void attn_k(const ushort_t* __restrict__ qkv,
                                              ushort_t* __restrict__ ctx) {
  __shared__ uint4 smemv[32768 / 16];  // K0|K1 @0,8192 ; V0|V1 @16384,24576
  char* sm = (char*)smemv;
  const int bh = blockIdx.y;
  const int b = bh >> 4, h = bh & 15;
  const int t = threadIdx.x, lane = t & 63, w = t >> 6;
  const int g = lane >> 4, li = lane & 15;
  const int rowb = b * 2048;
  const size_t qbase = (size_t)rowb * 3072 + h * 64;
  const ushort_t* kptr = qkv + qbase + 1024;
  const ushort_t* vptr = qkv + qbase + 2048;
  const int sb = g * 20;  // broadcast source base: lane sb+r has li == g*4+r

  const int vj = t & 63;
  const int vcol2 = 2 * (((vj >> 5) << 5) + (((vj >> 2) & 3) << 3) + (((vj >> 4) & 1) << 2) + (vj & 3));

  uint4 vr0, vr1;  // in-flight V registers (T14)
  auto stageK = [&](int buf, int kt) {
    char* dst = sm + buf * 8192;
    const ushort_t* src = kptr + (size_t)kt * 64 * 3072 + (size_t)(t & 63) * 3072;
    stage16(src + (t >> 6) * 8, dst + ((t & 192) << 4), lane);
    stage16(src + ((t >> 6) + 4) * 8, dst + 4096 + ((t & 192) << 4), lane);
  };
  auto loadV = [&](int kt) {
    const ushort_t* src = vptr + (size_t)(kt * 64 + vj) * 3072 + w * 16;
    vr0 = *(const uint4*)src;
    vr1 = *(const uint4*)(src + 8);
  };
  auto writeV = [&](int buf) {
    char* dst = sm + 16384 + buf * 8192;
    ushort_t tmp[16];
    *(uint4*)tmp = vr0;
    *(uint4*)(tmp + 8) = vr1;
#pragma unroll
    for (int e = 0; e < 16; ++e) {
      const int dh = w * 16 + e;
      *(ushort_t*)(dst + dh * 128 + (vcol2 ^ ((dh & 7) << 4))) = tmp[e];
    }
  };

  for (int hv = 0; hv < 2; ++hv) {
    const int qt = (hv == 0) ? (31 - (int)blockIdx.x) : (int)blockIdx.x;  // long half first
    const int q0 = qt * 64;

    short8 qa[2];
    {
      const int qrow = q0 + w * 16 + li;
      qa[0] = *(const short8*)(qkv + qbase + (size_t)qrow * 3072 + 8 * g);
      qa[1] = *(const short8*)(qkv + qbase + (size_t)qrow * 3072 + 32 + 8 * g);
    }
    f32x4 acc[4] = {};
    float mr = -INFINITY, lr = 0.f;  // per-lane: q = li

    stageK(0, 0);
    loadV(0);
    writeV(0);
    __syncthreads();
    int cur = 0;
    for (int kt = 0; kt <= qt; ++kt) {
      if (kt < qt) {  // issue next tile's loads EARLY
        stageK(cur ^ 1, kt + 1);
        loadV(kt + 1);
      }
      const char* Kf = sm + cur * 8192;
      const char* Vt = sm + 16384 + cur * 8192;
      f32x4 s[4];
      __builtin_amdgcn_s_setprio(1);
#pragma unroll
      for (int nt = 0; nt < 4; ++nt) {
        f32x4 z = {0.f, 0.f, 0.f, 0.f};
#pragma unroll
        for (int hh = 0; hh < 2; ++hh) {
          const short8 kf = *(const short8*)(Kf + (((hh * 4 + g) * 64 + nt * 16 + li) << 4));
          z = MFMA16(kf, qa[hh], z);
        }
        s[nt] = z;
      }
      __builtin_amdgcn_s_setprio(0);
      if (kt == qt) {  // causal mask on diagonal tile
        const int qq = q0 + w * 16 + li;
#pragma unroll
        for (int nt = 0; nt < 4; ++nt)
#pragma unroll
          for (int r = 0; r < 4; ++r)
            if (kt * 64 + nt * 16 + g * 4 + r > qq) s[nt][r] = -INFINITY;
      }
      float pm = -INFINITY;
#pragma unroll
      for (int nt = 0; nt < 4; ++nt)
#pragma unroll
        for (int r = 0; r < 4; ++r) pm = fmaxf(pm, s[nt][r]);
      pm = fmaxf(pm, __shfl_xor(pm, 16));
      pm = fmaxf(pm, __shfl_xor(pm, 32));
      if (__any(pm > mr + 11.5f)) {
        const float nm = fmaxf(mr, pm);
        const float rs = fast_exp2(mr - nm);
        mr = nm;
        lr *= rs;
#pragma unroll
        for (int r = 0; r < 4; ++r) {
          const float rsb = __shfl(rs, sb + r);
#pragma unroll
          for (int dt = 0; dt < 4; ++dt) acc[dt][r] *= rsb;
        }
      }
      float ps = 0.f;
#pragma unroll
      for (int nt = 0; nt < 4; ++nt)
#pragma unroll
        for (int r = 0; r < 4; ++r) {
          s[nt][r] = fast_exp2(s[nt][r] - mr);
          ps += s[nt][r];
        }
      ps += __shfl_xor(ps, 16);
      ps += __shfl_xor(ps, 32);
      lr += ps;
      if (kt < qt) writeV(cur ^ 1);
      short8 pa[2];
#pragma unroll
      for (int m = 0; m < 2; ++m)
#pragma unroll
        for (int r = 0; r < 4; ++r) {
          pa[m][r] = (short)f2bf_trunc(s[2 * m][r]);
          pa[m][4 + r] = (short)f2bf_trunc(s[2 * m + 1][r]);
        }
      __builtin_amdgcn_s_setprio(1);
#pragma unroll
      for (int dt = 0; dt < 4; ++dt) {
        const int dh = dt * 16 + li;
#pragma unroll
        for (int m = 0; m < 2; ++m) {
          const short8 vb = *(const short8*)(Vt + dh * 128 + ((m * 64 + g * 16) ^ ((dh & 7) << 4)));
          acc[dt] = MFMA16(pa[m], vb, acc[dt]);
        }
      }
      __builtin_amdgcn_s_setprio(0);
      __syncthreads();
      cur ^= 1;
    }
#pragma unroll
    for (int r = 0; r < 4; ++r) {
      const float lrb = __shfl(lr, sb + r);
      const float inv = 1.f / lrb;
      const int row = rowb + q0 + w * 16 + g * 4 + r;
#pragma unroll
      for (int dt = 0; dt < 4; ++dt) {
        const int col = h * 64 + dt * 16 + li;
        ctx[(size_t)row * 1024 + col] = f2bf(acc[dt][r] * inv);
      }
    }
  }
}

extern "C" void kernel_launch(void* const* d_in, const int* in_sizes, int n_in,
                              void* d_out, int out_size, void* d_ws, size_t ws_size,
                              hipStream_t stream) {
  const float* x = (const float*)d_in[0];
  const float* Wq = (const float*)d_in[1];
  const float* Wk = (const float*)d_in[2];
  const float* Wv = (const float*)d_in[3];
  const float* Wo = (const float*)d_in[4];
  const float* g1 = (const float*)d_in[5];
  const float* g2 = (const float*)d_in[6];
  const float* W1 = (const float*)d_in[7];
  const float* W2 = (const float*)d_in[8];
  const float* W3 = (const float*)d_in[9];
  float* out = (float*)d_out;

  char* wsb = (char*)d_ws;
  ushort_t* hb = (ushort_t*)(wsb);                   // 0..8 MiB
  ushort_t* qkv = (ushort_t*)(wsb + (8u << 20));     // 8..32 (dead after attn)
  ushort_t* ctx = (ushort_t*)(wsb + (32u << 20));    // 32..40 (dead after Wo)
  ushort_t* x1b = (ushort_t*)(wsb + (8u << 20));     // 8..40, overlays dead qkv+ctx
  ushort_t* wqkvT = (ushort_t*)(wsb + (72u << 20));  // 72..78
  ushort_t* woT = (ushort_t*)(wsb + (78u << 20));    // 78..80
  ushort_t* w13iT = (ushort_t*)(wsb + (80u << 20));  // 80..96 (interleaved W1|W3 fragments)
  ushort_t* w2T = (ushort_t*)(wsb + (96u << 20));    // 96..104

  // weight transpose+cast to bf16 [N][K]: four 1024^2 in one launch; W1/W3/W2 in one launch.
  transpose4_k<<<dim3(16, 16, 4), 256, 0, stream>>>(Wq, Wk, Wv, Wo, wqkvT,
                                                    wqkvT + 1024 * 1024,
                                                    wqkvT + 2 * 1024 * 1024, woT);
  transpose3_k<<<dim3(64, 16, 3), 256, 0, stream>>>(W1, W3, W2, w13iT, w2T);

  // 1. h = rmsnorm(x, g1) -> bf16
  rmsnorm_k<<<4096, 256, 0, stream>>>(x, g1, hb);
  // 2+3. qkv = h @ [Wq|Wk|Wv] with FUSED RoPE epilogue (2D XCD supertile, 12x8 regions)
  gemm_k<2, 1, 0><<<dim3(24, 32), 256, 0, stream>>>(hb, wqkvT, nullptr, qkv, 3072, 1024);
  // 4. ctx = causal flash attention (work-balanced q-tile pairs: 512 equal blocks)
  attn_k<<<dim3(16, 32), 256, 0, stream>>>(qkv, ctx);
  // 5. out1 = x + ctx @ Wo  (fp32, phase-split schedule)
  gemm_k<1, 0, 1><<<dim3(8, 32), 256, 0, stream>>>(ctx, woT, x, out, 1024, 1024);
  // 6. h2 = rmsnorm(out1, g2) -> bf16
  rmsnorm_k<<<4096, 256, 0, stream>>>(out, g2, hb);
  // 7. x1 = silu(h2@W1) * (h2@W3)  — 2D-XCD-supertiled fused interleaved GEMM
  gemm256_k<1><<<dim3(32, 16), 512, 0, stream>>>(hb, w13iT, x1b, 4096, 1024);
  // 8. out = out1 + x1 @ W2  (phase-split schedule)
  gemm_k<1, 0, 1><<<dim3(8, 32), 256, 0, stream>>>(x1b, w2T, out, out, 1024, 4096);
}

// Round 27
// 326.951 us; speedup vs baseline: 1.1704x; 1.0058x over previous
//
#include <hip/hip_runtime.h>
#include <math.h>

typedef unsigned short ushort_t;
typedef __attribute__((ext_vector_type(8))) short short8;
typedef __attribute__((ext_vector_type(4))) float f32x4;

#define MFMA16(a, b, c) __builtin_amdgcn_mfma_f32_16x16x32_bf16((a), (b), (c), 0, 0, 0)

static __device__ __forceinline__ float fast_exp2(float x) {
#if __has_builtin(__builtin_amdgcn_exp2f)
  return __builtin_amdgcn_exp2f(x);
#else
  return exp2f(x);
#endif
}

static __device__ __forceinline__ ushort_t f2bf(float f) {
  unsigned int u = __float_as_uint(f);
  u = u + 0x7FFFu + ((u >> 16) & 1u);  // RTNE
  return (ushort_t)(u >> 16);
}
static __device__ __forceinline__ ushort_t f2bf_trunc(float f) {
  return (ushort_t)(__float_as_uint(f) >> 16);  // truncate: 1 op, fine for P in [0,1]
}
static __device__ __forceinline__ float bf2f(ushort_t s) {
  return __uint_as_float(((unsigned int)s) << 16);
}

// async global->LDS, 16B per lane. l_uniform: wave-uniform LDS base (lane*16 implicit).
static __device__ __forceinline__ void stage16(const ushort_t* g_perlane, char* l_uniform, int lane) {
#if __has_builtin(__builtin_amdgcn_global_load_lds)
  __builtin_amdgcn_global_load_lds((const __attribute__((address_space(1))) void*)g_perlane,
                                   (__attribute__((address_space(3))) void*)l_uniform, 16, 0, 0);
#else
  *(uint4*)(l_uniform + lane * 16) = *(const uint4*)g_perlane;
#endif
}

// ---------------- RMSNorm fp32 in -> bf16 out ----------------
__global__ __launch_bounds__(256) void rmsnorm_k(const float* __restrict__ x,
                                                 const float* __restrict__ g,
                                                 ushort_t* __restrict__ o) {
  const int r = blockIdx.x, t = threadIdx.x;
  const float4 xv = ((const float4*)(x + (size_t)r * 1024))[t];
  float ss = xv.x * xv.x + xv.y * xv.y + xv.z * xv.z + xv.w * xv.w;
#pragma unroll
  for (int m = 32; m >= 1; m >>= 1) ss += __shfl_xor(ss, m);
  __shared__ float wp[4];
  if ((t & 63) == 0) wp[t >> 6] = ss;
  __syncthreads();
  const float inv = rsqrtf((wp[0] + wp[1] + wp[2] + wp[3]) * (1.f / 1024.f) + 1e-5f);
  const float4 gv = ((const float4*)g)[t];
  ushort4 ov = {f2bf(xv.x * inv * gv.x), f2bf(xv.y * inv * gv.y),
                f2bf(xv.z * inv * gv.z), f2bf(xv.w * inv * gv.w)};
  *(ushort4*)(o + (size_t)r * 1024 + t * 4) = ov;
}

// ---------------- 4x fused 1024x1024 transpose+cast (Wq,Wk,Wv,Wo in one launch) ----------------
__global__ __launch_bounds__(256) void transpose4_k(const float* __restrict__ s0,
                                                    const float* __restrict__ s1,
                                                    const float* __restrict__ s2,
                                                    const float* __restrict__ s3,
                                                    ushort_t* __restrict__ d0,
                                                    ushort_t* __restrict__ d1,
                                                    ushort_t* __restrict__ d2,
                                                    ushort_t* __restrict__ d3) {
  const int z = blockIdx.z;
  const float* in = (z == 0) ? s0 : (z == 1) ? s1 : (z == 2) ? s2 : s3;
  ushort_t* out = (z == 0) ? d0 : (z == 1) ? d1 : (z == 2) ? d2 : d3;
  __shared__ ushort_t Ts[64][72];
  const int t = threadIdx.x;
  const int c0 = blockIdx.x * 64, r0 = blockIdx.y * 64;
  const int lr = t >> 4, lc = (t & 15) * 4;
#pragma unroll
  for (int i = 0; i < 4; ++i) {
    const float4 v = *(const float4*)&in[(size_t)(r0 + lr + i * 16) * 1024 + c0 + lc];
    Ts[lr + i * 16][lc + 0] = f2bf(v.x);
    Ts[lr + i * 16][lc + 1] = f2bf(v.y);
    Ts[lr + i * 16][lc + 2] = f2bf(v.z);
    Ts[lr + i * 16][lc + 3] = f2bf(v.w);
  }
  __syncthreads();
  const int rr = (t & 15) * 4;
#pragma unroll
  for (int i = 0; i < 4; ++i) {
    const int cc = (t >> 4) + i * 16;
    ushort4 o = {Ts[rr + 0][cc], Ts[rr + 1][cc], Ts[rr + 2][cc], Ts[rr + 3][cc]};
    *(ushort4*)&out[(size_t)(c0 + cc) * 1024 + r0 + rr] = o;
  }
}

// ---------------- 3x fused FFN-weight transpose+cast (W1,W3,W2 in one launch) ----------------
__global__ __launch_bounds__(256) void transpose3_k(const float* __restrict__ s0,
                                                    const float* __restrict__ s1,
                                                    const float* __restrict__ s2,
                                                    ushort_t* __restrict__ d01,
                                                    ushort_t* __restrict__ d2) {
  const int z = blockIdx.z;
  const float* in;
  ushort_t* out;
  int R, C, mode, c0, r0;
  if (z == 2) {
    in = s2; out = d2; R = 4096; C = 1024; mode = 0;
    const int flat = blockIdx.y * 64 + blockIdx.x;  // 0..1023
    c0 = (flat & 15) * 64;
    r0 = (flat >> 4) * 64;
  } else {
    in = (z == 0) ? s0 : s1; out = d01; R = 1024; C = 4096; mode = (z == 0) ? 1 : 2;
    c0 = blockIdx.x * 64;
    r0 = blockIdx.y * 64;
  }
  __shared__ ushort_t Ts[64][72];
  const int t = threadIdx.x;
  const int lr = t >> 4, lc = (t & 15) * 4;
#pragma unroll
  for (int i = 0; i < 4; ++i) {
    const float4 v = *(const float4*)&in[(size_t)(r0 + lr + i * 16) * C + c0 + lc];
    Ts[lr + i * 16][lc + 0] = f2bf(v.x);
    Ts[lr + i * 16][lc + 1] = f2bf(v.y);
    Ts[lr + i * 16][lc + 2] = f2bf(v.z);
    Ts[lr + i * 16][lc + 3] = f2bf(v.w);
  }
  __syncthreads();
  const int rr = (t & 15) * 4;
#pragma unroll
  for (int i = 0; i < 4; ++i) {
    const int cc = (t >> 4) + i * 16;
    const int cg = c0 + cc;
    int orow;
    if (mode == 0)
      orow = cg;
    else
      orow = ((cg >> 7) << 8) + (((cg >> 4) & 7) << 5) + (cg & 15) + (mode == 2 ? 16 : 0);
    ushort4 o = {Ts[rr + 0][cc], Ts[rr + 1][cc], Ts[rr + 2][cc], Ts[rr + 3][cc]};
    *(ushort4*)&out[(size_t)orow * R + r0 + rr] = o;
  }
}

// ---------------- 256x256-tile MFMA GEMM: BK=32, 4-slot ring, PHASE-SPLIT schedule ----------------
// 2D XCD supertiling (grid fixed at 32x16): XCD = flat&7 owns an 8bx x 8by region.
template <int FUSED>
__global__ __launch_bounds__(512, 2) void gemm256_k(const ushort_t* __restrict__ A,
                                                    const ushort_t* __restrict__ Bt,
                                                    ushort_t* __restrict__ C,
                                                    int N, int K) {
  __shared__ uint4 smem[131072 / 16];  // A: 4 x 16KB @0 ; B: 4 x 16KB @65536
  char* sm = (char*)smem;
  const int flat = blockIdx.y * gridDim.x + blockIdx.x;
  const int xcd = flat & 7;
  const int idx = flat >> 3;  // 0..63
  const int bx = (xcd & 3) * 8 + (idx & 7);
  const int by = (xcd >> 2) * 8 + (idx >> 3);
  const int t = threadIdx.x, lane = t & 63, w = t >> 6;
  const int g = lane >> 4, li = lane & 15;
  const int wr = w >> 2, wc = w & 3;
  const int nr0 = bx * 256, m0 = by * 256;
  const int wb4 = (t & 448) << 4;  // wave base * 16
  const int srow = t & 255;
  const int sg0 = t >> 8;  // 0..1
  const size_t rowA = (size_t)(m0 + srow) * K;
  const size_t rowB = (size_t)(nr0 + srow) * K;
  f32x4 acc[8][4] = {};
  const int nkt = K >> 5;  // BK=32

  auto stageA = [&](int kt) {
    char* dA = sm + (kt & 3) * 16384;
    const int k0 = kt << 5;
#pragma unroll
    for (int c = 0; c < 2; ++c)
      stage16(A + rowA + k0 + (c * 2 + sg0) * 8, dA + ((c * 512) << 4) + wb4, lane);
  };
  auto stageB = [&](int kt) {
    char* dB = sm + 65536 + (kt & 3) * 16384;
    const int k0 = kt << 5;
#pragma unroll
    for (int c = 0; c < 2; ++c)
      stage16(Bt + rowB + k0 + (c * 2 + sg0) * 8, dB + ((c * 512) << 4) + wb4, lane);
  };

  stageA(0); stageB(0); stageA(1); stageB(1);       // 8 loads
  asm volatile("s_waitcnt vmcnt(4)" ::: "memory");  // tile0 forced; tile1 in flight
  __builtin_amdgcn_s_barrier();
  for (int kt = 0; kt < nkt; ++kt) {
    const char* sA = sm + (kt & 3) * 16384;
    const char* sB = sm + 65536 + (kt & 3) * 16384;
    const bool pf = (kt + 2 < nkt);
    // ---- phase 0: quadrant mi0-3 ----
    short8 af0[4], bfr[4];
#pragma unroll
    for (int mi = 0; mi < 4; ++mi)
      af0[mi] = *(const short8*)(sA + ((g * 256 + wr * 128 + mi * 16 + li) << 4));
#pragma unroll
    for (int ni = 0; ni < 4; ++ni)
      bfr[ni] = *(const short8*)(sB + ((g * 256 + wc * 64 + ni * 16 + li) << 4));
    if (pf) stageA(kt + 2);
    __builtin_amdgcn_s_barrier();
    __builtin_amdgcn_s_setprio(1);
#pragma unroll
    for (int mi = 0; mi < 4; ++mi)
#pragma unroll
      for (int ni = 0; ni < 4; ++ni) acc[mi][ni] = MFMA16(af0[mi], bfr[ni], acc[mi][ni]);
    __builtin_amdgcn_s_setprio(0);
    __builtin_amdgcn_s_barrier();
    // ---- phase 1: quadrant mi4-7 ----
    short8 af1[4];
#pragma unroll
    for (int mi = 0; mi < 4; ++mi)
      af1[mi] = *(const short8*)(sA + ((g * 256 + wr * 128 + (mi + 4) * 16 + li) << 4));
    if (pf) stageB(kt + 2);
    if (pf)
      asm volatile("s_waitcnt vmcnt(4)" ::: "memory");  // force tile kt+1; kt+2 stays in flight
    else if (kt + 1 < nkt)
      asm volatile("s_waitcnt vmcnt(0)" ::: "memory");  // tail: force last tile
    __builtin_amdgcn_s_barrier();
    __builtin_amdgcn_s_setprio(1);
#pragma unroll
    for (int mi = 0; mi < 4; ++mi)
#pragma unroll
      for (int ni = 0; ni < 4; ++ni) acc[mi + 4][ni] = MFMA16(af1[mi], bfr[ni], acc[mi + 4][ni]);
    __builtin_amdgcn_s_setprio(0);
    __builtin_amdgcn_s_barrier();
  }
  if (FUSED == 0) {
#pragma unroll
    for (int mi = 0; mi < 8; ++mi)
#pragma unroll
      for (int ni = 0; ni < 4; ++ni)
#pragma unroll
        for (int r = 0; r < 4; ++r) {
          const int row = m0 + wr * 128 + mi * 16 + g * 4 + r;
          const int col = nr0 + wc * 64 + ni * 16 + li;
          C[(size_t)row * N + col] = f2bf(acc[mi][ni][r]);
        }
  } else {
#pragma unroll
    for (int mi = 0; mi < 8; ++mi)
#pragma unroll
      for (int p = 0; p < 2; ++p)
#pragma unroll
        for (int r = 0; r < 4; ++r) {
          const float v1 = acc[mi][2 * p][r];
          const float v3 = acc[mi][2 * p + 1][r];
          const float o = v1 / (1.f + __expf(-v1)) * v3;
          const int row = m0 + wr * 128 + mi * 16 + g * 4 + r;
          const int col = bx * 128 + wc * 32 + p * 16 + li;
          C[(size_t)row * N + col] = f2bf(o);
        }
  }
}

// ---------------- 128x128-tile MFMA GEMM, BK=32, 3-buffer ring (QKV w/ fused RoPE) ----------------
// MODE 2: C=bf16 with fused RoPE. QKV2D: 2D XCD supertile for grid (24,32).
template <int MODE, int QKV2D>
__global__ __launch_bounds__(256) void gemm_k(const ushort_t* __restrict__ A,
                                              const ushort_t* __restrict__ Bt,
                                              const float* __restrict__ R,
                                              void* __restrict__ C,
                                              int N, int K) {
  __shared__ uint4 smem[49152 / 16];  // 3 x (A 8KB @ buf*8192 | B 8KB @ 24576+buf*8192)
  char* sm = (char*)smem;
  const int flat = blockIdx.y * gridDim.x + blockIdx.x;
  int bx, by;
  if (QKV2D) {  // grid (24,32): region 12x8 per XCD -> A 2MB + B 3MB working set
    const int xcd = flat & 7;
    const int idx = flat >> 3;  // 0..95
    bx = (xcd & 1) * 12 + idx % 12;
    by = (xcd >> 1) * 8 + idx / 12;
  } else {
    const int total = gridDim.x * gridDim.y;
    const int swz = (flat & 7) * (total >> 3) + (flat >> 3);
    bx = swz % gridDim.x;
    by = swz / gridDim.x;
  }
  const int t = threadIdx.x, lane = t & 63, w = t >> 6;
  const int g = lane >> 4, li = lane & 15;
  const int wr = w >> 1, wc = w & 1;
  const int n0 = bx * 128, m0 = by * 128;
  const int wb = t & 192;
  const int r0s = t & 127, g0s = (t >> 7) << 3;
  const size_t rowA = (size_t)(m0 + r0s) * K;
  const size_t rowB = (size_t)(n0 + r0s) * K;
  f32x4 acc[4][4] = {};
  const int nkt = K >> 5;

  auto stage_all = [&](int buf, int kt) {
    const int k0 = (kt << 5) + g0s;
    char* dA = sm + buf * 8192;
    char* dB = sm + 24576 + buf * 8192;
    stage16(A + rowA + k0, dA + (wb << 4), lane);
    stage16(A + rowA + k0 + 16, dA + ((256 + wb) << 4), lane);
    stage16(Bt + rowB + k0, dB + (wb << 4), lane);
    stage16(Bt + rowB + k0 + 16, dB + ((256 + wb) << 4), lane);
  };

  stage_all(0, 0);
  stage_all(1, 1);
  asm volatile("s_waitcnt vmcnt(4)" ::: "memory");  // buf0 landed; buf1 in flight
  __builtin_amdgcn_s_barrier();
  int b0 = 0;
  for (int kt = 0; kt < nkt; ++kt) {
    int bn = b0 + 2;
    if (bn >= 3) bn -= 3;
    if (kt + 2 < nkt) stage_all(bn, kt + 2);
    const char* smA = sm + b0 * 8192;
    const char* smB = sm + 24576 + b0 * 8192;
    short8 af[4], bfr[4];
#pragma unroll
    for (int mi = 0; mi < 4; ++mi)
      af[mi] = *(const short8*)(smA + ((g * 128 + wr * 64 + mi * 16 + li) << 4));
#pragma unroll
    for (int ni = 0; ni < 4; ++ni)
      bfr[ni] = *(const short8*)(smB + ((g * 128 + wc * 64 + ni * 16 + li) << 4));
    __builtin_amdgcn_s_setprio(1);
#pragma unroll
    for (int mi = 0; mi < 4; ++mi)
#pragma unroll
      for (int ni = 0; ni < 4; ++ni) acc[mi][ni] = MFMA16(af[mi], bfr[ni], acc[mi][ni]);
    __builtin_amdgcn_s_setprio(0);
    if (kt + 2 < nkt) {
      asm volatile("s_waitcnt vmcnt(4) lgkmcnt(0)" ::: "memory");  // kt+1 done, kt+2 in flight
      __builtin_amdgcn_s_barrier();
    } else if (kt + 1 < nkt) {
      asm volatile("s_waitcnt vmcnt(0) lgkmcnt(0)" ::: "memory");
      __builtin_amdgcn_s_barrier();
    }
    ++b0;
    if (b0 == 3) b0 = 0;
  }
#pragma unroll
  for (int mi = 0; mi < 4; ++mi)
#pragma unroll
    for (int ni = 0; ni < 4; ++ni)
#pragma unroll
      for (int r = 0; r < 4; ++r) {
        const int row = m0 + wr * 64 + mi * 16 + g * 4 + r;
        const int col = n0 + wc * 64 + ni * 16 + li;
        const float v = acc[mi][ni][r];
        if (MODE == 1) {
          ((float*)C)[(size_t)row * N + col] = v + R[(size_t)row * N + col];
        } else if (MODE == 2) {
          // fused RoPE: sect 0 = Q (scale folded), 1 = K, 2 = V (no rotation).
          const int sect = col >> 10;
          float ov = v;
          const float p = __shfl_xor(v, 1);  // partner value (uniform control flow)
          if (sect < 2) {
            const float fi = (float)((col & 63) >> 1);
            const float fs = (float)(row & 2047);
            const float ang = fs * __expf(-fi * 0.28782313662425572f);  // ln(1e4)/32
            float sn, cs;
            __sincosf(ang, &sn, &cs);
            const float scale = (sect == 0) ? 0.18033688011112042f : 1.0f;  // 0.125*log2e
            ov = ((li & 1) == 0) ? (v * cs - p * sn) * scale : (v * cs + p * sn) * scale;
          }
          ((ushort_t*)C)[(size_t)row * N + col] = f2bf(ov);
        } else {
          ((ushort_t*)C)[(size_t)row * N + col] = f2bf(v);
        }
      }
}

// ---------------- 128x128-tile MFMA GEMM, BK=64, 3-slot ring, PSPLIT (Wo, W2) ----------------
// MODE 1: C=fp32(A@B + R). Per K-step (64 k): ph0 {read kk0 frags; stage A(kt+2); barrier;
// 16 MFMA; barrier} ph1 {read kk1 frags; stage B(kt+2); vmcnt(8); barrier; 16 MFMA; barrier}.
// 8 loads/step in flight across barriers; halved step count vs BK=32 at constant traffic.
// LDS 96 KB -> still 1 block/CU (unchanged; grid 256 = 1/CU anyway).
template <int MODE>
__global__ __launch_bounds__(256) void gemmbk64_k(const ushort_t* __restrict__ A,
                                                  const ushort_t* __restrict__ Bt,
                                                  const float* __restrict__ R,
                                                  void* __restrict__ C,
                                                  int N, int K) {
  __shared__ uint4 smem[98304 / 16];  // A: 3 x 16KB @0 ; B: 3 x 16KB @49152
  char* sm = (char*)smem;
  const int flat = blockIdx.y * gridDim.x + blockIdx.x;
  const int total = gridDim.x * gridDim.y;
  const int swz = (flat & 7) * (total >> 3) + (flat >> 3);
  const int bx = swz % gridDim.x, by = swz / gridDim.x;
  const int t = threadIdx.x, lane = t & 63, w = t >> 6;
  const int g = lane >> 4, li = lane & 15;
  const int wr = w >> 1, wc = w & 1;
  const int n0 = bx * 128, m0 = by * 128;
  const int wb = t & 192;
  const int r0s = t & 127, oc = t >> 7;  // staged row, k-octet parity
  const size_t rowA = (size_t)(m0 + r0s) * K;
  const size_t rowB = (size_t)(n0 + r0s) * K;
  f32x4 acc[4][4] = {};
  const int nkt = K >> 6;  // BK=64

  // slot layout: 16B slot s = octet*128 + row (octet 0..7 of 8 k-values each)
  auto stageAh = [&](int buf, int kt) {
    const int k0 = kt << 6;
    char* dA = sm + buf * 16384;
#pragma unroll
    for (int c = 0; c < 4; ++c)
      stage16(A + rowA + k0 + (c * 2 + oc) * 8, dA + ((c * 256 + wb) << 4), lane);
  };
  auto stageBh = [&](int buf, int kt) {
    const int k0 = kt << 6;
    char* dB = sm + 49152 + buf * 16384;
#pragma unroll
    for (int c = 0; c < 4; ++c)
      stage16(Bt + rowB + k0 + (c * 2 + oc) * 8, dB + ((c * 256 + wb) << 4), lane);
  };

  stageAh(0, 0); stageBh(0, 0);
  stageAh(1, 1); stageBh(1, 1);
  asm volatile("s_waitcnt vmcnt(8)" ::: "memory");  // slot0's 8 landed; slot1's in flight
  __builtin_amdgcn_s_barrier();
  int b0 = 0;
  for (int kt = 0; kt < nkt; ++kt) {
    int bn = b0 + 2;
    if (bn >= 3) bn -= 3;
    const bool pf = (kt + 2 < nkt);
    const char* smA = sm + b0 * 16384;
    const char* smB = sm + 49152 + b0 * 16384;
    // ---- phase 0: kk=0 (octets g) ----
    short8 af0[4], bf0[4];
#pragma unroll
    for (int mi = 0; mi < 4; ++mi)
      af0[mi] = *(const short8*)(smA + ((g * 128 + wr * 64 + mi * 16 + li) << 4));
#pragma unroll
    for (int ni = 0; ni < 4; ++ni)
      bf0[ni] = *(const short8*)(smB + ((g * 128 + wc * 64 + ni * 16 + li) << 4));
    if (pf) stageAh(bn, kt + 2);
    __builtin_amdgcn_s_barrier();
    __builtin_amdgcn_s_setprio(1);
#pragma unroll
    for (int mi = 0; mi < 4; ++mi)
#pragma unroll
      for (int ni = 0; ni < 4; ++ni) acc[mi][ni] = MFMA16(af0[mi], bf0[ni], acc[mi][ni]);
    __builtin_amdgcn_s_setprio(0);
    __builtin_amdgcn_s_barrier();
    // ---- phase 1: kk=1 (octets 4+g) ----
    short8 af1[4], bf1[4];
#pragma unroll
    for (int mi = 0; mi < 4; ++mi)
      af1[mi] = *(const short8*)(smA + (((4 + g) * 128 + wr * 64 + mi * 16 + li) << 4));
#pragma unroll
    for (int ni = 0; ni < 4; ++ni)
      bf1[ni] = *(const short8*)(smB + (((4 + g) * 128 + wc * 64 + ni * 16 + li) << 4));
    if (pf) stageBh(bn, kt + 2);
    if (pf)
      asm volatile("s_waitcnt vmcnt(8) lgkmcnt(0)" ::: "memory");  // kt+1 done; kt+2 in flight
    else if (kt + 1 < nkt)
      asm volatile("s_waitcnt vmcnt(0) lgkmcnt(0)" ::: "memory");
    __builtin_amdgcn_s_barrier();
    __builtin_amdgcn_s_setprio(1);
#pragma unroll
    for (int mi = 0; mi < 4; ++mi)
#pragma unroll
      for (int ni = 0; ni < 4; ++ni) acc[mi][ni] = MFMA16(af1[mi], bf1[ni], acc[mi][ni]);
    __builtin_amdgcn_s_setprio(0);
    __builtin_amdgcn_s_barrier();
    ++b0;
    if (b0 == 3) b0 = 0;
  }
#pragma unroll
  for (int mi = 0; mi < 4; ++mi)
#pragma unroll
    for (int ni = 0; ni < 4; ++ni)
#pragma unroll
      for (int r = 0; r < 4; ++r) {
        const int row = m0 + wr * 64 + mi * 16 + g * 4 + r;
        const int col = n0 + wc * 64 + ni * 16 + li;
        const float v = acc[mi][ni][r];
        if (MODE == 1)
          ((float*)C)[(size_t)row * N + col] = v + R[(size_t)row * N + col];
        else
          ((ushort_t*)C)[(size_t)row * N + col] = f2bf(v);
      }
}

// ---------------- Swapped-operand MFMA flash attention (causal), WORK-BALANCED PAIRS ----------
// grid (16, 32): block bx processes q-tiles {31-bx, bx} -> every block exactly 33 K-tiles.
__global__ __launch_bounds__(256) void attn_k(const ushort_t* __restrict__ qkv,
                                              ushort_t* __restrict__ ctx) {
  __shared__ uint4 smemv[32768 / 16];  // K0|K1 @0,8192 ; V0|V1 @16384,24576
  char* sm = (char*)smemv;
  const int bh = blockIdx.y;
  const int b = bh >> 4, h = bh & 15;
  const int t = threadIdx.x, lane = t & 63, w = t >> 6;
  const int g = lane >> 4, li = lane & 15;
  const int rowb = b * 2048;
  const size_t qbase = (size_t)rowb * 3072 + h * 64;
  const ushort_t* kptr = qkv + qbase + 1024;
  const ushort_t* vptr = qkv + qbase + 2048;
  const int sb = g * 20;  // broadcast source base: lane sb+r has li == g*4+r

  const int vj = t & 63;
  const int vcol2 = 2 * (((vj >> 5) << 5) + (((vj >> 2) & 3) << 3) + (((vj >> 4) & 1) << 2) + (vj & 3));

  uint4 vr0, vr1;  // in-flight V registers (T14)
  auto stageK = [&](int buf, int kt) {
    char* dst = sm + buf * 8192;
    const ushort_t* src = kptr + (size_t)kt * 64 * 3072 + (size_t)(t & 63) * 3072;
    stage16(src + (t >> 6) * 8, dst + ((t & 192) << 4), lane);
    stage16(src + ((t >> 6) + 4) * 8, dst + 4096 + ((t & 192) << 4), lane);
  };
  auto loadV = [&](int kt) {
    const ushort_t* src = vptr + (size_t)(kt * 64 + vj) * 3072 + w * 16;
    vr0 = *(const uint4*)src;
    vr1 = *(const uint4*)(src + 8);
  };
  auto writeV = [&](int buf) {
    char* dst = sm + 16384 + buf * 8192;
    ushort_t tmp[16];
    *(uint4*)tmp = vr0;
    *(uint4*)(tmp + 8) = vr1;
#pragma unroll
    for (int e = 0; e < 16; ++e) {
      const int dh = w * 16 + e;
      *(ushort_t*)(dst + dh * 128 + (vcol2 ^ ((dh & 7) << 4))) = tmp[e];
    }
  };

  for (int hv = 0; hv < 2; ++hv) {
    const int qt = (hv == 0) ? (31 - (int)blockIdx.x) : (int)blockIdx.x;  // long half first
    const int q0 = qt * 64;

    short8 qa[2];
    {
      const int qrow = q0 + w * 16 + li;
      qa[0] = *(const short8*)(qkv + qbase + (size_t)qrow * 3072 + 8 * g);
      qa[1] = *(const short8*)(qkv + qbase + (size_t)qrow * 3072 + 32 + 8 * g);
    }
    f32x4 acc[4] = {};
    float mr = -INFINITY, lr = 0.f;  // per-lane: q = li

    stageK(0, 0);
    loadV(0);
    writeV(0);
    __syncthreads();
    int cur = 0;
    for (int kt = 0; kt <= qt; ++kt) {
      if (kt < qt) {  // issue next tile's loads EARLY
        stageK(cur ^ 1, kt + 1);
        loadV(kt + 1);
      }
      const char* Kf = sm + cur * 8192;
      const char* Vt = sm + 16384 + cur * 8192;
      f32x4 s[4];
      __builtin_amdgcn_s_setprio(1);
#pragma unroll
      for (int nt = 0; nt < 4; ++nt) {
        f32x4 z = {0.f, 0.f, 0.f, 0.f};
#pragma unroll
        for (int hh = 0; hh < 2; ++hh) {
          const short8 kf = *(const short8*)(Kf + (((hh * 4 + g) * 64 + nt * 16 + li) << 4));
          z = MFMA16(kf, qa[hh], z);
        }
        s[nt] = z;
      }
      __builtin_amdgcn_s_setprio(0);
      if (kt == qt) {  // causal mask on diagonal tile
        const int qq = q0 + w * 16 + li;
#pragma unroll
        for (int nt = 0; nt < 4; ++nt)
#pragma unroll
          for (int r = 0; r < 4; ++r)
            if (kt * 64 + nt * 16 + g * 4 + r > qq) s[nt][r] = -INFINITY;
      }
      float pm = -INFINITY;
#pragma unroll
      for (int nt = 0; nt < 4; ++nt)
#pragma unroll
        for (int r = 0; r < 4; ++r) pm = fmaxf(pm, s[nt][r]);
      pm = fmaxf(pm, __shfl_xor(pm, 16));
      pm = fmaxf(pm, __shfl_xor(pm, 32));
      if (__any(pm > mr + 11.5f)) {
        const float nm = fmaxf(mr, pm);
        const float rs = fast_exp2(mr - nm);
        mr = nm;
        lr *= rs;
#pragma unroll
        for (int r = 0; r < 4; ++r) {
          const float rsb = __shfl(rs, sb + r);
#pragma unroll
          for (int dt = 0; dt < 4; ++dt) acc[dt][r] *= rsb;
        }
      }
      float ps = 0.f;
#pragma unroll
      for (int nt = 0; nt < 4; ++nt)
#pragma unroll
        for (int r = 0; r < 4; ++r) {
          s[nt][r] = fast_exp2(s[nt][r] - mr);
          ps += s[nt][r];
        }
      ps += __shfl_xor(ps, 16);
      ps += __shfl_xor(ps, 32);
      lr += ps;
      if (kt < qt) writeV(cur ^ 1);
      short8 pa[2];
#pragma unroll
      for (int m = 0; m < 2; ++m)
#pragma unroll
        for (int r = 0; r < 4; ++r) {
          pa[m][r] = (short)f2bf_trunc(s[2 * m][r]);
          pa[m][4 + r] = (short)f2bf_trunc(s[2 * m + 1][r]);
        }
      __builtin_amdgcn_s_setprio(1);
#pragma unroll
      for (int dt = 0; dt < 4; ++dt) {
        const int dh = dt * 16 + li;
#pragma unroll
        for (int m = 0; m < 2; ++m) {
          const short8 vb = *(const short8*)(Vt + dh * 128 + ((m * 64 + g * 16) ^ ((dh & 7) << 4)));
          acc[dt] = MFMA16(pa[m], vb, acc[dt]);
        }
      }
      __builtin_amdgcn_s_setprio(0);
      __syncthreads();
      cur ^= 1;
    }
#pragma unroll
    for (int r = 0; r < 4; ++r) {
      const float lrb = __shfl(lr, sb + r);
      const float inv = 1.f / lrb;
      const int row = rowb + q0 + w * 16 + g * 4 + r;
#pragma unroll
      for (int dt = 0; dt < 4; ++dt) {
        const int col = h * 64 + dt * 16 + li;
        ctx[(size_t)row * 1024 + col] = f2bf(acc[dt][r] * inv);
      }
    }
  }
}

extern "C" void kernel_launch(void* const* d_in, const int* in_sizes, int n_in,
                              void* d_out, int out_size, void* d_ws, size_t ws_size,
                              hipStream_t stream) {
  const float* x = (const float*)d_in[0];
  const float* Wq = (const float*)d_in[1];
  const float* Wk = (const float*)d_in[2];
  const float* Wv = (const float*)d_in[3];
  const float* Wo = (const float*)d_in[4];
  const float* g1 = (const float*)d_in[5];
  const float* g2 = (const float*)d_in[6];
  const float* W1 = (const float*)d_in[7];
  const float* W2 = (const float*)d_in[8];
  const float* W3 = (const float*)d_in[9];
  float* out = (float*)d_out;

  char* wsb = (char*)d_ws;
  ushort_t* hb = (ushort_t*)(wsb);                   // 0..8 MiB
  ushort_t* qkv = (ushort_t*)(wsb + (8u << 20));     // 8..32 (dead after attn)
  ushort_t* ctx = (ushort_t*)(wsb + (32u << 20));    // 32..40 (dead after Wo)
  ushort_t* x1b = (ushort_t*)(wsb + (8u << 20));     // 8..40, overlays dead qkv+ctx
  ushort_t* wqkvT = (ushort_t*)(wsb + (72u << 20));  // 72..78
  ushort_t* woT = (ushort_t*)(wsb + (78u << 20));    // 78..80
  ushort_t* w13iT = (ushort_t*)(wsb + (80u << 20));  // 80..96 (interleaved W1|W3 fragments)
  ushort_t* w2T = (ushort_t*)(wsb + (96u << 20));    // 96..104

  // weight transpose+cast to bf16 [N][K]: four 1024^2 in one launch; W1/W3/W2 in one launch.
  transpose4_k<<<dim3(16, 16, 4), 256, 0, stream>>>(Wq, Wk, Wv, Wo, wqkvT,
                                                    wqkvT + 1024 * 1024,
                                                    wqkvT + 2 * 1024 * 1024, woT);
  transpose3_k<<<dim3(64, 16, 3), 256, 0, stream>>>(W1, W3, W2, w13iT, w2T);

  // 1. h = rmsnorm(x, g1) -> bf16
  rmsnorm_k<<<4096, 256, 0, stream>>>(x, g1, hb);
  // 2+3. qkv = h @ [Wq|Wk|Wv] with FUSED RoPE epilogue (2D XCD supertile, 12x8 regions)
  gemm_k<2, 1><<<dim3(24, 32), 256, 0, stream>>>(hb, wqkvT, nullptr, qkv, 3072, 1024);
  // 4. ctx = causal flash attention (work-balanced q-tile pairs: 512 equal blocks)
  attn_k<<<dim3(16, 32), 256, 0, stream>>>(qkv, ctx);
  // 5. out1 = x + ctx @ Wo  (fp32, BK=64 PSPLIT schedule)
  gemmbk64_k<1><<<dim3(8, 32), 256, 0, stream>>>(ctx, woT, x, out, 1024, 1024);
  // 6. h2 = rmsnorm(out1, g2) -> bf16
  rmsnorm_k<<<4096, 256, 0, stream>>>(out, g2, hb);
  // 7. x1 = silu(h2@W1) * (h2@W3)  — 2D-XCD-supertiled fused interleaved GEMM
  gemm256_k<1><<<dim3(32, 16), 512, 0, stream>>>(hb, w13iT, x1b, 4096, 1024);
  // 8. out = out1 + x1 @ W2  (BK=64 PSPLIT schedule)
  gemmbk64_k<1><<<dim3(8, 32), 256, 0, stream>>>(x1b, w2T, out, out, 1024, 4096);
}